// Round 1
// baseline (1459.884 us; speedup 1.0000x reference)
//
#include <hip/hip_runtime.h>
#include <hip/hip_bf16.h>

#define QW 64
#define KW 128
#define PADW 32
#define DEPTH 3
#define HEADS 4
#define B_ 2
#define N_ 8192
#define DS 128
#define DP 16
#define DT 384
#define NT 1024
#define NWIN (N_ / QW)   // 128
#define DH (DS / HEADS)  // 32

// ---------------------------------------------------------------------------
// Kernel 1: s = feats @ W_single ; p = relu(s) @ W_outer
// feats = [pos(3), charge(1), mask(1), element(128), chars(256)] -> 389
// One block = 4 rows, 128 threads (one output column each).
// ---------------------------------------------------------------------------
__global__ __launch_bounds__(128) void embed_kernel(
    const float* __restrict__ pos, const float* __restrict__ charge,
    const float* __restrict__ mask, const float* __restrict__ elem,
    const float* __restrict__ chars, const float* __restrict__ Wsingle,
    const float* __restrict__ Wouter, float* __restrict__ X,
    float* __restrict__ P)
{
    const int ROWS = 4;
    __shared__ float sf[ROWS][392];
    __shared__ float srelu[ROWS][DS];
    int row0 = blockIdx.x * ROWS;  // global row = b*N + i
    int tid = threadIdx.x;         // 0..127

    for (int r = 0; r < ROWS; ++r) {
        int g = row0 + r;
        for (int c = tid; c < 389; c += 128) {
            float v;
            if (c < 3)        v = pos[g * 3 + c];
            else if (c == 3)  v = charge[g];
            else if (c == 4)  v = mask[g];
            else if (c < 133) v = elem[g * 128 + (c - 5)];
            else              v = chars[g * 256 + (c - 133)];
            sf[r][c] = v;
        }
    }
    __syncthreads();

    float acc[ROWS] = {0.f, 0.f, 0.f, 0.f};
    for (int c = 0; c < 389; ++c) {
        float w = Wsingle[c * DS + tid];
        #pragma unroll
        for (int r = 0; r < ROWS; ++r) acc[r] += sf[r][c] * w;
    }
    for (int r = 0; r < ROWS; ++r) {
        int g = row0 + r;
        X[(size_t)g * DS + tid] = acc[r];
        srelu[r][tid] = fmaxf(acc[r], 0.f);
    }
    __syncthreads();

    // p = relu(s) @ W_outer : 4 rows x 32 cols = 128 outputs, one per thread
    int r = tid >> 5, e = tid & 31;
    float a = 0.f;
    for (int k = 0; k < DS; ++k) a += srelu[r][k] * Wouter[k * 32 + e];
    P[(size_t)(row0 + r) * 32 + e] = a;
}

// ---------------------------------------------------------------------------
// Kernel 2: fused pair pipeline -> attention bias (B, n, H, QW, KW)
// One thread per (b, w, q, k) cell. All intermediates in registers.
// ---------------------------------------------------------------------------
__global__ __launch_bounds__(256) void bias_kernel(
    const float* __restrict__ pos, const int* __restrict__ uid,
    const float* __restrict__ P, const float* __restrict__ Wpair,
    const float* __restrict__ Wff1, const float* __restrict__ Wff2,
    const float* __restrict__ Wb, float* __restrict__ BIAS)
{
    __shared__ float sW1[DP * 64];
    __shared__ float sW2[64 * DP];
    __shared__ float sWp[5 * DP];
    __shared__ float sWb[DP * HEADS];
    for (int i = threadIdx.x; i < DP * 64; i += 256) sW1[i] = Wff1[i];
    for (int i = threadIdx.x; i < 64 * DP; i += 256) sW2[i] = Wff2[i];
    if (threadIdx.x < 5 * DP) sWp[threadIdx.x] = Wpair[threadIdx.x];
    if (threadIdx.x < DP * HEADS) sWb[threadIdx.x] = Wb[threadIdx.x];
    __syncthreads();

    int tid = blockIdx.x * 256 + threadIdx.x;  // over B*NWIN*QW*KW = 2^21
    int kk = tid & (KW - 1);
    int q  = (tid >> 7) & (QW - 1);
    int w  = (tid >> 13) & (NWIN - 1);
    int b  = tid >> 20;
    int iq = w * QW + q;
    int jk = w * QW + kk - PADW;
    bool valid = (jk >= 0) && (jk < N_);
    int gq = b * N_ + iq;
    int gk = b * N_ + jk;

    float pxi = pos[gq * 3], pyi = pos[gq * 3 + 1], pzi = pos[gq * 3 + 2];
    float pxj = 0.f, pyj = 0.f, pzj = 0.f;
    int uj = 0;  // jnp.pad pads uid with 0 -> bij can match uid==0!
    if (valid) {
        pxj = pos[gk * 3]; pyj = pos[gk * 3 + 1]; pzj = pos[gk * 3 + 2];
        uj = uid[gk];
    }
    int ui = uid[gq];
    float dx = pxi - pxj, dy = pyi - pyj, dz = pzi - pzj;
    float inv = 1.f / (1.f + dx * dx + dy * dy + dz * dz);
    float bflag = (ui == uj) ? 1.f : 0.f;

    float pr[DP];
    #pragma unroll
    for (int c = 0; c < DP; ++c) {
        float t = dx * sWp[0 * DP + c] + dy * sWp[1 * DP + c] +
                  dz * sWp[2 * DP + c] + inv * sWp[3 * DP + c] +
                  bflag * sWp[4 * DP + c];
        pr[c] = t * bflag;
    }
    #pragma unroll
    for (int c = 0; c < DP; ++c) {
        pr[c] += P[(size_t)gq * 32 + c];
        if (valid) pr[c] += P[(size_t)gk * 32 + 16 + c];
    }

    // LayerNorm over 16
    float m = 0.f;
    #pragma unroll
    for (int c = 0; c < DP; ++c) m += pr[c];
    m *= (1.f / DP);
    float ss = 0.f;
    #pragma unroll
    for (int c = 0; c < DP; ++c) { float d = pr[c] - m; ss += d * d; }
    float rstd = rsqrtf(ss * (1.f / DP) + 1e-5f);
    float lp[DP];
    #pragma unroll
    for (int c = 0; c < DP; ++c) lp[c] = (pr[c] - m) * rstd;

    // 16 -> 64 relu -> 16, residual
    float t64[64];
    #pragma unroll
    for (int j = 0; j < 64; ++j) {
        float a = 0.f;
        #pragma unroll
        for (int c = 0; c < DP; ++c) a += lp[c] * sW1[c * 64 + j];
        t64[j] = fmaxf(a, 0.f);
    }
    #pragma unroll
    for (int c = 0; c < DP; ++c) {
        float a = 0.f;
        #pragma unroll
        for (int j = 0; j < 64; ++j) a += t64[j] * sW2[j * DP + c];
        pr[c] += a;
    }

    // bias heads
    #pragma unroll
    for (int h = 0; h < HEADS; ++h) {
        float a = 0.f;
        #pragma unroll
        for (int c = 0; c < DP; ++c) a += pr[c] * sWb[c * HEADS + h];
        BIAS[(((size_t)(b * NWIN + w) * HEADS + h) * QW + q) * KW + kk] = a;
    }
}

// ---------------------------------------------------------------------------
// Kernel 3: LayerNorm over DS=128. One wave per row, 4 rows per block.
// ---------------------------------------------------------------------------
__global__ __launch_bounds__(256) void ln_kernel(const float* __restrict__ X,
                                                 float* __restrict__ H)
{
    int wave = threadIdx.x >> 6;
    int lane = threadIdx.x & 63;
    int row = blockIdx.x * 4 + wave;
    const float* x = X + (size_t)row * DS;
    float a0 = x[lane], a1 = x[lane + 64];
    float s = a0 + a1, ss = a0 * a0 + a1 * a1;
    for (int o = 32; o > 0; o >>= 1) {
        s  += __shfl_down(s, o);
        ss += __shfl_down(ss, o);
    }
    s = __shfl(s, 0); ss = __shfl(ss, 0);
    float m = s * (1.f / DS);
    float v = ss * (1.f / DS) - m * m;
    float r = rsqrtf(v + 1e-5f);
    H[(size_t)row * DS + lane]      = (a0 - m) * r;
    H[(size_t)row * DS + lane + 64] = (a1 - m) * r;
}

// ---------------------------------------------------------------------------
// Kernel 4: generic GEMM  Out[M,N] (+)= (relu)(A[M,K] @ W[K,N])
// Block: 256 threads, 32 rows x 128 cols tile. grid = (M/32, N/128).
// ---------------------------------------------------------------------------
template <bool ADD, bool RELU>
__global__ __launch_bounds__(256) void gemm_kernel(
    const float* __restrict__ A, const float* __restrict__ W,
    float* __restrict__ Out, int M, int K, int N)
{
    __shared__ float As[32][128];
    int col = blockIdx.y * 128 + (threadIdx.x & 127);
    int ty = threadIdx.x >> 7;  // 0..1
    int row0 = blockIdx.x * 32;

    float acc[16];
    #pragma unroll
    for (int j = 0; j < 16; ++j) acc[j] = 0.f;

    for (int k0 = 0; k0 < K; k0 += 128) {
        __syncthreads();
        for (int idx = threadIdx.x; idx < 32 * 128; idx += 256) {
            int r = idx >> 7, c = idx & 127;
            As[r][c] = A[(size_t)(row0 + r) * K + k0 + c];
        }
        __syncthreads();
        for (int k = 0; k < 128; ++k) {
            float w = W[(size_t)(k0 + k) * N + col];
            #pragma unroll
            for (int j = 0; j < 16; ++j) acc[j] += As[ty + 2 * j][k] * w;
        }
    }
    #pragma unroll
    for (int j = 0; j < 16; ++j) {
        int row = row0 + ty + 2 * j;
        size_t o = (size_t)row * N + col;
        float v = acc[j];
        if (RELU) v = fmaxf(v, 0.f);
        if (ADD) v += Out[o];
        Out[o] = v;
    }
}

// ---------------------------------------------------------------------------
// Kernel 5: windowed attention, one block per (b, window, head).
// ---------------------------------------------------------------------------
__global__ __launch_bounds__(256) void attn_kernel(
    const float* __restrict__ Q, const float* __restrict__ K,
    const float* __restrict__ V, const float* __restrict__ BIAS,
    float* __restrict__ O)
{
    __shared__ float sQK[QW * 33 + KW * 33];  // 6336 floats
    __shared__ float sL[QW * 129];            // 8256 floats
    float* sQ = sQK;
    float* sK = sQK + QW * 33;
    float* sV = sQK;  // reused after logits (KW*33 = 4224 <= 6336)

    int blk = blockIdx.x;  // b*NWIN*HEADS + w*HEADS + h
    int h = blk % HEADS;
    int w = (blk / HEADS) % NWIN;
    int b = blk / (HEADS * NWIN);
    int tid = threadIdx.x;

    for (int idx = tid; idx < QW * DH; idx += 256) {
        int q = idx >> 5, d = idx & 31;
        sQ[q * 33 + d] = Q[((size_t)b * N_ + w * QW + q) * DS + h * DH + d];
    }
    for (int idx = tid; idx < KW * DH; idx += 256) {
        int kk = idx >> 5, d = idx & 31;
        int jk = w * QW + kk - PADW;
        float v = 0.f;
        if (jk >= 0 && jk < N_) v = K[((size_t)b * N_ + jk) * DS + h * DH + d];
        sK[kk * 33 + d] = v;
    }
    __syncthreads();

    const float scale = 0.17677669529663687f;  // 1/sqrt(32)
    const float* biasBase = BIAS + ((size_t)(b * NWIN + w) * HEADS + h) * QW * KW;
    for (int idx = tid; idx < QW * KW; idx += 256) {
        int q = idx >> 7, kk = idx & 127;
        float a = 0.f;
        #pragma unroll
        for (int d = 0; d < DH; ++d) a += sQ[q * 33 + d] * sK[kk * 33 + d];
        int jk = w * QW + kk - PADW;
        float msk = (jk >= 0 && jk < N_) ? 0.f : -1e9f;
        sL[q * 129 + kk] = a * scale + biasBase[q * KW + kk] + msk;
    }
    __syncthreads();

    // load V (overwrites sQ/sK) + per-row softmax, concurrently
    for (int idx = tid; idx < KW * DH; idx += 256) {
        int kk = idx >> 5, d = idx & 31;
        int jk = w * QW + kk - PADW;
        float v = 0.f;
        if (jk >= 0 && jk < N_) v = V[((size_t)b * N_ + jk) * DS + h * DH + d];
        sV[kk * 33 + d] = v;
    }
    if (tid < QW) {
        float mx = -1e30f;
        for (int kk = 0; kk < KW; ++kk) mx = fmaxf(mx, sL[tid * 129 + kk]);
        float sum = 0.f;
        for (int kk = 0; kk < KW; ++kk) {
            float e = __expf(sL[tid * 129 + kk] - mx);
            sL[tid * 129 + kk] = e;
            sum += e;
        }
        float inv = 1.f / sum;
        for (int kk = 0; kk < KW; ++kk) sL[tid * 129 + kk] *= inv;
    }
    __syncthreads();

    for (int idx = tid; idx < QW * DH; idx += 256) {
        int q = idx >> 5, d = idx & 31;
        float a = 0.f;
        for (int kk = 0; kk < KW; ++kk) a += sL[q * 129 + kk] * sV[kk * 33 + d];
        O[((size_t)b * N_ + w * QW + q) * DS + h * DH + d] = a;
    }
}

// ---------------------------------------------------------------------------
// Kernel 6: segment mean over sorted atom_to_token_idx. One block per (b, t).
// ---------------------------------------------------------------------------
__global__ __launch_bounds__(128) void seg_kernel(
    const float* __restrict__ TOK, const int* __restrict__ idx,
    float* __restrict__ out)
{
    int t = blockIdx.x & (NT - 1);
    int b = blockIdx.x >> 10;
    const int* id = idx + (size_t)b * N_;

    int lo = 0, hi = N_;
    while (lo < hi) { int mid = (lo + hi) >> 1; if (id[mid] < t) lo = mid + 1; else hi = mid; }
    int start = lo;
    hi = N_;
    while (lo < hi) { int mid = (lo + hi) >> 1; if (id[mid] < t + 1) lo = mid + 1; else hi = mid; }
    int end = lo;

    float inv = 1.f / fmaxf((float)(end - start), 1.f);
    for (int c = threadIdx.x; c < DT; c += 128) {
        float s = 0.f;
        for (int r = start; r < end; ++r) s += TOK[((size_t)b * N_ + r) * DT + c];
        out[((size_t)b * NT + t) * DT + c] = s * inv;
    }
}

// ---------------------------------------------------------------------------
extern "C" void kernel_launch(void* const* d_in, const int* in_sizes, int n_in,
                              void* d_out, int out_size, void* d_ws, size_t ws_size,
                              hipStream_t stream)
{
    const float* ref_pos    = (const float*)d_in[0];
    const float* ref_charge = (const float*)d_in[1];
    const float* ref_mask   = (const float*)d_in[2];
    const float* ref_elem   = (const float*)d_in[3];
    const float* ref_chars  = (const float*)d_in[4];
    const float* W_single   = (const float*)d_in[5];
    const float* W_pair     = (const float*)d_in[6];
    const float* W_outer    = (const float*)d_in[7];
    const float* Wp_ff1     = (const float*)d_in[8];
    const float* Wp_ff2     = (const float*)d_in[9];
    const float* Wq         = (const float*)d_in[10];
    const float* Wk         = (const float*)d_in[11];
    const float* Wv         = (const float*)d_in[12];
    const float* Wo         = (const float*)d_in[13];
    const float* Wb         = (const float*)d_in[14];
    const float* Wff1       = (const float*)d_in[15];
    const float* Wff2       = (const float*)d_in[16];
    const float* W_out      = (const float*)d_in[17];
    const int*   uid        = (const int*)d_in[18];
    const int*   a2t        = (const int*)d_in[19];
    float* out = (float*)d_out;

    const size_t ROWS = (size_t)B_ * N_;  // 16384
    float* ws = (float*)d_ws;
    float* X    = ws;                    // ROWS*DS     = 2097152
    float* H    = X    + ROWS * DS;      // 2097152
    float* Qb   = H    + ROWS * DS;      // 2097152
    float* Kb   = Qb   + ROWS * DS;      // 2097152
    float* Vb   = Kb   + ROWS * DS;      // 2097152
    float* Ob   = Vb   + ROWS * DS;      // 2097152
    float* P    = Ob   + ROWS * DS;      // ROWS*32     = 524288
    float* BIAS = P    + ROWS * 32;      // B*n*H*QW*KW = 8388608
    float* FF   = BIAS + (size_t)B_ * NWIN * HEADS * QW * KW;  // ROWS*512
    float* TOK  = FF;                    // reuse FF region (ROWS*384 <= ROWS*512)

    embed_kernel<<<ROWS / 4, 128, 0, stream>>>(ref_pos, ref_charge, ref_mask,
                                               ref_elem, ref_chars, W_single,
                                               W_outer, X, P);
    bias_kernel<<<(B_ * NWIN * QW * KW) / 256, 256, 0, stream>>>(
        ref_pos, uid, P, W_pair, Wp_ff1, Wp_ff2, Wb, BIAS);

    for (int l = 0; l < DEPTH; ++l) {
        ln_kernel<<<ROWS / 4, 256, 0, stream>>>(X, H);
        gemm_kernel<false, false><<<dim3(ROWS / 32, 1), 256, 0, stream>>>(
            H, Wq + (size_t)l * DS * DS, Qb, ROWS, DS, DS);
        gemm_kernel<false, false><<<dim3(ROWS / 32, 1), 256, 0, stream>>>(
            H, Wk + (size_t)l * DS * DS, Kb, ROWS, DS, DS);
        gemm_kernel<false, false><<<dim3(ROWS / 32, 1), 256, 0, stream>>>(
            H, Wv + (size_t)l * DS * DS, Vb, ROWS, DS, DS);
        attn_kernel<<<B_ * NWIN * HEADS, 256, 0, stream>>>(Qb, Kb, Vb, BIAS, Ob);
        gemm_kernel<true, false><<<dim3(ROWS / 32, 1), 256, 0, stream>>>(
            Ob, Wo + (size_t)l * DS * DS, X, ROWS, DS, DS);
        ln_kernel<<<ROWS / 4, 256, 0, stream>>>(X, H);
        gemm_kernel<false, true><<<dim3(ROWS / 32, 4), 256, 0, stream>>>(
            H, Wff1 + (size_t)l * DS * 4 * DS, FF, ROWS, DS, 4 * DS);
        gemm_kernel<true, false><<<dim3(ROWS / 32, 1), 256, 0, stream>>>(
            FF, Wff2 + (size_t)l * 4 * DS * DS, X, ROWS, 4 * DS, DS);
    }

    gemm_kernel<false, true><<<dim3(ROWS / 32, 3), 256, 0, stream>>>(
        X, W_out, TOK, ROWS, DS, DT);
    seg_kernel<<<B_ * NT, 128, 0, stream>>>(TOK, a2t, out);
}

// Round 2
// 792.967 us; speedup vs baseline: 1.8410x; 1.8410x over previous
//
#include <hip/hip_runtime.h>
#include <hip/hip_bf16.h>

#define QW 64
#define KW 128
#define PADW 32
#define DEPTH 3
#define HEADS 4
#define B_ 2
#define N_ 8192
#define DS 128
#define DP 16
#define DT 384
#define NT 1024
#define NWIN (N_ / QW)   // 128
#define DH (DS / HEADS)  // 32

typedef unsigned short u16;
typedef __attribute__((ext_vector_type(8))) short short8;
typedef __attribute__((ext_vector_type(4))) float f32x4v;
typedef __attribute__((ext_vector_type(4))) unsigned short us4;

__device__ __forceinline__ u16 f2b(float x) {
    union { float f; unsigned u; } v; v.f = x;
    unsigned r = v.u + 0x7fffu + ((v.u >> 16) & 1u);
    return (u16)(r >> 16);
}
__device__ __forceinline__ float b2f(u16 h) {
    union { unsigned u; float f; } v; v.u = ((unsigned)h) << 16; return v.f;
}

// ---------------------------------------------------------------------------
// Weight conversion: fp32 -> bf16, transposed to [n][k] for MFMA B-frags.
// ---------------------------------------------------------------------------
__global__ __launch_bounds__(256) void convw_kernel(
    const float* __restrict__ Wq, const float* __restrict__ Wk,
    const float* __restrict__ Wv, const float* __restrict__ Wo,
    const float* __restrict__ Wff1, const float* __restrict__ Wff2,
    const float* __restrict__ Wout,
    u16* __restrict__ qkvT, u16* __restrict__ woT, u16* __restrict__ ff1T,
    u16* __restrict__ ff2T, u16* __restrict__ woutT)
{
    int idx = blockIdx.x * 256 + threadIdx.x;
    if (idx < 3 * 384 * 128) {  // qkvT[l][n(384)][k(128)]
        int l = idx / (384 * 128), r = idx % (384 * 128);
        int n = r / 128, k = r % 128;
        const float* W = (n < 128) ? Wq : (n < 256) ? Wk : Wv;
        qkvT[idx] = f2b(W[(size_t)l * 16384 + k * 128 + (n & 127)]);
    }
    if (idx < 3 * 128 * 128) {  // woT[l][n][k]
        int l = idx / 16384, r = idx % 16384;
        int n = r / 128, k = r % 128;
        woT[idx] = f2b(Wo[(size_t)l * 16384 + k * 128 + n]);
    }
    if (idx < 3 * 512 * 128) {  // ff1T[l][n(512)][k(128)]
        int l = idx / 65536, r = idx % 65536;
        int n = r / 128, k = r % 128;
        ff1T[idx] = f2b(Wff1[(size_t)l * 65536 + k * 512 + n]);
    }
    if (idx < 3 * 128 * 512) {  // ff2T[l][n(128)][k(512)]
        int l = idx / 65536, r = idx % 65536;
        int n = r / 512, k = r % 512;
        ff2T[idx] = f2b(Wff2[(size_t)l * 65536 + k * 128 + n]);
    }
    if (idx < 384 * 128) {      // woutT[n(384)][k(128)]
        int n = idx / 128, k = idx % 128;
        woutT[idx] = f2b(Wout[(size_t)k * 384 + n]);
    }
}

// ---------------------------------------------------------------------------
// MFMA GEMM: Out[M,N] op= A[M,K] @ WT[N,K]^T   (bf16 inputs, fp32 acc)
// Block 256 thr = 4 waves; tile 64(M)x128(N); wave tile 32x64; KSTEP=64.
// ---------------------------------------------------------------------------
template <bool AF32, bool ADD, bool RELU, bool OUTB>
__global__ __launch_bounds__(256) void gemm_mfma(
    const void* __restrict__ Ap, const u16* __restrict__ WT,
    float* __restrict__ OutF, u16* __restrict__ OutB,
    int M, int K, int N)
{
    __shared__ __align__(16) u16 As[64 * 88];  // pad 64->88: 2-way max
    const int row0 = blockIdx.x * 64, n0 = blockIdx.y * 128;
    const int tid = threadIdx.x;
    const int w = tid >> 6, lane = tid & 63, quad = lane >> 4, l16 = lane & 15;
    const int wm = (w & 1) * 32, wn = (w >> 1) * 64;

    f32x4v acc[2][4];
    #pragma unroll
    for (int i = 0; i < 2; ++i)
        #pragma unroll
        for (int j = 0; j < 4; ++j) acc[i][j] = (f32x4v){0.f, 0.f, 0.f, 0.f};

    for (int k0 = 0; k0 < K; k0 += 64) {
        __syncthreads();
        if (AF32) {
            const float* A = (const float*)Ap;
            #pragma unroll
            for (int it = 0; it < 4; ++it) {
                int idx = tid + it * 256;       // 1024 float4 chunks
                int r = idx >> 4, c = idx & 15;
                f32x4v v = *(const f32x4v*)(A + (size_t)(row0 + r) * K + k0 + c * 4);
                us4 o = (us4){f2b(v[0]), f2b(v[1]), f2b(v[2]), f2b(v[3])};
                *(us4*)&As[r * 88 + c * 4] = o;
            }
        } else {
            const u16* A = (const u16*)Ap;
            #pragma unroll
            for (int it = 0; it < 2; ++it) {
                int idx = tid + it * 256;       // 512 16B chunks
                int r = idx >> 3, c = idx & 7;
                short8 v = *(const short8*)(A + (size_t)(row0 + r) * K + k0 + c * 8);
                *(short8*)&As[r * 88 + c * 8] = v;
            }
        }
        __syncthreads();
        #pragma unroll
        for (int kk = 0; kk < 64; kk += 32) {
            short8 a0 = *(const short8*)&As[(wm + l16) * 88 + kk + quad * 8];
            short8 a1 = *(const short8*)&As[(wm + 16 + l16) * 88 + kk + quad * 8];
            #pragma unroll
            for (int nt = 0; nt < 4; ++nt) {
                short8 b = *(const short8*)&WT[(size_t)(n0 + wn + nt * 16 + l16) * K + k0 + kk + quad * 8];
                acc[0][nt] = __builtin_amdgcn_mfma_f32_16x16x32_bf16(a0, b, acc[0][nt], 0, 0, 0);
                acc[1][nt] = __builtin_amdgcn_mfma_f32_16x16x32_bf16(a1, b, acc[1][nt], 0, 0, 0);
            }
        }
    }
    #pragma unroll
    for (int mt = 0; mt < 2; ++mt)
        #pragma unroll
        for (int nt = 0; nt < 4; ++nt)
            #pragma unroll
            for (int r = 0; r < 4; ++r) {
                int row = row0 + wm + mt * 16 + quad * 4 + r;
                int col = n0 + wn + nt * 16 + l16;
                size_t o = (size_t)row * N + col;
                float v = acc[mt][nt][r];
                if (RELU) v = fmaxf(v, 0.f);
                if (ADD) v += OutF[o];
                if (OUTB) OutB[o] = f2b(v);
                else      OutF[o] = v;
            }
}

// ---------------------------------------------------------------------------
// Embed: s = feats @ W_single ; p = relu(s) @ W_outer  (unchanged)
// ---------------------------------------------------------------------------
__global__ __launch_bounds__(128) void embed_kernel(
    const float* __restrict__ pos, const float* __restrict__ charge,
    const float* __restrict__ mask, const float* __restrict__ elem,
    const float* __restrict__ chars, const float* __restrict__ Wsingle,
    const float* __restrict__ Wouter, float* __restrict__ X,
    float* __restrict__ P)
{
    const int ROWS = 4;
    __shared__ float sf[ROWS][392];
    __shared__ float srelu[ROWS][DS];
    int row0 = blockIdx.x * ROWS;
    int tid = threadIdx.x;

    for (int r = 0; r < ROWS; ++r) {
        int g = row0 + r;
        for (int c = tid; c < 389; c += 128) {
            float v;
            if (c < 3)        v = pos[g * 3 + c];
            else if (c == 3)  v = charge[g];
            else if (c == 4)  v = mask[g];
            else if (c < 133) v = elem[g * 128 + (c - 5)];
            else              v = chars[g * 256 + (c - 133)];
            sf[r][c] = v;
        }
    }
    __syncthreads();

    float acc[ROWS] = {0.f, 0.f, 0.f, 0.f};
    for (int c = 0; c < 389; ++c) {
        float w = Wsingle[c * DS + tid];
        #pragma unroll
        for (int r = 0; r < ROWS; ++r) acc[r] += sf[r][c] * w;
    }
    for (int r = 0; r < ROWS; ++r) {
        X[(size_t)(row0 + r) * DS + tid] = acc[r];
        srelu[r][tid] = fmaxf(acc[r], 0.f);
    }
    __syncthreads();

    int r = tid >> 5, e = tid & 31;
    float a = 0.f;
    for (int k = 0; k < DS; ++k) a += srelu[r][k] * Wouter[k * 32 + e];
    P[(size_t)(row0 + r) * 32 + e] = a;
}

// ---------------------------------------------------------------------------
// Bias kernel: 4 cells per thread (same q, k strided by 32).
// ---------------------------------------------------------------------------
__global__ __launch_bounds__(256) void bias_kernel(
    const float* __restrict__ pos, const int* __restrict__ uid,
    const float* __restrict__ P, const float* __restrict__ Wpair,
    const float* __restrict__ Wff1, const float* __restrict__ Wff2,
    const float* __restrict__ Wb, float* __restrict__ BIAS)
{
    __shared__ float sW1T[64 * 16];  // [j][c] (transposed)
    __shared__ float sW2[64 * 16];   // [j][c]
    __shared__ float sWp[5 * 16];
    __shared__ float sWb[16 * 4];
    for (int i = threadIdx.x; i < 1024; i += 256) {
        sW1T[i] = Wff1[(i & 15) * 64 + (i >> 4)];
        sW2[i]  = Wff2[i];
    }
    if (threadIdx.x < 80) sWp[threadIdx.x] = Wpair[threadIdx.x];
    if (threadIdx.x < 64) sWb[threadIdx.x] = Wb[threadIdx.x];
    __syncthreads();

    int blk = blockIdx.x;            // 2048 blocks
    int b = blk >> 10;
    int w = (blk >> 3) & 127;
    int q = (blk & 7) * 8 + (threadIdx.x >> 5);
    int kb = threadIdx.x & 31;

    int gq = b * N_ + w * QW + q;
    float pxi = pos[gq * 3], pyi = pos[gq * 3 + 1], pzi = pos[gq * 3 + 2];
    int ui = uid[gq];
    float pi[16];
    {
        const f32x4v* P4 = (const f32x4v*)(P + (size_t)gq * 32);
        #pragma unroll
        for (int c4 = 0; c4 < 4; ++c4) {
            f32x4v t = P4[c4];
            pi[c4 * 4] = t[0]; pi[c4 * 4 + 1] = t[1];
            pi[c4 * 4 + 2] = t[2]; pi[c4 * 4 + 3] = t[3];
        }
    }

    float lp[4][16], acc[4][16], mmean[4], mstd[4];
    #pragma unroll
    for (int i = 0; i < 4; ++i) {
        int kk = kb + 32 * i;
        int jk = w * QW + kk - PADW;
        bool valid = (jk >= 0) && (jk < N_);
        int gk = b * N_ + jk;
        float pxj = 0.f, pyj = 0.f, pzj = 0.f;
        int uj = 0;  // jnp.pad pads uid with 0
        float pj[16];
        #pragma unroll
        for (int c = 0; c < 16; ++c) pj[c] = 0.f;
        if (valid) {
            pxj = pos[gk * 3]; pyj = pos[gk * 3 + 1]; pzj = pos[gk * 3 + 2];
            uj = uid[gk];
            const f32x4v* Pj = (const f32x4v*)(P + (size_t)gk * 32 + 16);
            #pragma unroll
            for (int c4 = 0; c4 < 4; ++c4) {
                f32x4v t = Pj[c4];
                pj[c4 * 4] = t[0]; pj[c4 * 4 + 1] = t[1];
                pj[c4 * 4 + 2] = t[2]; pj[c4 * 4 + 3] = t[3];
            }
        }
        float dx = pxi - pxj, dy = pyi - pyj, dz = pzi - pzj;
        float inv = 1.f / (1.f + dx * dx + dy * dy + dz * dz);
        float bf = (ui == uj) ? 1.f : 0.f;
        float pr[16];
        #pragma unroll
        for (int c = 0; c < 16; ++c) {
            float t = dx * sWp[c] + dy * sWp[16 + c] + dz * sWp[32 + c] +
                      inv * sWp[48 + c] + bf * sWp[64 + c];
            pr[c] = t * bf + pi[c] + pj[c];
        }
        float m = 0.f;
        #pragma unroll
        for (int c = 0; c < 16; ++c) m += pr[c];
        m *= (1.f / 16.f);
        float ss = 0.f;
        #pragma unroll
        for (int c = 0; c < 16; ++c) { float d = pr[c] - m; ss += d * d; }
        float ve = ss * (1.f / 16.f) + 1e-5f;
        float rstd = rsqrtf(ve);
        mmean[i] = m;
        mstd[i] = ve * rstd;  // sqrt(ve) = 1/rstd
        #pragma unroll
        for (int c = 0; c < 16; ++c) lp[i][c] = (pr[c] - m) * rstd;
        #pragma unroll
        for (int c = 0; c < 16; ++c) acc[i][c] = 0.f;
    }

    const f32x4v* W14 = (const f32x4v*)sW1T;
    const f32x4v* W24 = (const f32x4v*)sW2;
    for (int j = 0; j < 64; ++j) {
        f32x4v w1v[4], w2v[4];
        #pragma unroll
        for (int c4 = 0; c4 < 4; ++c4) w1v[c4] = W14[j * 4 + c4];
        float t[4];
        #pragma unroll
        for (int i = 0; i < 4; ++i) {
            float a = 0.f;
            #pragma unroll
            for (int c4 = 0; c4 < 4; ++c4)
                a += lp[i][c4 * 4] * w1v[c4][0] + lp[i][c4 * 4 + 1] * w1v[c4][1] +
                     lp[i][c4 * 4 + 2] * w1v[c4][2] + lp[i][c4 * 4 + 3] * w1v[c4][3];
            t[i] = fmaxf(a, 0.f);
        }
        #pragma unroll
        for (int c4 = 0; c4 < 4; ++c4) w2v[c4] = W24[j * 4 + c4];
        #pragma unroll
        for (int i = 0; i < 4; ++i)
            #pragma unroll
            for (int c4 = 0; c4 < 4; ++c4) {
                acc[i][c4 * 4]     += t[i] * w2v[c4][0];
                acc[i][c4 * 4 + 1] += t[i] * w2v[c4][1];
                acc[i][c4 * 4 + 2] += t[i] * w2v[c4][2];
                acc[i][c4 * 4 + 3] += t[i] * w2v[c4][3];
            }
    }

    #pragma unroll
    for (int i = 0; i < 4; ++i) {
        int kk = kb + 32 * i;
        float b0 = 0.f, b1 = 0.f, b2 = 0.f, b3 = 0.f;
        #pragma unroll
        for (int c = 0; c < 16; ++c) {
            float pv = lp[i][c] * mstd[i] + mmean[i] + acc[i][c];
            b0 += pv * sWb[c * 4 + 0];
            b1 += pv * sWb[c * 4 + 1];
            b2 += pv * sWb[c * 4 + 2];
            b3 += pv * sWb[c * 4 + 3];
        }
        size_t base = (((size_t)(b * NWIN + w) * HEADS) * QW + q) * KW + kk;
        BIAS[base]                       = b0;
        BIAS[base + (size_t)QW * KW]     = b1;
        BIAS[base + (size_t)QW * KW * 2] = b2;
        BIAS[base + (size_t)QW * KW * 3] = b3;
    }
}

// ---------------------------------------------------------------------------
// LayerNorm over DS=128 (fp32 in/out).
// ---------------------------------------------------------------------------
__global__ __launch_bounds__(256) void ln_kernel(const float* __restrict__ X,
                                                 float* __restrict__ H)
{
    int wave = threadIdx.x >> 6;
    int lane = threadIdx.x & 63;
    int row = blockIdx.x * 4 + wave;
    const float* x = X + (size_t)row * DS;
    float a0 = x[lane], a1 = x[lane + 64];
    float s = a0 + a1, ss = a0 * a0 + a1 * a1;
    for (int o = 32; o > 0; o >>= 1) {
        s  += __shfl_down(s, o);
        ss += __shfl_down(ss, o);
    }
    s = __shfl(s, 0); ss = __shfl(ss, 0);
    float m = s * (1.f / DS);
    float v = ss * (1.f / DS) - m * m;
    float r = rsqrtf(v + 1e-5f);
    H[(size_t)row * DS + lane]      = (a0 - m) * r;
    H[(size_t)row * DS + lane + 64] = (a1 - m) * r;
}

// ---------------------------------------------------------------------------
// Windowed attention; QKV packed bf16 [row][384]; Ob bf16.
// ---------------------------------------------------------------------------
__global__ __launch_bounds__(256) void attn_kernel(
    const u16* __restrict__ QKV, const float* __restrict__ BIAS,
    u16* __restrict__ O)
{
    __shared__ float sQK[QW * 33 + KW * 33];
    __shared__ float sL[QW * 129];
    float* sQ = sQK;
    float* sK = sQK + QW * 33;
    float* sV = sQK;  // reused after logits

    int blk = blockIdx.x;
    int h = blk % HEADS;
    int w = (blk / HEADS) % NWIN;
    int b = blk / (HEADS * NWIN);
    int tid = threadIdx.x;

    for (int idx = tid; idx < QW * DH; idx += 256) {
        int q = idx >> 5, d = idx & 31;
        sQ[q * 33 + d] = b2f(QKV[((size_t)b * N_ + w * QW + q) * 384 + h * DH + d]);
    }
    for (int idx = tid; idx < KW * DH; idx += 256) {
        int kk = idx >> 5, d = idx & 31;
        int jk = w * QW + kk - PADW;
        float v = 0.f;
        if (jk >= 0 && jk < N_) v = b2f(QKV[((size_t)b * N_ + jk) * 384 + 128 + h * DH + d]);
        sK[kk * 33 + d] = v;
    }
    __syncthreads();

    const float scale = 0.17677669529663687f;
    const float* biasBase = BIAS + ((size_t)(b * NWIN + w) * HEADS + h) * QW * KW;
    for (int idx = tid; idx < QW * KW; idx += 256) {
        int q = idx >> 7, kk = idx & 127;
        float a = 0.f;
        #pragma unroll
        for (int d = 0; d < DH; ++d) a += sQ[q * 33 + d] * sK[kk * 33 + d];
        int jk = w * QW + kk - PADW;
        float msk = (jk >= 0 && jk < N_) ? 0.f : -1e9f;
        sL[q * 129 + kk] = a * scale + biasBase[q * KW + kk] + msk;
    }
    __syncthreads();

    for (int idx = tid; idx < KW * DH; idx += 256) {
        int kk = idx >> 5, d = idx & 31;
        int jk = w * QW + kk - PADW;
        float v = 0.f;
        if (jk >= 0 && jk < N_) v = b2f(QKV[((size_t)b * N_ + jk) * 384 + 256 + h * DH + d]);
        sV[kk * 33 + d] = v;
    }
    if (tid < QW) {
        float mx = -1e30f;
        for (int kk = 0; kk < KW; ++kk) mx = fmaxf(mx, sL[tid * 129 + kk]);
        float sum = 0.f;
        for (int kk = 0; kk < KW; ++kk) {
            float e = __expf(sL[tid * 129 + kk] - mx);
            sL[tid * 129 + kk] = e;
            sum += e;
        }
        float inv = 1.f / sum;
        for (int kk = 0; kk < KW; ++kk) sL[tid * 129 + kk] *= inv;
    }
    __syncthreads();

    for (int idx = tid; idx < QW * DH; idx += 256) {
        int q = idx >> 5, d = idx & 31;
        float a = 0.f;
        for (int kk = 0; kk < KW; ++kk) a += sL[q * 129 + kk] * sV[kk * 33 + d];
        O[((size_t)b * N_ + w * QW + q) * DS + h * DH + d] = f2b(a);
    }
}

// ---------------------------------------------------------------------------
// Segment mean (sorted indices).
// ---------------------------------------------------------------------------
__global__ __launch_bounds__(128) void seg_kernel(
    const float* __restrict__ TOK, const int* __restrict__ idx,
    float* __restrict__ out)
{
    int t = blockIdx.x & (NT - 1);
    int b = blockIdx.x >> 10;
    const int* id = idx + (size_t)b * N_;

    int lo = 0, hi = N_;
    while (lo < hi) { int mid = (lo + hi) >> 1; if (id[mid] < t) lo = mid + 1; else hi = mid; }
    int start = lo;
    hi = N_;
    while (lo < hi) { int mid = (lo + hi) >> 1; if (id[mid] < t + 1) lo = mid + 1; else hi = mid; }
    int end = lo;

    float inv = 1.f / fmaxf((float)(end - start), 1.f);
    for (int c = threadIdx.x; c < DT; c += 128) {
        float s = 0.f;
        for (int r = start; r < end; ++r) s += TOK[((size_t)b * N_ + r) * DT + c];
        out[((size_t)b * NT + t) * DT + c] = s * inv;
    }
}

// ---------------------------------------------------------------------------
extern "C" void kernel_launch(void* const* d_in, const int* in_sizes, int n_in,
                              void* d_out, int out_size, void* d_ws, size_t ws_size,
                              hipStream_t stream)
{
    const float* ref_pos    = (const float*)d_in[0];
    const float* ref_charge = (const float*)d_in[1];
    const float* ref_mask   = (const float*)d_in[2];
    const float* ref_elem   = (const float*)d_in[3];
    const float* ref_chars  = (const float*)d_in[4];
    const float* W_single   = (const float*)d_in[5];
    const float* W_pair     = (const float*)d_in[6];
    const float* W_outer    = (const float*)d_in[7];
    const float* Wp_ff1     = (const float*)d_in[8];
    const float* Wp_ff2     = (const float*)d_in[9];
    const float* Wq         = (const float*)d_in[10];
    const float* Wk         = (const float*)d_in[11];
    const float* Wv         = (const float*)d_in[12];
    const float* Wo         = (const float*)d_in[13];
    const float* Wb         = (const float*)d_in[14];
    const float* Wff1       = (const float*)d_in[15];
    const float* Wff2       = (const float*)d_in[16];
    const float* W_out      = (const float*)d_in[17];
    const int*   uid        = (const int*)d_in[18];
    const int*   a2t        = (const int*)d_in[19];
    float* out = (float*)d_out;

    const size_t ROWS = (size_t)B_ * N_;  // 16384
    float* ws = (float*)d_ws;
    float* X    = ws;                              // 2,097,152 f
    float* H    = X + ROWS * DS;                   // 2,097,152 f
    float* P    = H + ROWS * DS;                   //   524,288 f
    float* BIAS = P + ROWS * 32;                   // 8,388,608 f
    float* TOK  = BIAS + (size_t)B_ * NWIN * HEADS * QW * KW;  // 6,291,456 f
    u16* QKVb = (u16*)(TOK + ROWS * DT);           // 6,291,456 u16
    u16* Ob   = QKVb + ROWS * 384;                 // 2,097,152 u16
    u16* FFb  = Ob + ROWS * DS;                    // 8,388,608 u16
    u16* qkvT = FFb + ROWS * 512;                  //   147,456 u16
    u16* woT  = qkvT + 3 * 384 * 128;              //    49,152 u16
    u16* ff1T = woT + 3 * 128 * 128;               //   196,608 u16
    u16* ff2T = ff1T + 3 * 512 * 128;              //   196,608 u16
    u16* woutT = ff2T + 3 * 128 * 512;             //    49,152 u16

    convw_kernel<<<768, 256, 0, stream>>>(Wq, Wk, Wv, Wo, Wff1, Wff2, W_out,
                                          qkvT, woT, ff1T, ff2T, woutT);
    embed_kernel<<<ROWS / 4, 128, 0, stream>>>(ref_pos, ref_charge, ref_mask,
                                               ref_elem, ref_chars, W_single,
                                               W_outer, X, P);
    bias_kernel<<<2048, 256, 0, stream>>>(ref_pos, uid, P, W_pair, Wp_ff1,
                                          Wp_ff2, Wb, BIAS);

    for (int l = 0; l < DEPTH; ++l) {
        ln_kernel<<<ROWS / 4, 256, 0, stream>>>(X, H);
        gemm_mfma<true, false, false, true><<<dim3(ROWS / 64, 3), 256, 0, stream>>>(
            H, qkvT + (size_t)l * 384 * 128, nullptr, QKVb, ROWS, DS, 384);
        attn_kernel<<<B_ * NWIN * HEADS, 256, 0, stream>>>(QKVb, BIAS, Ob);
        gemm_mfma<false, true, false, false><<<dim3(ROWS / 64, 1), 256, 0, stream>>>(
            Ob, woT + (size_t)l * 128 * 128, X, nullptr, ROWS, DS, DS);
        ln_kernel<<<ROWS / 4, 256, 0, stream>>>(X, H);
        gemm_mfma<true, false, true, true><<<dim3(ROWS / 64, 4), 256, 0, stream>>>(
            H, ff1T + (size_t)l * 512 * 128, nullptr, FFb, ROWS, DS, 512);
        gemm_mfma<false, true, false, false><<<dim3(ROWS / 64, 1), 256, 0, stream>>>(
            FFb, ff2T + (size_t)l * 128 * 512, X, nullptr, ROWS, 4 * DS, DS);
    }

    gemm_mfma<true, false, true, false><<<dim3(ROWS / 64, 3), 256, 0, stream>>>(
        X, woutT, TOK, nullptr, ROWS, DS, DT);
    seg_kernel<<<B_ * NT, 128, 0, stream>>>(TOK, a2t, out);
}

// Round 3
// 565.356 us; speedup vs baseline: 2.5822x; 1.4026x over previous
//
#include <hip/hip_runtime.h>
#include <hip/hip_bf16.h>

#define QW 64
#define KW 128
#define PADW 32
#define DEPTH 3
#define HEADS 4
#define B_ 2
#define N_ 8192
#define DS 128
#define DP 16
#define DT 384
#define NT 1024
#define NWIN (N_ / QW)   // 128
#define DH (DS / HEADS)  // 32

typedef unsigned short u16;
typedef __attribute__((ext_vector_type(8))) short short8;
typedef __attribute__((ext_vector_type(4))) float f32x4v;
typedef __attribute__((ext_vector_type(4))) unsigned short us4;

__device__ __forceinline__ u16 f2b(float x) {
    union { float f; unsigned u; } v; v.f = x;
    unsigned r = v.u + 0x7fffu + ((v.u >> 16) & 1u);
    return (u16)(r >> 16);
}
__device__ __forceinline__ float b2f(u16 h) {
    union { unsigned u; float f; } v; v.u = ((unsigned)h) << 16; return v.f;
}

// ---------------------------------------------------------------------------
// Weight prep: fp32 -> bf16, transposed [n][k] for MFMA B-frags. Also
// w1T32 = pair-MLP W1^T padded to K=32 (rows k>=16 zero) and
// w2bT  = (W2 @ Wb)^T padded to 16 heads (rows h>=4 zero).
// ---------------------------------------------------------------------------
__global__ __launch_bounds__(256) void convw_kernel(
    const float* __restrict__ Wq, const float* __restrict__ Wk,
    const float* __restrict__ Wv, const float* __restrict__ Wo,
    const float* __restrict__ Wff1, const float* __restrict__ Wff2,
    const float* __restrict__ Wout, const float* __restrict__ Wpff1,
    const float* __restrict__ Wpff2, const float* __restrict__ Wb,
    u16* __restrict__ qkvT, u16* __restrict__ woT, u16* __restrict__ ff1T,
    u16* __restrict__ ff2T, u16* __restrict__ woutT,
    u16* __restrict__ w1T32, u16* __restrict__ w2bT)
{
    int idx = blockIdx.x * 256 + threadIdx.x;
    if (idx < 3 * 384 * 128) {  // qkvT[l][n(384)][k(128)]
        int l = idx / (384 * 128), r = idx % (384 * 128);
        int n = r / 128, k = r % 128;
        const float* W = (n < 128) ? Wq : (n < 256) ? Wk : Wv;
        qkvT[idx] = f2b(W[(size_t)l * 16384 + k * 128 + (n & 127)]);
    }
    if (idx < 3 * 128 * 128) {  // woT[l][n][k]
        int l = idx / 16384, r = idx % 16384;
        int n = r / 128, k = r % 128;
        woT[idx] = f2b(Wo[(size_t)l * 16384 + k * 128 + n]);
    }
    if (idx < 3 * 512 * 128) {  // ff1T[l][n(512)][k(128)]
        int l = idx / 65536, r = idx % 65536;
        int n = r / 128, k = r % 128;
        ff1T[idx] = f2b(Wff1[(size_t)l * 65536 + k * 512 + n]);
    }
    if (idx < 3 * 128 * 512) {  // ff2T[l][n(128)][k(512)]
        int l = idx / 65536, r = idx % 65536;
        int n = r / 512, k = r % 512;
        ff2T[idx] = f2b(Wff2[(size_t)l * 65536 + k * 128 + n]);
    }
    if (idx < 384 * 128) {      // woutT[n(384)][k(128)]
        int n = idx / 128, k = idx % 128;
        woutT[idx] = f2b(Wout[(size_t)k * 384 + n]);
    }
    if (idx < 64 * 32) {        // w1T32[n(64)][k(32)], k>=16 zero
        int n = idx >> 5, k = idx & 31;
        w1T32[idx] = (k < 16) ? f2b(Wpff1[k * 64 + n]) : (u16)0;
    }
    if (idx < 16 * 64) {        // w2bT[h(16)][j(64)], h>=4 zero
        int h = idx >> 6, j = idx & 63;
        float s = 0.f;
        if (h < 4)
            for (int c = 0; c < 16; ++c) s += Wpff2[j * 16 + c] * Wb[c * 4 + h];
        w2bT[idx] = f2b(s);
    }
}

// ---------------------------------------------------------------------------
// Embed: s = feats @ W_single ; p = relu(s) @ W_outer  (fp32, unchanged)
// ---------------------------------------------------------------------------
__global__ __launch_bounds__(128) void embed_kernel(
    const float* __restrict__ pos, const float* __restrict__ charge,
    const float* __restrict__ mask, const float* __restrict__ elem,
    const float* __restrict__ chars, const float* __restrict__ Wsingle,
    const float* __restrict__ Wouter, float* __restrict__ X,
    float* __restrict__ P)
{
    const int ROWS = 4;
    __shared__ float sf[ROWS][392];
    __shared__ float srelu[ROWS][DS];
    int row0 = blockIdx.x * ROWS;
    int tid = threadIdx.x;

    for (int r = 0; r < ROWS; ++r) {
        int g = row0 + r;
        for (int c = tid; c < 389; c += 128) {
            float v;
            if (c < 3)        v = pos[g * 3 + c];
            else if (c == 3)  v = charge[g];
            else if (c == 4)  v = mask[g];
            else if (c < 133) v = elem[g * 128 + (c - 5)];
            else              v = chars[g * 256 + (c - 133)];
            sf[r][c] = v;
        }
    }
    __syncthreads();

    float acc[ROWS] = {0.f, 0.f, 0.f, 0.f};
    for (int c = 0; c < 389; ++c) {
        float w = Wsingle[c * DS + tid];
        #pragma unroll
        for (int r = 0; r < ROWS; ++r) acc[r] += sf[r][c] * w;
    }
    for (int r = 0; r < ROWS; ++r) {
        X[(size_t)(row0 + r) * DS + tid] = acc[r];
        srelu[r][tid] = fmaxf(acc[r], 0.f);
    }
    __syncthreads();

    int r = tid >> 5, e = tid & 31;
    float a = 0.f;
    for (int k = 0; k < DS; ++k) a += srelu[r][k] * Wouter[k * 32 + e];
    P[(size_t)(row0 + r) * 32 + e] = a;
}

// ---------------------------------------------------------------------------
// Bias kernel (MFMA MLP). Block = (b, w, qg): 8 q rows x 128 kk = 1024 cells.
// Phase 1 (VALU): pair features + LN -> lp (bf16, LDS) and pr@Wb (f32, LDS).
// Phase 2 (MFMA): relu(lp@W1) @ (W2@Wb), add pr@Wb, store bf16 BIAS.
// ---------------------------------------------------------------------------
__global__ __launch_bounds__(256) void bias_kernel(
    const float* __restrict__ pos, const int* __restrict__ uid,
    const float* __restrict__ P, const float* __restrict__ Wpair,
    const float* __restrict__ Wb, const u16* __restrict__ w1T32,
    const u16* __restrict__ w2bT, u16* __restrict__ BIASb)
{
    __shared__ u16 lpS[1024 * 16];      // [cell][16] bf16
    __shared__ float prWbS[1024 * 4];   // [cell][4]
    __shared__ u16 H1S[128 * 72];       // [cell_in_chunk][64] pad->72
    __shared__ float sWp[5 * 16];
    __shared__ float sWb[16 * 4];
    int tid = threadIdx.x;
    if (tid < 80) sWp[tid] = Wpair[tid];
    if (tid < 64) sWb[tid] = Wb[tid];

    int wv = tid >> 6, lane = tid & 63, quad = lane >> 4, l16 = lane & 15;
    // B-fragments (held in registers the whole kernel)
    short8 b1[4], b2[2];
    #pragma unroll
    for (int nt = 0; nt < 4; ++nt)
        b1[nt] = *(const short8*)&w1T32[(nt * 16 + l16) * 32 + quad * 8];
    #pragma unroll
    for (int ks = 0; ks < 2; ++ks)
        b2[ks] = *(const short8*)&w2bT[l16 * 64 + ks * 32 + quad * 8];
    __syncthreads();

    int b = blockIdx.x >> 10;
    int w = (blockIdx.x >> 3) & 127;
    int qg = blockIdx.x & 7;

    // ---------------- phase 1 ----------------
    int kk = tid & 127, tb = tid >> 7;
    int jk = w * QW + kk - PADW;
    bool valid = (jk >= 0) && (jk < N_);
    int gk = b * N_ + jk;
    float pxj = 0.f, pyj = 0.f, pzj = 0.f;
    int uj = 0;  // jnp.pad pads uid with 0
    float pj[16];
    #pragma unroll
    for (int c = 0; c < 16; ++c) pj[c] = 0.f;
    if (valid) {
        pxj = pos[gk * 3]; pyj = pos[gk * 3 + 1]; pzj = pos[gk * 3 + 2];
        uj = uid[gk];
        const f32x4v* Pj = (const f32x4v*)(P + (size_t)gk * 32 + 16);
        #pragma unroll
        for (int c4 = 0; c4 < 4; ++c4) {
            f32x4v t = Pj[c4];
            pj[c4 * 4] = t[0]; pj[c4 * 4 + 1] = t[1];
            pj[c4 * 4 + 2] = t[2]; pj[c4 * 4 + 3] = t[3];
        }
    }
    #pragma unroll
    for (int i = 0; i < 4; ++i) {
        int cell = i * 256 + tid;
        int ql = i * 2 + tb;
        int q = qg * 8 + ql;
        int gq = b * N_ + w * QW + q;
        float pxi = pos[gq * 3], pyi = pos[gq * 3 + 1], pzi = pos[gq * 3 + 2];
        int ui = uid[gq];
        float dx = pxi - pxj, dy = pyi - pyj, dz = pzi - pzj;
        float inv = 1.f / (1.f + dx * dx + dy * dy + dz * dz);
        float bf = (ui == uj) ? 1.f : 0.f;
        const f32x4v* Pi = (const f32x4v*)(P + (size_t)gq * 32);
        float pr[16];
        #pragma unroll
        for (int c4 = 0; c4 < 4; ++c4) {
            f32x4v t = Pi[c4];
            #pragma unroll
            for (int j = 0; j < 4; ++j) {
                int c = c4 * 4 + j;
                float tt = dx * sWp[c] + dy * sWp[16 + c] + dz * sWp[32 + c] +
                           inv * sWp[48 + c] + bf * sWp[64 + c];
                pr[c] = tt * bf + t[j] + pj[c];
            }
        }
        // pr @ Wb (residual part of bias head)
        float w0 = 0.f, w1 = 0.f, w2 = 0.f, w3 = 0.f;
        #pragma unroll
        for (int c = 0; c < 16; ++c) {
            w0 += pr[c] * sWb[c * 4 + 0];
            w1 += pr[c] * sWb[c * 4 + 1];
            w2 += pr[c] * sWb[c * 4 + 2];
            w3 += pr[c] * sWb[c * 4 + 3];
        }
        *(f32x4v*)&prWbS[cell * 4] = (f32x4v){w0, w1, w2, w3};
        // LayerNorm -> lp (bf16)
        float m = 0.f;
        #pragma unroll
        for (int c = 0; c < 16; ++c) m += pr[c];
        m *= (1.f / 16.f);
        float ss = 0.f;
        #pragma unroll
        for (int c = 0; c < 16; ++c) { float d = pr[c] - m; ss += d * d; }
        float rstd = rsqrtf(ss * (1.f / 16.f) + 1e-5f);
        short8 o;
        #pragma unroll
        for (int j = 0; j < 8; ++j) o[j] = (short)f2b((pr[j] - m) * rstd);
        *(short8*)&lpS[cell * 16] = o;
        #pragma unroll
        for (int j = 0; j < 8; ++j) o[j] = (short)f2b((pr[8 + j] - m) * rstd);
        *(short8*)&lpS[cell * 16 + 8] = o;
    }
    __syncthreads();

    // ---------------- phase 2 ----------------
    size_t bias_head_base = ((size_t)(b * NWIN + w) * HEADS) * (QW * KW);
    for (int c = 0; c < 8; ++c) {       // chunk = q row c, 128 cells, 8 tiles
        int q = qg * 8 + c;
        // MLP1: lp @ W1 -> relu -> H1S
        #pragma unroll
        for (int ti = 0; ti < 2; ++ti) {
            int t = wv * 2 + ti;
            int cellbase = c * 128 + t * 16;
            short8 a = *(short8*)&lpS[(cellbase + l16) * 16 + (quad & 1) * 8];
            #pragma unroll
            for (int nt = 0; nt < 4; ++nt) {
                f32x4v z = (f32x4v){0.f, 0.f, 0.f, 0.f};
                z = __builtin_amdgcn_mfma_f32_16x16x32_bf16(a, b1[nt], z, 0, 0, 0);
                #pragma unroll
                for (int r = 0; r < 4; ++r)
                    H1S[(t * 16 + quad * 4 + r) * 72 + nt * 16 + l16] =
                        f2b(fmaxf(z[r], 0.f));
            }
        }
        __syncthreads();
        // MLP2: H1 @ (W2@Wb), add pr@Wb, store
        #pragma unroll
        for (int ti = 0; ti < 2; ++ti) {
            int t = wv * 2 + ti;
            int cellbase = c * 128 + t * 16;
            f32x4v acc2 = (f32x4v){0.f, 0.f, 0.f, 0.f};
            #pragma unroll
            for (int ks = 0; ks < 2; ++ks) {
                short8 a2 = *(short8*)&H1S[(t * 16 + l16) * 72 + ks * 32 + quad * 8];
                acc2 = __builtin_amdgcn_mfma_f32_16x16x32_bf16(a2, b2[ks], acc2, 0, 0, 0);
            }
            if (l16 < 4) {
                us4 o;
                #pragma unroll
                for (int r = 0; r < 4; ++r) {
                    float v = acc2[r] + prWbS[(cellbase + quad * 4 + r) * 4 + l16];
                    o[r] = f2b(v);
                }
                *(us4*)&BIASb[bias_head_base + (size_t)l16 * (QW * KW) +
                              q * KW + t * 16 + quad * 4] = o;
            }
        }
        __syncthreads();
    }
}

// ---------------------------------------------------------------------------
// LN-fused MFMA GEMM: OutB[M,N] = (relu)(LN(X[M,128]) @ WT[N,128]^T), bf16 out
// Block 256 thr; tile 64(M)x128(N); wave tile 32x64.
// ---------------------------------------------------------------------------
template <bool RELU>
__global__ __launch_bounds__(256) void gemm_ln(
    const float* __restrict__ X, const u16* __restrict__ WT,
    u16* __restrict__ OutB, int N)
{
    __shared__ __align__(16) u16 As[64 * 152];
    int tid = threadIdx.x;
    int row0 = blockIdx.x * 64, n0 = blockIdx.y * 128;

    // LN staging: 4 threads per row, 32 cols each
    {
        int r = tid >> 2, cg = tid & 3;
        const float* xr = X + (size_t)(row0 + r) * 128 + cg * 32;
        f32x4v xv[8];
        float s = 0.f, ss = 0.f;
        #pragma unroll
        for (int i = 0; i < 8; ++i) {
            xv[i] = *(const f32x4v*)(xr + i * 4);
            #pragma unroll
            for (int j = 0; j < 4; ++j) { s += xv[i][j]; ss += xv[i][j] * xv[i][j]; }
        }
        s += __shfl_xor(s, 1); s += __shfl_xor(s, 2);
        ss += __shfl_xor(ss, 1); ss += __shfl_xor(ss, 2);
        float m = s * (1.f / 128.f);
        float var = ss * (1.f / 128.f) - m * m;
        float rs = rsqrtf(var + 1e-5f);
        #pragma unroll
        for (int i2 = 0; i2 < 4; ++i2) {
            short8 o;
            #pragma unroll
            for (int j = 0; j < 4; ++j) {
                o[j]     = (short)f2b((xv[i2 * 2][j] - m) * rs);
                o[4 + j] = (short)f2b((xv[i2 * 2 + 1][j] - m) * rs);
            }
            *(short8*)&As[r * 152 + cg * 32 + i2 * 8] = o;
        }
    }
    __syncthreads();

    int wv = tid >> 6, lane = tid & 63, quad = lane >> 4, l16 = lane & 15;
    int wm = (wv & 1) * 32, wn = (wv >> 1) * 64;
    f32x4v acc[2][4];
    #pragma unroll
    for (int i = 0; i < 2; ++i)
        #pragma unroll
        for (int j = 0; j < 4; ++j) acc[i][j] = (f32x4v){0.f, 0.f, 0.f, 0.f};

    #pragma unroll
    for (int kk = 0; kk < 4; ++kk) {
        short8 a0 = *(short8*)&As[(wm + l16) * 152 + kk * 32 + quad * 8];
        short8 a1 = *(short8*)&As[(wm + 16 + l16) * 152 + kk * 32 + quad * 8];
        #pragma unroll
        for (int nt = 0; nt < 4; ++nt) {
            short8 bw = *(const short8*)&WT[(size_t)(n0 + wn + nt * 16 + l16) * 128 +
                                            kk * 32 + quad * 8];
            acc[0][nt] = __builtin_amdgcn_mfma_f32_16x16x32_bf16(a0, bw, acc[0][nt], 0, 0, 0);
            acc[1][nt] = __builtin_amdgcn_mfma_f32_16x16x32_bf16(a1, bw, acc[1][nt], 0, 0, 0);
        }
    }
    #pragma unroll
    for (int mt = 0; mt < 2; ++mt)
        #pragma unroll
        for (int nt = 0; nt < 4; ++nt)
            #pragma unroll
            for (int r = 0; r < 4; ++r) {
                int row = row0 + wm + mt * 16 + quad * 4 + r;
                int col = n0 + wn + nt * 16 + l16;
                float v = acc[mt][nt][r];
                if (RELU) v = fmaxf(v, 0.f);
                OutB[(size_t)row * N + col] = f2b(v);
            }
}

// ---------------------------------------------------------------------------
// Generic MFMA GEMM (round-2, kept for WO / FF2 / final): fp32 out.
// ---------------------------------------------------------------------------
template <bool AF32, bool ADD, bool RELU>
__global__ __launch_bounds__(256) void gemm_mfma(
    const void* __restrict__ Ap, const u16* __restrict__ WT,
    float* __restrict__ OutF, int M, int K, int N)
{
    __shared__ __align__(16) u16 As[64 * 88];
    const int row0 = blockIdx.x * 64, n0 = blockIdx.y * 128;
    const int tid = threadIdx.x;
    const int w = tid >> 6, lane = tid & 63, quad = lane >> 4, l16 = lane & 15;
    const int wm = (w & 1) * 32, wn = (w >> 1) * 64;

    f32x4v acc[2][4];
    #pragma unroll
    for (int i = 0; i < 2; ++i)
        #pragma unroll
        for (int j = 0; j < 4; ++j) acc[i][j] = (f32x4v){0.f, 0.f, 0.f, 0.f};

    for (int k0 = 0; k0 < K; k0 += 64) {
        __syncthreads();
        if (AF32) {
            const float* A = (const float*)Ap;
            #pragma unroll
            for (int it = 0; it < 4; ++it) {
                int idx = tid + it * 256;
                int r = idx >> 4, c = idx & 15;
                f32x4v v = *(const f32x4v*)(A + (size_t)(row0 + r) * K + k0 + c * 4);
                us4 o = (us4){f2b(v[0]), f2b(v[1]), f2b(v[2]), f2b(v[3])};
                *(us4*)&As[r * 88 + c * 4] = o;
            }
        } else {
            const u16* A = (const u16*)Ap;
            #pragma unroll
            for (int it = 0; it < 2; ++it) {
                int idx = tid + it * 256;
                int r = idx >> 3, c = idx & 7;
                short8 v = *(const short8*)(A + (size_t)(row0 + r) * K + k0 + c * 8);
                *(short8*)&As[r * 88 + c * 8] = v;
            }
        }
        __syncthreads();
        #pragma unroll
        for (int kk = 0; kk < 64; kk += 32) {
            short8 a0 = *(const short8*)&As[(wm + l16) * 88 + kk + quad * 8];
            short8 a1 = *(const short8*)&As[(wm + 16 + l16) * 88 + kk + quad * 8];
            #pragma unroll
            for (int nt = 0; nt < 4; ++nt) {
                short8 b = *(const short8*)&WT[(size_t)(n0 + wn + nt * 16 + l16) * K + k0 + kk + quad * 8];
                acc[0][nt] = __builtin_amdgcn_mfma_f32_16x16x32_bf16(a0, b, acc[0][nt], 0, 0, 0);
                acc[1][nt] = __builtin_amdgcn_mfma_f32_16x16x32_bf16(a1, b, acc[1][nt], 0, 0, 0);
            }
        }
    }
    #pragma unroll
    for (int mt = 0; mt < 2; ++mt)
        #pragma unroll
        for (int nt = 0; nt < 4; ++nt)
            #pragma unroll
            for (int r = 0; r < 4; ++r) {
                int row = row0 + wm + mt * 16 + quad * 4 + r;
                int col = n0 + wn + nt * 16 + l16;
                size_t o = (size_t)row * N + col;
                float v = acc[mt][nt][r];
                if (RELU) v = fmaxf(v, 0.f);
                if (ADD) v += OutF[o];
                OutF[o] = v;
            }
}

// ---------------------------------------------------------------------------
// Windowed attention, MFMA. Block per (b, w, h), 256 thr = 4 waves.
// ---------------------------------------------------------------------------
__global__ __launch_bounds__(256) void attn_kernel(
    const u16* __restrict__ QKV, const u16* __restrict__ BIASb,
    u16* __restrict__ O)
{
    __shared__ __align__(16) u16 sQ[64 * 40];
    __shared__ __align__(16) u16 sK[128 * 40];
    __shared__ __align__(16) u16 sVt[32 * 152];
    __shared__ float sS[64 * 132];
    __shared__ __align__(16) u16 sP[64 * 152];

    int tid = threadIdx.x;
    int h = blockIdx.x & 3, w = (blockIdx.x >> 2) & 127, b = blockIdx.x >> 9;
    size_t rowbase = (size_t)b * N_ + w * QW;
    const short8 zero8 = (short8){0, 0, 0, 0, 0, 0, 0, 0};

    {   // Q: 64 rows x 32 d
        int r = tid >> 2, d8 = (tid & 3) * 8;
        *(short8*)&sQ[r * 40 + d8] =
            *(const short8*)&QKV[(rowbase + r) * 384 + h * DH + d8];
    }
    #pragma unroll
    for (int i = 0; i < 2; ++i) {  // K: 128 rows x 32 d
        int idx = tid + i * 256;
        int r = idx >> 2, d8 = (idx & 3) * 8;
        int jk = w * QW + r - PADW;
        short8 v = zero8;
        if (jk >= 0 && jk < N_)
            v = *(const short8*)&QKV[((size_t)b * N_ + jk) * 384 + 128 + h * DH + d8];
        *(short8*)&sK[r * 40 + d8] = v;
    }
    {   // V transposed: sVt[d][kk]
        int kk = tid >> 1, d0 = (tid & 1) * 16;
        int jk = w * QW + kk - PADW;
        short8 v0 = zero8, v1 = zero8;
        if (jk >= 0 && jk < N_) {
            const u16* src = &QKV[((size_t)b * N_ + jk) * 384 + 256 + h * DH + d0];
            v0 = *(const short8*)src;
            v1 = *(const short8*)(src + 8);
        }
        #pragma unroll
        for (int j = 0; j < 8; ++j) {
            sVt[(d0 + j) * 152 + kk] = (u16)v0[j];
            sVt[(d0 + 8 + j) * 152 + kk] = (u16)v1[j];
        }
    }
    __syncthreads();

    int wv = tid >> 6, lane = tid & 63, quad = lane >> 4, l16 = lane & 15;
    const float scale = 0.17677669529663687f;  // 1/sqrt(32)
    size_t bbase = ((size_t)(b * NWIN + w) * HEADS + h) * (QW * KW);

    // QK^T + bias + mask -> sS
    short8 aq[4];
    #pragma unroll
    for (int mt = 0; mt < 4; ++mt)
        aq[mt] = *(short8*)&sQ[(mt * 16 + l16) * 40 + quad * 8];
    #pragma unroll
    for (int ni = 0; ni < 2; ++ni) {
        int nt = wv * 2 + ni;
        short8 bk = *(short8*)&sK[(nt * 16 + l16) * 40 + quad * 8];
        int kk = nt * 16 + l16;
        int jk = w * QW + kk - PADW;
        float msk = (jk >= 0 && jk < N_) ? 0.f : -1e9f;
        #pragma unroll
        for (int mt = 0; mt < 4; ++mt) {
            f32x4v acc = (f32x4v){0.f, 0.f, 0.f, 0.f};
            acc = __builtin_amdgcn_mfma_f32_16x16x32_bf16(aq[mt], bk, acc, 0, 0, 0);
            #pragma unroll
            for (int r = 0; r < 4; ++r) {
                int q = mt * 16 + quad * 4 + r;
                float bias = b2f(BIASb[bbase + q * KW + kk]);
                sS[q * 132 + kk] = acc[r] * scale + bias + msk;
            }
        }
    }
    __syncthreads();

    {   // softmax: 4 threads per row, strided cols (bank-friendly)
        int row = tid >> 2, g = tid & 3;
        float v[32];
        float mx = -1e30f;
        #pragma unroll
        for (int k = 0; k < 32; ++k) {
            v[k] = sS[row * 132 + g + 4 * k];
            mx = fmaxf(mx, v[k]);
        }
        mx = fmaxf(mx, __shfl_xor(mx, 1));
        mx = fmaxf(mx, __shfl_xor(mx, 2));
        float s = 0.f;
        #pragma unroll
        for (int k = 0; k < 32; ++k) { v[k] = __expf(v[k] - mx); s += v[k]; }
        s += __shfl_xor(s, 1);
        s += __shfl_xor(s, 2);
        float inv = 1.f / s;
        #pragma unroll
        for (int k = 0; k < 32; ++k)
            sP[row * 152 + g + 4 * k] = f2b(v[k] * inv);
    }
    __syncthreads();

    {   // P @ V  (wave wv owns M-tile wv)
        int mt = wv;
        short8 ap[4];
        #pragma unroll
        for (int ks = 0; ks < 4; ++ks)
            ap[ks] = *(short8*)&sP[(mt * 16 + l16) * 152 + ks * 32 + quad * 8];
        #pragma unroll
        for (int nt = 0; nt < 2; ++nt) {
            f32x4v acc = (f32x4v){0.f, 0.f, 0.f, 0.f};
            #pragma unroll
            for (int ks = 0; ks < 4; ++ks) {
                short8 bv = *(short8*)&sVt[(nt * 16 + l16) * 152 + ks * 32 + quad * 8];
                acc = __builtin_amdgcn_mfma_f32_16x16x32_bf16(ap[ks], bv, acc, 0, 0, 0);
            }
            int d = nt * 16 + l16;
            #pragma unroll
            for (int r = 0; r < 4; ++r) {
                int q = mt * 16 + quad * 4 + r;
                O[(rowbase + q) * DS + h * DH + d] = f2b(acc[r]);
            }
        }
    }
}

// ---------------------------------------------------------------------------
// Segment mean (sorted indices).
// ---------------------------------------------------------------------------
__global__ __launch_bounds__(128) void seg_kernel(
    const float* __restrict__ TOK, const int* __restrict__ idx,
    float* __restrict__ out)
{
    int t = blockIdx.x & (NT - 1);
    int b = blockIdx.x >> 10;
    const int* id = idx + (size_t)b * N_;

    int lo = 0, hi = N_;
    while (lo < hi) { int mid = (lo + hi) >> 1; if (id[mid] < t) lo = mid + 1; else hi = mid; }
    int start = lo;
    hi = N_;
    while (lo < hi) { int mid = (lo + hi) >> 1; if (id[mid] < t + 1) lo = mid + 1; else hi = mid; }
    int end = lo;

    float inv = 1.f / fmaxf((float)(end - start), 1.f);
    for (int c = threadIdx.x; c < DT; c += 128) {
        float s = 0.f;
        for (int r = start; r < end; ++r) s += TOK[((size_t)b * N_ + r) * DT + c];
        out[((size_t)b * NT + t) * DT + c] = s * inv;
    }
}

// ---------------------------------------------------------------------------
extern "C" void kernel_launch(void* const* d_in, const int* in_sizes, int n_in,
                              void* d_out, int out_size, void* d_ws, size_t ws_size,
                              hipStream_t stream)
{
    const float* ref_pos    = (const float*)d_in[0];
    const float* ref_charge = (const float*)d_in[1];
    const float* ref_mask   = (const float*)d_in[2];
    const float* ref_elem   = (const float*)d_in[3];
    const float* ref_chars  = (const float*)d_in[4];
    const float* W_single   = (const float*)d_in[5];
    const float* W_pair     = (const float*)d_in[6];
    const float* W_outer    = (const float*)d_in[7];
    const float* Wp_ff1     = (const float*)d_in[8];
    const float* Wp_ff2     = (const float*)d_in[9];
    const float* Wq         = (const float*)d_in[10];
    const float* Wk         = (const float*)d_in[11];
    const float* Wv         = (const float*)d_in[12];
    const float* Wo         = (const float*)d_in[13];
    const float* Wb         = (const float*)d_in[14];
    const float* Wff1       = (const float*)d_in[15];
    const float* Wff2       = (const float*)d_in[16];
    const float* W_out      = (const float*)d_in[17];
    const int*   uid        = (const int*)d_in[18];
    const int*   a2t        = (const int*)d_in[19];
    float* out = (float*)d_out;

    const size_t ROWS = (size_t)B_ * N_;  // 16384
    float* ws = (float*)d_ws;
    float* X    = ws;                          // 2,097,152 f
    float* P    = X + ROWS * DS;               //   524,288 f
    float* TOK  = P + ROWS * 32;               // 6,291,456 f
    u16* QKVb  = (u16*)(TOK + ROWS * DT);      // 6,291,456 u16
    u16* Ob    = QKVb + ROWS * 384;            // 2,097,152
    u16* FFb   = Ob + ROWS * DS;               // 8,388,608
    u16* BIASb = FFb + ROWS * 512;             // 8,388,608
    u16* qkvT  = BIASb + (size_t)B_ * NWIN * HEADS * QW * KW;
    u16* woT   = qkvT + 3 * 384 * 128;
    u16* ff1T  = woT + 3 * 128 * 128;
    u16* ff2T  = ff1T + 3 * 512 * 128;
    u16* woutT = ff2T + 3 * 128 * 512;
    u16* w1T32 = woutT + 384 * 128;
    u16* w2bT  = w1T32 + 64 * 32;

    convw_kernel<<<768, 256, 0, stream>>>(Wq, Wk, Wv, Wo, Wff1, Wff2, W_out,
                                          Wp_ff1, Wp_ff2, Wb,
                                          qkvT, woT, ff1T, ff2T, woutT,
                                          w1T32, w2bT);
    embed_kernel<<<ROWS / 4, 128, 0, stream>>>(ref_pos, ref_charge, ref_mask,
                                               ref_elem, ref_chars, W_single,
                                               W_outer, X, P);
    bias_kernel<<<2048, 256, 0, stream>>>(ref_pos, uid, P, W_pair, Wb,
                                          w1T32, w2bT, BIASb);

    for (int l = 0; l < DEPTH; ++l) {
        gemm_ln<false><<<dim3(ROWS / 64, 3), 256, 0, stream>>>(
            X, qkvT + (size_t)l * 384 * 128, QKVb, 384);
        attn_kernel<<<B_ * NWIN * HEADS, 256, 0, stream>>>(QKVb, BIASb, Ob);
        gemm_mfma<false, true, false><<<dim3(ROWS / 64, 1), 256, 0, stream>>>(
            Ob, woT + (size_t)l * 128 * 128, X, ROWS, DS, DS);
        gemm_ln<true><<<dim3(ROWS / 64, 4), 256, 0, stream>>>(
            X, ff1T + (size_t)l * 512 * 128, FFb, 512);
        gemm_mfma<false, true, false><<<dim3(ROWS / 64, 1), 256, 0, stream>>>(
            FFb, ff2T + (size_t)l * 128 * 512, X, ROWS, 4 * DS, DS);
    }

    gemm_mfma<true, false, true><<<dim3(ROWS / 64, 3), 256, 0, stream>>>(
        X, woutT, TOK, ROWS, DS, DT);
    seg_kernel<<<B_ * NT, 128, 0, stream>>>(TOK, a2t, out);
}

// Round 4
// 558.846 us; speedup vs baseline: 2.6123x; 1.0116x over previous
//
#include <hip/hip_runtime.h>
#include <hip/hip_bf16.h>

#define QW 64
#define KW 128
#define PADW 32
#define DEPTH 3
#define HEADS 4
#define B_ 2
#define N_ 8192
#define DS 128
#define DP 16
#define DT 384
#define NT 1024
#define NWIN (N_ / QW)   // 128
#define DH (DS / HEADS)  // 32

typedef unsigned short u16;
typedef __attribute__((ext_vector_type(8))) short short8;
typedef __attribute__((ext_vector_type(4))) float f32x4v;
typedef __attribute__((ext_vector_type(4))) unsigned short us4;

__device__ __forceinline__ u16 f2b(float x) {
    union { float f; unsigned u; } v; v.f = x;
    unsigned r = v.u + 0x7fffu + ((v.u >> 16) & 1u);
    return (u16)(r >> 16);
}
__device__ __forceinline__ float b2f(u16 h) {
    union { unsigned u; float f; } v; v.u = ((unsigned)h) << 16; return v.f;
}

// ---------------------------------------------------------------------------
// Weight prep: fp32 -> bf16, transposed [n][k] for MFMA B-frags. Also
// w1T32 = pair-MLP W1^T padded to K=32 (rows k>=16 zero) and
// w2bT  = (W2 @ Wb)^T padded to 16 heads (rows h>=4 zero).
// ---------------------------------------------------------------------------
__global__ __launch_bounds__(256) void convw_kernel(
    const float* __restrict__ Wq, const float* __restrict__ Wk,
    const float* __restrict__ Wv, const float* __restrict__ Wo,
    const float* __restrict__ Wff1, const float* __restrict__ Wff2,
    const float* __restrict__ Wout, const float* __restrict__ Wpff1,
    const float* __restrict__ Wpff2, const float* __restrict__ Wb,
    u16* __restrict__ qkvT, u16* __restrict__ woT, u16* __restrict__ ff1T,
    u16* __restrict__ ff2T, u16* __restrict__ woutT,
    u16* __restrict__ w1T32, u16* __restrict__ w2bT)
{
    int idx = blockIdx.x * 256 + threadIdx.x;
    if (idx < 3 * 384 * 128) {  // qkvT[l][n(384)][k(128)]
        int l = idx / (384 * 128), r = idx % (384 * 128);
        int n = r / 128, k = r % 128;
        const float* W = (n < 128) ? Wq : (n < 256) ? Wk : Wv;
        qkvT[idx] = f2b(W[(size_t)l * 16384 + k * 128 + (n & 127)]);
    }
    if (idx < 3 * 128 * 128) {  // woT[l][n][k]
        int l = idx / 16384, r = idx % 16384;
        int n = r / 128, k = r % 128;
        woT[idx] = f2b(Wo[(size_t)l * 16384 + k * 128 + n]);
    }
    if (idx < 3 * 512 * 128) {  // ff1T[l][n(512)][k(128)]
        int l = idx / 65536, r = idx % 65536;
        int n = r / 128, k = r % 128;
        ff1T[idx] = f2b(Wff1[(size_t)l * 65536 + k * 512 + n]);
    }
    if (idx < 3 * 128 * 512) {  // ff2T[l][n(128)][k(512)]
        int l = idx / 65536, r = idx % 65536;
        int n = r / 512, k = r % 512;
        ff2T[idx] = f2b(Wff2[(size_t)l * 65536 + k * 128 + n]);
    }
    if (idx < 384 * 128) {      // woutT[n(384)][k(128)]
        int n = idx / 128, k = idx % 128;
        woutT[idx] = f2b(Wout[(size_t)k * 384 + n]);
    }
    if (idx < 64 * 32) {        // w1T32[n(64)][k(32)], k>=16 zero
        int n = idx >> 5, k = idx & 31;
        w1T32[idx] = (k < 16) ? f2b(Wpff1[k * 64 + n]) : (u16)0;
    }
    if (idx < 16 * 64) {        // w2bT[h(16)][j(64)], h>=4 zero
        int h = idx >> 6, j = idx & 63;
        float s = 0.f;
        if (h < 4)
            for (int c = 0; c < 16; ++c) s += Wpff2[j * 16 + c] * Wb[c * 4 + h];
        w2bT[idx] = f2b(s);
    }
}

// ---------------------------------------------------------------------------
// Embed: s = feats @ W_single ; p = relu(s) @ W_outer  (fp32)
// ---------------------------------------------------------------------------
__global__ __launch_bounds__(128) void embed_kernel(
    const float* __restrict__ pos, const float* __restrict__ charge,
    const float* __restrict__ mask, const float* __restrict__ elem,
    const float* __restrict__ chars, const float* __restrict__ Wsingle,
    const float* __restrict__ Wouter, float* __restrict__ X,
    float* __restrict__ P)
{
    const int ROWS = 4;
    __shared__ float sf[ROWS][392];
    __shared__ float srelu[ROWS][DS];
    int row0 = blockIdx.x * ROWS;
    int tid = threadIdx.x;

    for (int r = 0; r < ROWS; ++r) {
        int g = row0 + r;
        for (int c = tid; c < 389; c += 128) {
            float v;
            if (c < 3)        v = pos[g * 3 + c];
            else if (c == 3)  v = charge[g];
            else if (c == 4)  v = mask[g];
            else if (c < 133) v = elem[g * 128 + (c - 5)];
            else              v = chars[g * 256 + (c - 133)];
            sf[r][c] = v;
        }
    }
    __syncthreads();

    float acc[ROWS] = {0.f, 0.f, 0.f, 0.f};
    for (int c = 0; c < 389; ++c) {
        float w = Wsingle[c * DS + tid];
        #pragma unroll
        for (int r = 0; r < ROWS; ++r) acc[r] += sf[r][c] * w;
    }
    for (int r = 0; r < ROWS; ++r) {
        X[(size_t)(row0 + r) * DS + tid] = acc[r];
        srelu[r][tid] = fmaxf(acc[r], 0.f);
    }
    __syncthreads();

    int r = tid >> 5, e = tid & 31;
    float a = 0.f;
    for (int k = 0; k < DS; ++k) a += srelu[r][k] * Wouter[k * 32 + e];
    P[(size_t)(row0 + r) * 32 + e] = a;
}

// ---------------------------------------------------------------------------
// Bias kernel v3. Block = (b, w, qg): 4 q rows x 128 kk = 512 cells.
// Phase 1 (VALU): pair features + LN -> lp bf16 (LDS), pr@Wb f32 (LDS).
// Phase 2 (MFMA, barrier-free): wave wv owns q-row wv (128 cells, 8 tiles).
//   MLP1 swapped operands: A=W1^T (M=j), B=lp (N=cells) -> C rows=j, cols=cell
//   -> relu packs 4 contiguous j per lane -> ONE ds_write_b64 per N-tile.
//   MLP2: A=H1[cell][j], B=(W2@Wb)^T -> bias heads, packed us4 global store.
// ---------------------------------------------------------------------------
__global__ __launch_bounds__(256) void bias_kernel(
    const float* __restrict__ pos, const int* __restrict__ uid,
    const float* __restrict__ P, const float* __restrict__ Wpair,
    const float* __restrict__ Wb, const u16* __restrict__ w1T32,
    const u16* __restrict__ w2bT, u16* __restrict__ BIASb)
{
    __shared__ __align__(16) u16 lpS[512 * 16];     // 16 KB
    __shared__ __align__(16) float prWbS[512 * 4];  // 8 KB
    __shared__ __align__(16) u16 H1S[4][16 * 72];   // 9 KB (per-wave scratch)
    __shared__ float sWp[80];
    __shared__ float sWb[64];
    int tid = threadIdx.x;
    if (tid < 80) sWp[tid] = Wpair[tid];
    if (tid < 64) sWb[tid] = Wb[tid];

    int wv = tid >> 6, lane = tid & 63, quad = lane >> 4, l16 = lane & 15;
    // weight fragments in registers for the whole kernel
    short8 w1f[4], b2[2];
    #pragma unroll
    for (int nt = 0; nt < 4; ++nt)
        w1f[nt] = *(const short8*)&w1T32[(nt * 16 + l16) * 32 + quad * 8];
    #pragma unroll
    for (int ks = 0; ks < 2; ++ks)
        b2[ks] = *(const short8*)&w2bT[l16 * 64 + ks * 32 + quad * 8];
    __syncthreads();

    int b  = blockIdx.x >> 11;          // 4096 blocks: b(2) x w(128) x qg(16)
    int w  = (blockIdx.x >> 4) & 127;
    int qg = blockIdx.x & 15;

    // ---------------- phase 1: 2 cells per thread (same kk) ----------------
    {
        int kk = tid & 127;
        int jk = w * QW + kk - PADW;
        bool valid = (jk >= 0) && (jk < N_);
        int gk = b * N_ + jk;
        float pxj = 0.f, pyj = 0.f, pzj = 0.f;
        int uj = 0;  // jnp.pad pads uid with 0
        float pj[16];
        #pragma unroll
        for (int c = 0; c < 16; ++c) pj[c] = 0.f;
        if (valid) {
            pxj = pos[gk * 3]; pyj = pos[gk * 3 + 1]; pzj = pos[gk * 3 + 2];
            uj = uid[gk];
            const f32x4v* Pj = (const f32x4v*)(P + (size_t)gk * 32 + 16);
            #pragma unroll
            for (int c4 = 0; c4 < 4; ++c4) {
                f32x4v t = Pj[c4];
                pj[c4 * 4] = t[0]; pj[c4 * 4 + 1] = t[1];
                pj[c4 * 4 + 2] = t[2]; pj[c4 * 4 + 3] = t[3];
            }
        }
        #pragma unroll
        for (int i = 0; i < 2; ++i) {
            int cell = tid + i * 256;
            int ql = cell >> 7;
            int q = qg * 4 + ql;
            int gq = b * N_ + w * QW + q;
            float pxi = pos[gq * 3], pyi = pos[gq * 3 + 1], pzi = pos[gq * 3 + 2];
            int ui = uid[gq];
            float dx = pxi - pxj, dy = pyi - pyj, dz = pzi - pzj;
            float inv = 1.f / (1.f + dx * dx + dy * dy + dz * dz);
            float bf = (ui == uj) ? 1.f : 0.f;
            const f32x4v* Pi = (const f32x4v*)(P + (size_t)gq * 32);
            float pr[16];
            #pragma unroll
            for (int c4 = 0; c4 < 4; ++c4) {
                f32x4v t = Pi[c4];
                #pragma unroll
                for (int j = 0; j < 4; ++j) {
                    int c = c4 * 4 + j;
                    float tt = dx * sWp[c] + dy * sWp[16 + c] + dz * sWp[32 + c] +
                               inv * sWp[48 + c] + bf * sWp[64 + c];
                    pr[c] = tt * bf + t[j] + pj[c];
                }
            }
            float w0 = 0.f, w1 = 0.f, w2 = 0.f, w3 = 0.f;
            #pragma unroll
            for (int c = 0; c < 16; ++c) {
                w0 += pr[c] * sWb[c * 4 + 0];
                w1 += pr[c] * sWb[c * 4 + 1];
                w2 += pr[c] * sWb[c * 4 + 2];
                w3 += pr[c] * sWb[c * 4 + 3];
            }
            *(f32x4v*)&prWbS[cell * 4] = (f32x4v){w0, w1, w2, w3};
            float m = 0.f;
            #pragma unroll
            for (int c = 0; c < 16; ++c) m += pr[c];
            m *= (1.f / 16.f);
            float ss = 0.f;
            #pragma unroll
            for (int c = 0; c < 16; ++c) { float d = pr[c] - m; ss += d * d; }
            float rstd = rsqrtf(ss * (1.f / 16.f) + 1e-5f);
            short8 o;
            #pragma unroll
            for (int j = 0; j < 8; ++j) o[j] = (short)f2b((pr[j] - m) * rstd);
            *(short8*)&lpS[cell * 16] = o;
            #pragma unroll
            for (int j = 0; j < 8; ++j) o[j] = (short)f2b((pr[8 + j] - m) * rstd);
            *(short8*)&lpS[cell * 16 + 8] = o;
        }
    }
    __syncthreads();

    // ---------------- phase 2 (no barriers) ----------------
    size_t bbase = ((size_t)(b * NWIN + w) * HEADS) * (QW * KW);
    int q = qg * 4 + wv;
    u16* H1 = H1S[wv];
    const short8 zero8 = (short8){0, 0, 0, 0, 0, 0, 0, 0};

    for (int t = 0; t < 8; ++t) {
        int cb = wv * 128 + t * 16;
        // B1 fragment: lp[cell][k], quads 2,3 are the K-padding (zero)
        short8 blp = zero8;
        if (quad < 2) blp = *(short8*)&lpS[(cb + l16) * 16 + quad * 8];
        // MLP1: C rows = j, cols = cell -> pack 4 j per lane, b64 store
        #pragma unroll
        for (int nt = 0; nt < 4; ++nt) {
            f32x4v z = (f32x4v){0.f, 0.f, 0.f, 0.f};
            z = __builtin_amdgcn_mfma_f32_16x16x32_bf16(w1f[nt], blp, z, 0, 0, 0);
            us4 o;
            #pragma unroll
            for (int r = 0; r < 4; ++r) o[r] = f2b(fmaxf(z[r], 0.f));
            *(us4*)&H1[l16 * 72 + nt * 16 + quad * 4] = o;
        }
        // MLP2: A = H1[cell][j], B = (W2@Wb)^T
        f32x4v acc2 = (f32x4v){0.f, 0.f, 0.f, 0.f};
        #pragma unroll
        for (int ks = 0; ks < 2; ++ks) {
            short8 a2 = *(short8*)&H1[l16 * 72 + ks * 32 + quad * 8];
            acc2 = __builtin_amdgcn_mfma_f32_16x16x32_bf16(a2, b2[ks], acc2, 0, 0, 0);
        }
        if (l16 < 4) {
            us4 o;
            #pragma unroll
            for (int r = 0; r < 4; ++r)
                o[r] = f2b(acc2[r] + prWbS[(cb + quad * 4 + r) * 4 + l16]);
            *(us4*)&BIASb[bbase + (size_t)l16 * (QW * KW) + q * KW +
                          t * 16 + quad * 4] = o;
        }
    }
}

// ---------------------------------------------------------------------------
// LN-fused MFMA GEMM: OutB[M,N] = (relu)(LN(X[M,128]) @ WT[N,128]^T), bf16 out
// ---------------------------------------------------------------------------
template <bool RELU>
__global__ __launch_bounds__(256) void gemm_ln(
    const float* __restrict__ X, const u16* __restrict__ WT,
    u16* __restrict__ OutB, int N)
{
    __shared__ __align__(16) u16 As[64 * 152];
    int tid = threadIdx.x;
    int row0 = blockIdx.x * 64, n0 = blockIdx.y * 128;

    {
        int r = tid >> 2, cg = tid & 3;
        const float* xr = X + (size_t)(row0 + r) * 128 + cg * 32;
        f32x4v xv[8];
        float s = 0.f, ss = 0.f;
        #pragma unroll
        for (int i = 0; i < 8; ++i) {
            xv[i] = *(const f32x4v*)(xr + i * 4);
            #pragma unroll
            for (int j = 0; j < 4; ++j) { s += xv[i][j]; ss += xv[i][j] * xv[i][j]; }
        }
        s += __shfl_xor(s, 1); s += __shfl_xor(s, 2);
        ss += __shfl_xor(ss, 1); ss += __shfl_xor(ss, 2);
        float m = s * (1.f / 128.f);
        float var = ss * (1.f / 128.f) - m * m;
        float rs = rsqrtf(var + 1e-5f);
        #pragma unroll
        for (int i2 = 0; i2 < 4; ++i2) {
            short8 o;
            #pragma unroll
            for (int j = 0; j < 4; ++j) {
                o[j]     = (short)f2b((xv[i2 * 2][j] - m) * rs);
                o[4 + j] = (short)f2b((xv[i2 * 2 + 1][j] - m) * rs);
            }
            *(short8*)&As[r * 152 + cg * 32 + i2 * 8] = o;
        }
    }
    __syncthreads();

    int wv = tid >> 6, lane = tid & 63, quad = lane >> 4, l16 = lane & 15;
    int wm = (wv & 1) * 32, wn = (wv >> 1) * 64;
    f32x4v acc[2][4];
    #pragma unroll
    for (int i = 0; i < 2; ++i)
        #pragma unroll
        for (int j = 0; j < 4; ++j) acc[i][j] = (f32x4v){0.f, 0.f, 0.f, 0.f};

    #pragma unroll
    for (int kk = 0; kk < 4; ++kk) {
        short8 a0 = *(short8*)&As[(wm + l16) * 152 + kk * 32 + quad * 8];
        short8 a1 = *(short8*)&As[(wm + 16 + l16) * 152 + kk * 32 + quad * 8];
        #pragma unroll
        for (int nt = 0; nt < 4; ++nt) {
            short8 bw = *(const short8*)&WT[(size_t)(n0 + wn + nt * 16 + l16) * 128 +
                                            kk * 32 + quad * 8];
            acc[0][nt] = __builtin_amdgcn_mfma_f32_16x16x32_bf16(a0, bw, acc[0][nt], 0, 0, 0);
            acc[1][nt] = __builtin_amdgcn_mfma_f32_16x16x32_bf16(a1, bw, acc[1][nt], 0, 0, 0);
        }
    }
    #pragma unroll
    for (int mt = 0; mt < 2; ++mt)
        #pragma unroll
        for (int nt = 0; nt < 4; ++nt)
            #pragma unroll
            for (int r = 0; r < 4; ++r) {
                int row = row0 + wm + mt * 16 + quad * 4 + r;
                int col = n0 + wn + nt * 16 + l16;
                float v = acc[mt][nt][r];
                if (RELU) v = fmaxf(v, 0.f);
                OutB[(size_t)row * N + col] = f2b(v);
            }
}

// ---------------------------------------------------------------------------
// Generic MFMA GEMM (WO / FF2 / final): fp32 out.
// ---------------------------------------------------------------------------
template <bool AF32, bool ADD, bool RELU>
__global__ __launch_bounds__(256) void gemm_mfma(
    const void* __restrict__ Ap, const u16* __restrict__ WT,
    float* __restrict__ OutF, int M, int K, int N)
{
    __shared__ __align__(16) u16 As[64 * 88];
    const int row0 = blockIdx.x * 64, n0 = blockIdx.y * 128;
    const int tid = threadIdx.x;
    const int w = tid >> 6, lane = tid & 63, quad = lane >> 4, l16 = lane & 15;
    const int wm = (w & 1) * 32, wn = (w >> 1) * 64;

    f32x4v acc[2][4];
    #pragma unroll
    for (int i = 0; i < 2; ++i)
        #pragma unroll
        for (int j = 0; j < 4; ++j) acc[i][j] = (f32x4v){0.f, 0.f, 0.f, 0.f};

    for (int k0 = 0; k0 < K; k0 += 64) {
        __syncthreads();
        if (AF32) {
            const float* A = (const float*)Ap;
            #pragma unroll
            for (int it = 0; it < 4; ++it) {
                int idx = tid + it * 256;
                int r = idx >> 4, c = idx & 15;
                f32x4v v = *(const f32x4v*)(A + (size_t)(row0 + r) * K + k0 + c * 4);
                us4 o = (us4){f2b(v[0]), f2b(v[1]), f2b(v[2]), f2b(v[3])};
                *(us4*)&As[r * 88 + c * 4] = o;
            }
        } else {
            const u16* A = (const u16*)Ap;
            #pragma unroll
            for (int it = 0; it < 2; ++it) {
                int idx = tid + it * 256;
                int r = idx >> 3, c = idx & 7;
                short8 v = *(const short8*)(A + (size_t)(row0 + r) * K + k0 + c * 8);
                *(short8*)&As[r * 88 + c * 8] = v;
            }
        }
        __syncthreads();
        #pragma unroll
        for (int kk = 0; kk < 64; kk += 32) {
            short8 a0 = *(const short8*)&As[(wm + l16) * 88 + kk + quad * 8];
            short8 a1 = *(const short8*)&As[(wm + 16 + l16) * 88 + kk + quad * 8];
            #pragma unroll
            for (int nt = 0; nt < 4; ++nt) {
                short8 b = *(const short8*)&WT[(size_t)(n0 + wn + nt * 16 + l16) * K + k0 + kk + quad * 8];
                acc[0][nt] = __builtin_amdgcn_mfma_f32_16x16x32_bf16(a0, b, acc[0][nt], 0, 0, 0);
                acc[1][nt] = __builtin_amdgcn_mfma_f32_16x16x32_bf16(a1, b, acc[1][nt], 0, 0, 0);
            }
        }
    }
    #pragma unroll
    for (int mt = 0; mt < 2; ++mt)
        #pragma unroll
        for (int nt = 0; nt < 4; ++nt)
            #pragma unroll
            for (int r = 0; r < 4; ++r) {
                int row = row0 + wm + mt * 16 + quad * 4 + r;
                int col = n0 + wn + nt * 16 + l16;
                size_t o = (size_t)row * N + col;
                float v = acc[mt][nt][r];
                if (RELU) v = fmaxf(v, 0.f);
                if (ADD) v += OutF[o];
                OutF[o] = v;
            }
}

// ---------------------------------------------------------------------------
// Windowed attention, MFMA. Block per (b, w, h), 256 thr = 4 waves.
// ---------------------------------------------------------------------------
__global__ __launch_bounds__(256) void attn_kernel(
    const u16* __restrict__ QKV, const u16* __restrict__ BIASb,
    u16* __restrict__ O)
{
    __shared__ __align__(16) u16 sQ[64 * 40];
    __shared__ __align__(16) u16 sK[128 * 40];
    __shared__ __align__(16) u16 sVt[32 * 152];
    __shared__ float sS[64 * 132];
    __shared__ __align__(16) u16 sP[64 * 152];

    int tid = threadIdx.x;
    int h = blockIdx.x & 3, w = (blockIdx.x >> 2) & 127, b = blockIdx.x >> 9;
    size_t rowbase = (size_t)b * N_ + w * QW;
    const short8 zero8 = (short8){0, 0, 0, 0, 0, 0, 0, 0};

    {   // Q: 64 rows x 32 d
        int r = tid >> 2, d8 = (tid & 3) * 8;
        *(short8*)&sQ[r * 40 + d8] =
            *(const short8*)&QKV[(rowbase + r) * 384 + h * DH + d8];
    }
    #pragma unroll
    for (int i = 0; i < 2; ++i) {  // K: 128 rows x 32 d
        int idx = tid + i * 256;
        int r = idx >> 2, d8 = (idx & 3) * 8;
        int jk = w * QW + r - PADW;
        short8 v = zero8;
        if (jk >= 0 && jk < N_)
            v = *(const short8*)&QKV[((size_t)b * N_ + jk) * 384 + 128 + h * DH + d8];
        *(short8*)&sK[r * 40 + d8] = v;
    }
    {   // V transposed: sVt[d][kk]
        int kk = tid >> 1, d0 = (tid & 1) * 16;
        int jk = w * QW + kk - PADW;
        short8 v0 = zero8, v1 = zero8;
        if (jk >= 0 && jk < N_) {
            const u16* src = &QKV[((size_t)b * N_ + jk) * 384 + 256 + h * DH + d0];
            v0 = *(const short8*)src;
            v1 = *(const short8*)(src + 8);
        }
        #pragma unroll
        for (int j = 0; j < 8; ++j) {
            sVt[(d0 + j) * 152 + kk] = (u16)v0[j];
            sVt[(d0 + 8 + j) * 152 + kk] = (u16)v1[j];
        }
    }
    __syncthreads();

    int wv = tid >> 6, lane = tid & 63, quad = lane >> 4, l16 = lane & 15;
    const float scale = 0.17677669529663687f;  // 1/sqrt(32)
    size_t bbase = ((size_t)(b * NWIN + w) * HEADS + h) * (QW * KW);

    short8 aq[4];
    #pragma unroll
    for (int mt = 0; mt < 4; ++mt)
        aq[mt] = *(short8*)&sQ[(mt * 16 + l16) * 40 + quad * 8];
    #pragma unroll
    for (int ni = 0; ni < 2; ++ni) {
        int nt = wv * 2 + ni;
        short8 bk = *(short8*)&sK[(nt * 16 + l16) * 40 + quad * 8];
        int kk = nt * 16 + l16;
        int jk = w * QW + kk - PADW;
        float msk = (jk >= 0 && jk < N_) ? 0.f : -1e9f;
        #pragma unroll
        for (int mt = 0; mt < 4; ++mt) {
            f32x4v acc = (f32x4v){0.f, 0.f, 0.f, 0.f};
            acc = __builtin_amdgcn_mfma_f32_16x16x32_bf16(aq[mt], bk, acc, 0, 0, 0);
            #pragma unroll
            for (int r = 0; r < 4; ++r) {
                int q = mt * 16 + quad * 4 + r;
                float bias = b2f(BIASb[bbase + q * KW + kk]);
                sS[q * 132 + kk] = acc[r] * scale + bias + msk;
            }
        }
    }
    __syncthreads();

    {   // softmax: 4 threads per row
        int row = tid >> 2, g = tid & 3;
        float v[32];
        float mx = -1e30f;
        #pragma unroll
        for (int k = 0; k < 32; ++k) {
            v[k] = sS[row * 132 + g + 4 * k];
            mx = fmaxf(mx, v[k]);
        }
        mx = fmaxf(mx, __shfl_xor(mx, 1));
        mx = fmaxf(mx, __shfl_xor(mx, 2));
        float s = 0.f;
        #pragma unroll
        for (int k = 0; k < 32; ++k) { v[k] = __expf(v[k] - mx); s += v[k]; }
        s += __shfl_xor(s, 1);
        s += __shfl_xor(s, 2);
        float inv = 1.f / s;
        #pragma unroll
        for (int k = 0; k < 32; ++k)
            sP[row * 152 + g + 4 * k] = f2b(v[k] * inv);
    }
    __syncthreads();

    {   // P @ V
        int mt = wv;
        short8 ap[4];
        #pragma unroll
        for (int ks = 0; ks < 4; ++ks)
            ap[ks] = *(short8*)&sP[(mt * 16 + l16) * 152 + ks * 32 + quad * 8];
        #pragma unroll
        for (int nt = 0; nt < 2; ++nt) {
            f32x4v acc = (f32x4v){0.f, 0.f, 0.f, 0.f};
            #pragma unroll
            for (int ks = 0; ks < 4; ++ks) {
                short8 bv = *(short8*)&sVt[(nt * 16 + l16) * 152 + ks * 32 + quad * 8];
                acc = __builtin_amdgcn_mfma_f32_16x16x32_bf16(ap[ks], bv, acc, 0, 0, 0);
            }
            int d = nt * 16 + l16;
            #pragma unroll
            for (int r = 0; r < 4; ++r) {
                int q = mt * 16 + quad * 4 + r;
                O[(rowbase + q) * DS + h * DH + d] = f2b(acc[r]);
            }
        }
    }
}

// ---------------------------------------------------------------------------
// Segment mean (sorted indices).
// ---------------------------------------------------------------------------
__global__ __launch_bounds__(128) void seg_kernel(
    const float* __restrict__ TOK, const int* __restrict__ idx,
    float* __restrict__ out)
{
    int t = blockIdx.x & (NT - 1);
    int b = blockIdx.x >> 10;
    const int* id = idx + (size_t)b * N_;

    int lo = 0, hi = N_;
    while (lo < hi) { int mid = (lo + hi) >> 1; if (id[mid] < t) lo = mid + 1; else hi = mid; }
    int start = lo;
    hi = N_;
    while (lo < hi) { int mid = (lo + hi) >> 1; if (id[mid] < t + 1) lo = mid + 1; else hi = mid; }
    int end = lo;

    float inv = 1.f / fmaxf((float)(end - start), 1.f);
    for (int c = threadIdx.x; c < DT; c += 128) {
        float s = 0.f;
        for (int r = start; r < end; ++r) s += TOK[((size_t)b * N_ + r) * DT + c];
        out[((size_t)b * NT + t) * DT + c] = s * inv;
    }
}

// ---------------------------------------------------------------------------
extern "C" void kernel_launch(void* const* d_in, const int* in_sizes, int n_in,
                              void* d_out, int out_size, void* d_ws, size_t ws_size,
                              hipStream_t stream)
{
    const float* ref_pos    = (const float*)d_in[0];
    const float* ref_charge = (const float*)d_in[1];
    const float* ref_mask   = (const float*)d_in[2];
    const float* ref_elem   = (const float*)d_in[3];
    const float* ref_chars  = (const float*)d_in[4];
    const float* W_single   = (const float*)d_in[5];
    const float* W_pair     = (const float*)d_in[6];
    const float* W_outer    = (const float*)d_in[7];
    const float* Wp_ff1     = (const float*)d_in[8];
    const float* Wp_ff2     = (const float*)d_in[9];
    const float* Wq         = (const float*)d_in[10];
    const float* Wk         = (const float*)d_in[11];
    const float* Wv         = (const float*)d_in[12];
    const float* Wo         = (const float*)d_in[13];
    const float* Wb         = (const float*)d_in[14];
    const float* Wff1       = (const float*)d_in[15];
    const float* Wff2       = (const float*)d_in[16];
    const float* W_out      = (const float*)d_in[17];
    const int*   uid        = (const int*)d_in[18];
    const int*   a2t        = (const int*)d_in[19];
    float* out = (float*)d_out;

    const size_t ROWS = (size_t)B_ * N_;  // 16384
    float* ws = (float*)d_ws;
    float* X    = ws;                          // 2,097,152 f
    float* P    = X + ROWS * DS;               //   524,288 f
    float* TOK  = P + ROWS * 32;               // 6,291,456 f
    u16* QKVb  = (u16*)(TOK + ROWS * DT);      // 6,291,456 u16
    u16* Ob    = QKVb + ROWS * 384;            // 2,097,152
    u16* FFb   = Ob + ROWS * DS;               // 8,388,608
    u16* BIASb = FFb + ROWS * 512;             // 8,388,608
    u16* qkvT  = BIASb + (size_t)B_ * NWIN * HEADS * QW * KW;
    u16* woT   = qkvT + 3 * 384 * 128;
    u16* ff1T  = woT + 3 * 128 * 128;
    u16* ff2T  = ff1T + 3 * 512 * 128;
    u16* woutT = ff2T + 3 * 128 * 512;
    u16* w1T32 = woutT + 384 * 128;
    u16* w2bT  = w1T32 + 64 * 32;

    convw_kernel<<<768, 256, 0, stream>>>(Wq, Wk, Wv, Wo, Wff1, Wff2, W_out,
                                          Wp_ff1, Wp_ff2, Wb,
                                          qkvT, woT, ff1T, ff2T, woutT,
                                          w1T32, w2bT);
    embed_kernel<<<ROWS / 4, 128, 0, stream>>>(ref_pos, ref_charge, ref_mask,
                                               ref_elem, ref_chars, W_single,
                                               W_outer, X, P);
    bias_kernel<<<4096, 256, 0, stream>>>(ref_pos, uid, P, W_pair, Wb,
                                          w1T32, w2bT, BIASb);

    for (int l = 0; l < DEPTH; ++l) {
        gemm_ln<false><<<dim3(ROWS / 64, 3), 256, 0, stream>>>(
            X, qkvT + (size_t)l * 384 * 128, QKVb, 384);
        attn_kernel<<<B_ * NWIN * HEADS, 256, 0, stream>>>(QKVb, BIASb, Ob);
        gemm_mfma<false, true, false><<<dim3(ROWS / 64, 1), 256, 0, stream>>>(
            Ob, woT + (size_t)l * 128 * 128, X, ROWS, DS, DS);
        gemm_ln<true><<<dim3(ROWS / 64, 4), 256, 0, stream>>>(
            X, ff1T + (size_t)l * 512 * 128, FFb, 512);
        gemm_mfma<false, true, false><<<dim3(ROWS / 64, 1), 256, 0, stream>>>(
            FFb, ff2T + (size_t)l * 128 * 512, X, ROWS, 4 * DS, DS);
    }

    gemm_mfma<true, false, true><<<dim3(ROWS / 64, 3), 256, 0, stream>>>(
        X, woutT, TOK, ROWS, DS, DT);
    seg_kernel<<<B_ * NT, 128, 0, stream>>>(TOK, a2t, out);
}

// Round 5
// 514.010 us; speedup vs baseline: 2.8402x; 1.0872x over previous
//
#include <hip/hip_runtime.h>
#include <hip/hip_bf16.h>

#define QW 64
#define KW 128
#define PADW 32
#define DEPTH 3
#define HEADS 4
#define B_ 2
#define N_ 8192
#define DS 128
#define DP 16
#define DT 384
#define NT 1024
#define NWIN (N_ / QW)   // 128
#define DH (DS / HEADS)  // 32

typedef unsigned short u16;
typedef __attribute__((ext_vector_type(8))) short short8;
typedef __attribute__((ext_vector_type(4))) float f32x4v;
typedef __attribute__((ext_vector_type(4))) unsigned short us4;

__device__ __forceinline__ u16 f2b(float x) {
    union { float f; unsigned u; } v; v.f = x;
    unsigned r = v.u + 0x7fffu + ((v.u >> 16) & 1u);
    return (u16)(r >> 16);
}
__device__ __forceinline__ float b2f(u16 h) {
    union { unsigned u; float f; } v; v.u = ((unsigned)h) << 16; return v.f;
}

// ---------------------------------------------------------------------------
// Weight prep. wcatT[h(16)][k(96)]: rows h<4 = [Wb^T(16) | (W2@Wb)^T(64) | 0].
// ---------------------------------------------------------------------------
__global__ __launch_bounds__(256) void convw_kernel(
    const float* __restrict__ Wq, const float* __restrict__ Wk,
    const float* __restrict__ Wv, const float* __restrict__ Wo,
    const float* __restrict__ Wff1, const float* __restrict__ Wff2,
    const float* __restrict__ Wout, const float* __restrict__ Wpff1,
    const float* __restrict__ Wpff2, const float* __restrict__ Wb,
    u16* __restrict__ qkvT, u16* __restrict__ woT, u16* __restrict__ ff1T,
    u16* __restrict__ ff2T, u16* __restrict__ woutT,
    u16* __restrict__ w1T32, u16* __restrict__ wcatT)
{
    int idx = blockIdx.x * 256 + threadIdx.x;
    if (idx < 3 * 384 * 128) {
        int l = idx / (384 * 128), r = idx % (384 * 128);
        int n = r / 128, k = r % 128;
        const float* W = (n < 128) ? Wq : (n < 256) ? Wk : Wv;
        qkvT[idx] = f2b(W[(size_t)l * 16384 + k * 128 + (n & 127)]);
    }
    if (idx < 3 * 128 * 128) {
        int l = idx / 16384, r = idx % 16384;
        int n = r / 128, k = r % 128;
        woT[idx] = f2b(Wo[(size_t)l * 16384 + k * 128 + n]);
    }
    if (idx < 3 * 512 * 128) {
        int l = idx / 65536, r = idx % 65536;
        int n = r / 128, k = r % 128;
        ff1T[idx] = f2b(Wff1[(size_t)l * 65536 + k * 512 + n]);
    }
    if (idx < 3 * 128 * 512) {
        int l = idx / 65536, r = idx % 65536;
        int n = r / 512, k = r % 512;
        ff2T[idx] = f2b(Wff2[(size_t)l * 65536 + k * 128 + n]);
    }
    if (idx < 384 * 128) {
        int n = idx / 128, k = idx % 128;
        woutT[idx] = f2b(Wout[(size_t)k * 384 + n]);
    }
    if (idx < 64 * 32) {
        int n = idx >> 5, k = idx & 31;
        w1T32[idx] = (k < 16) ? f2b(Wpff1[k * 64 + n]) : (u16)0;
    }
    if (idx < 16 * 96) {
        int h = idx / 96, k = idx % 96;
        float s = 0.f;
        if (h < 4) {
            if (k < 16) s = Wb[k * 4 + h];
            else if (k < 80) {
                int j = k - 16;
                for (int c = 0; c < 16; ++c) s += Wpff2[j * 16 + c] * Wb[c * 4 + h];
            }
        }
        wcatT[idx] = f2b(s);
    }
}

// ---------------------------------------------------------------------------
// Embed: s = feats @ W_single ; p = relu(s) @ W_outer  (fp32)
// ---------------------------------------------------------------------------
__global__ __launch_bounds__(128) void embed_kernel(
    const float* __restrict__ pos, const float* __restrict__ charge,
    const float* __restrict__ mask, const float* __restrict__ elem,
    const float* __restrict__ chars, const float* __restrict__ Wsingle,
    const float* __restrict__ Wouter, float* __restrict__ X,
    float* __restrict__ P)
{
    const int ROWS = 4;
    __shared__ float sf[ROWS][392];
    __shared__ float srelu[ROWS][DS];
    int row0 = blockIdx.x * ROWS;
    int tid = threadIdx.x;

    for (int r = 0; r < ROWS; ++r) {
        int g = row0 + r;
        for (int c = tid; c < 389; c += 128) {
            float v;
            if (c < 3)        v = pos[g * 3 + c];
            else if (c == 3)  v = charge[g];
            else if (c == 4)  v = mask[g];
            else if (c < 133) v = elem[g * 128 + (c - 5)];
            else              v = chars[g * 256 + (c - 133)];
            sf[r][c] = v;
        }
    }
    __syncthreads();

    float acc[ROWS] = {0.f, 0.f, 0.f, 0.f};
    for (int c = 0; c < 389; ++c) {
        float w = Wsingle[c * DS + tid];
        #pragma unroll
        for (int r = 0; r < ROWS; ++r) acc[r] += sf[r][c] * w;
    }
    for (int r = 0; r < ROWS; ++r) {
        X[(size_t)(row0 + r) * DS + tid] = acc[r];
        srelu[r][tid] = fmaxf(acc[r], 0.f);
    }
    __syncthreads();

    int r = tid >> 5, e = tid & 31;
    float a = 0.f;
    for (int k = 0; k < DS; ++k) a += srelu[r][k] * Wouter[k * 32 + e];
    P[(size_t)(row0 + r) * 32 + e] = a;
}

// ---------------------------------------------------------------------------
// Bias kernel v5. Block = (b, w, qg): 4 waves, wave = one q row, 128 kk.
// j-side staged once (1 barrier). Tile loop (8 x 16 cells) is barrier-free:
// phase 1 uses 4 lanes/cell (LN via shfl_xor), writes lp + pr (bf16) to
// per-wave LDS; phase 2: MLP1 operand-swapped (4 MFMA), then
// [pr|relu]@[[Wb],[W2@Wb]] as K=96 (3 MFMA), packed us4 global store.
// ---------------------------------------------------------------------------
__global__ __launch_bounds__(256) void bias_kernel(
    const float* __restrict__ pos, const int* __restrict__ uid,
    const float* __restrict__ P, const float* __restrict__ Wpair,
    const u16* __restrict__ w1T32, const u16* __restrict__ wcatT,
    u16* __restrict__ BIASb)
{
    __shared__ __align__(16) float pjS[128][16];   // 8 KB
    __shared__ __align__(16) float posjS[128][4];  // 2 KB (x,y,z,uid-bits)
    __shared__ __align__(16) u16 lpS[4][16 * 24];  // 0.75 KB x4
    __shared__ __align__(16) u16 A2S[4][16 * 104]; // 3.25 KB x4

    int tid = threadIdx.x;
    int b  = blockIdx.x >> 11;
    int w  = (blockIdx.x >> 4) & 127;
    int qg = blockIdx.x & 15;

    // stage j-side (pj, pos_j, uid_j) for the window's 128 kk
    {
        int r = tid >> 1, half = tid & 1;
        int jk = w * QW + r - PADW;
        bool valid = (jk >= 0) && (jk < N_);
        int gk = b * N_ + jk;
        f32x4v z = (f32x4v){0.f, 0.f, 0.f, 0.f};
        f32x4v v0 = z, v1 = z;
        if (valid) {
            v0 = *(const f32x4v*)(P + (size_t)gk * 32 + 16 + half * 8);
            v1 = *(const f32x4v*)(P + (size_t)gk * 32 + 20 + half * 8);
        }
        *(f32x4v*)&pjS[r][half * 8]     = v0;
        *(f32x4v*)&pjS[r][half * 8 + 4] = v1;
        if (half == 0) {
            float x = 0.f, y = 0.f, zz = 0.f; int u = 0;
            if (valid) { x = pos[gk * 3]; y = pos[gk * 3 + 1]; zz = pos[gk * 3 + 2]; u = uid[gk]; }
            posjS[r][0] = x; posjS[r][1] = y; posjS[r][2] = zz;
            ((int*)posjS[r])[3] = u;
        }
    }

    int wv = tid >> 6, lane = tid & 63, quad = lane >> 4, l16 = lane & 15;
    int cl = lane >> 2, cg = lane & 3;  // phase-1: 4 lanes per cell
    int q = qg * 4 + wv;
    int gq = b * N_ + w * QW + q;

    // wave-broadcast i-side + per-lane weights (registers)
    float xi = pos[gq * 3], yi = pos[gq * 3 + 1], zi = pos[gq * 3 + 2];
    int ui = uid[gq];
    f32x4v pi4 = *(const f32x4v*)(P + (size_t)gq * 32 + cg * 4);
    f32x4v wp[5];
    #pragma unroll
    for (int f = 0; f < 5; ++f)
        wp[f] = *(const f32x4v*)(Wpair + f * 16 + cg * 4);
    short8 w1f[4], wcat[3];
    #pragma unroll
    for (int nt = 0; nt < 4; ++nt)
        w1f[nt] = *(const short8*)&w1T32[(nt * 16 + l16) * 32 + quad * 8];
    #pragma unroll
    for (int ks = 0; ks < 3; ++ks)
        wcat[ks] = *(const short8*)&wcatT[l16 * 96 + ks * 32 + quad * 8];
    // zero A2 cols 80..95 (K padding)
    *(us4*)&A2S[wv][l16 * 104 + 80 + quad * 4] = (us4){0, 0, 0, 0};
    __syncthreads();

    size_t bbase = ((size_t)(b * NWIN + w) * HEADS) * (QW * KW);
    const short8 zero8 = (short8){0, 0, 0, 0, 0, 0, 0, 0};

    for (int t = 0; t < 8; ++t) {
        // ---- phase 1: 16 cells, 4 lanes each ----
        int kk1 = t * 16 + cl;
        f32x4v pjv = *(f32x4v*)&pjS[kk1][cg * 4];
        float xj = posjS[kk1][0], yj = posjS[kk1][1], zj = posjS[kk1][2];
        int uj = ((int*)posjS[kk1])[3];
        float dx = xi - xj, dy = yi - yj, dz = zi - zj;
        float inv = 1.f / (1.f + dx * dx + dy * dy + dz * dz);
        float bf = (ui == uj) ? 1.f : 0.f;
        float pr[4];
        #pragma unroll
        for (int j = 0; j < 4; ++j) {
            float s = fmaf(dx, wp[0][j], fmaf(dy, wp[1][j],
                      fmaf(dz, wp[2][j], fmaf(inv, wp[3][j], wp[4][j]))));
            pr[j] = fmaf(bf, s, pi4[j] + pjv[j]);
        }
        float sum = pr[0] + pr[1] + pr[2] + pr[3];
        sum += __shfl_xor(sum, 1); sum += __shfl_xor(sum, 2);
        float m = sum * (1.f / 16.f);
        float d0 = pr[0] - m, d1 = pr[1] - m, d2 = pr[2] - m, d3 = pr[3] - m;
        float vs = d0 * d0 + d1 * d1 + d2 * d2 + d3 * d3;
        vs += __shfl_xor(vs, 1); vs += __shfl_xor(vs, 2);
        float rstd = rsqrtf(vs * (1.f / 16.f) + 1e-5f);
        us4 lpu = (us4){f2b(d0 * rstd), f2b(d1 * rstd), f2b(d2 * rstd), f2b(d3 * rstd)};
        us4 pru = (us4){f2b(pr[0]), f2b(pr[1]), f2b(pr[2]), f2b(pr[3])};
        *(us4*)&lpS[wv][cl * 24 + cg * 4] = lpu;
        *(us4*)&A2S[wv][cl * 104 + cg * 4] = pru;

        // ---- phase 2 (same wave, LDS in-order) ----
        short8 blp = zero8;
        if (quad < 2) blp = *(short8*)&lpS[wv][l16 * 24 + quad * 8];
        #pragma unroll
        for (int nt = 0; nt < 4; ++nt) {
            f32x4v z4 = (f32x4v){0.f, 0.f, 0.f, 0.f};
            z4 = __builtin_amdgcn_mfma_f32_16x16x32_bf16(w1f[nt], blp, z4, 0, 0, 0);
            us4 o;
            #pragma unroll
            for (int r = 0; r < 4; ++r) o[r] = f2b(fmaxf(z4[r], 0.f));
            *(us4*)&A2S[wv][l16 * 104 + 16 + nt * 16 + quad * 4] = o;
        }
        f32x4v acc = (f32x4v){0.f, 0.f, 0.f, 0.f};
        #pragma unroll
        for (int ks = 0; ks < 3; ++ks) {
            short8 a2 = *(short8*)&A2S[wv][l16 * 104 + ks * 32 + quad * 8];
            acc = __builtin_amdgcn_mfma_f32_16x16x32_bf16(a2, wcat[ks], acc, 0, 0, 0);
        }
        if (l16 < 4) {
            us4 o;
            #pragma unroll
            for (int r = 0; r < 4; ++r) o[r] = f2b(acc[r]);
            *(us4*)&BIASb[bbase + (size_t)l16 * (QW * KW) + q * KW +
                          t * 16 + quad * 4] = o;
        }
    }
}

// ---------------------------------------------------------------------------
// LN-fused MFMA GEMM: OutB[M,N] = (relu)(LN(X[M,128]) @ WT[N,128]^T), bf16 out
// ---------------------------------------------------------------------------
template <bool RELU>
__global__ __launch_bounds__(256) void gemm_ln(
    const float* __restrict__ X, const u16* __restrict__ WT,
    u16* __restrict__ OutB, int N)
{
    __shared__ __align__(16) u16 As[64 * 152];
    int tid = threadIdx.x;
    int row0 = blockIdx.x * 64, n0 = blockIdx.y * 128;

    {
        int r = tid >> 2, cg = tid & 3;
        const float* xr = X + (size_t)(row0 + r) * 128 + cg * 32;
        f32x4v xv[8];
        float s = 0.f, ss = 0.f;
        #pragma unroll
        for (int i = 0; i < 8; ++i) {
            xv[i] = *(const f32x4v*)(xr + i * 4);
            #pragma unroll
            for (int j = 0; j < 4; ++j) { s += xv[i][j]; ss += xv[i][j] * xv[i][j]; }
        }
        s += __shfl_xor(s, 1); s += __shfl_xor(s, 2);
        ss += __shfl_xor(ss, 1); ss += __shfl_xor(ss, 2);
        float m = s * (1.f / 128.f);
        float var = ss * (1.f / 128.f) - m * m;
        float rs = rsqrtf(var + 1e-5f);
        #pragma unroll
        for (int i2 = 0; i2 < 4; ++i2) {
            short8 o;
            #pragma unroll
            for (int j = 0; j < 4; ++j) {
                o[j]     = (short)f2b((xv[i2 * 2][j] - m) * rs);
                o[4 + j] = (short)f2b((xv[i2 * 2 + 1][j] - m) * rs);
            }
            *(short8*)&As[r * 152 + cg * 32 + i2 * 8] = o;
        }
    }
    __syncthreads();

    int wv = tid >> 6, lane = tid & 63, quad = lane >> 4, l16 = lane & 15;
    int wm = (wv & 1) * 32, wn = (wv >> 1) * 64;
    f32x4v acc[2][4];
    #pragma unroll
    for (int i = 0; i < 2; ++i)
        #pragma unroll
        for (int j = 0; j < 4; ++j) acc[i][j] = (f32x4v){0.f, 0.f, 0.f, 0.f};

    #pragma unroll
    for (int kk = 0; kk < 4; ++kk) {
        short8 a0 = *(short8*)&As[(wm + l16) * 152 + kk * 32 + quad * 8];
        short8 a1 = *(short8*)&As[(wm + 16 + l16) * 152 + kk * 32 + quad * 8];
        #pragma unroll
        for (int nt = 0; nt < 4; ++nt) {
            short8 bw = *(const short8*)&WT[(size_t)(n0 + wn + nt * 16 + l16) * 128 +
                                            kk * 32 + quad * 8];
            acc[0][nt] = __builtin_amdgcn_mfma_f32_16x16x32_bf16(a0, bw, acc[0][nt], 0, 0, 0);
            acc[1][nt] = __builtin_amdgcn_mfma_f32_16x16x32_bf16(a1, bw, acc[1][nt], 0, 0, 0);
        }
    }
    #pragma unroll
    for (int mt = 0; mt < 2; ++mt)
        #pragma unroll
        for (int nt = 0; nt < 4; ++nt)
            #pragma unroll
            for (int r = 0; r < 4; ++r) {
                int row = row0 + wm + mt * 16 + quad * 4 + r;
                int col = n0 + wn + nt * 16 + l16;
                float v = acc[mt][nt][r];
                if (RELU) v = fmaxf(v, 0.f);
                OutB[(size_t)row * N + col] = f2b(v);
            }
}

// ---------------------------------------------------------------------------
// Generic MFMA GEMM (WO / FF2 / final): fp32 out.
// ---------------------------------------------------------------------------
template <bool AF32, bool ADD, bool RELU>
__global__ __launch_bounds__(256) void gemm_mfma(
    const void* __restrict__ Ap, const u16* __restrict__ WT,
    float* __restrict__ OutF, int M, int K, int N)
{
    __shared__ __align__(16) u16 As[64 * 88];
    const int row0 = blockIdx.x * 64, n0 = blockIdx.y * 128;
    const int tid = threadIdx.x;
    const int w = tid >> 6, lane = tid & 63, quad = lane >> 4, l16 = lane & 15;
    const int wm = (w & 1) * 32, wn = (w >> 1) * 64;

    f32x4v acc[2][4];
    #pragma unroll
    for (int i = 0; i < 2; ++i)
        #pragma unroll
        for (int j = 0; j < 4; ++j) acc[i][j] = (f32x4v){0.f, 0.f, 0.f, 0.f};

    for (int k0 = 0; k0 < K; k0 += 64) {
        __syncthreads();
        if (AF32) {
            const float* A = (const float*)Ap;
            #pragma unroll
            for (int it = 0; it < 4; ++it) {
                int idx = tid + it * 256;
                int r = idx >> 4, c = idx & 15;
                f32x4v v = *(const f32x4v*)(A + (size_t)(row0 + r) * K + k0 + c * 4);
                us4 o = (us4){f2b(v[0]), f2b(v[1]), f2b(v[2]), f2b(v[3])};
                *(us4*)&As[r * 88 + c * 4] = o;
            }
        } else {
            const u16* A = (const u16*)Ap;
            #pragma unroll
            for (int it = 0; it < 2; ++it) {
                int idx = tid + it * 256;
                int r = idx >> 3, c = idx & 7;
                short8 v = *(const short8*)(A + (size_t)(row0 + r) * K + k0 + c * 8);
                *(short8*)&As[r * 88 + c * 8] = v;
            }
        }
        __syncthreads();
        #pragma unroll
        for (int kk = 0; kk < 64; kk += 32) {
            short8 a0 = *(const short8*)&As[(wm + l16) * 88 + kk + quad * 8];
            short8 a1 = *(const short8*)&As[(wm + 16 + l16) * 88 + kk + quad * 8];
            #pragma unroll
            for (int nt = 0; nt < 4; ++nt) {
                short8 b = *(const short8*)&WT[(size_t)(n0 + wn + nt * 16 + l16) * K + k0 + kk + quad * 8];
                acc[0][nt] = __builtin_amdgcn_mfma_f32_16x16x32_bf16(a0, b, acc[0][nt], 0, 0, 0);
                acc[1][nt] = __builtin_amdgcn_mfma_f32_16x16x32_bf16(a1, b, acc[1][nt], 0, 0, 0);
            }
        }
    }
    #pragma unroll
    for (int mt = 0; mt < 2; ++mt)
        #pragma unroll
        for (int nt = 0; nt < 4; ++nt)
            #pragma unroll
            for (int r = 0; r < 4; ++r) {
                int row = row0 + wm + mt * 16 + quad * 4 + r;
                int col = n0 + wn + nt * 16 + l16;
                size_t o = (size_t)row * N + col;
                float v = acc[mt][nt][r];
                if (RELU) v = fmaxf(v, 0.f);
                if (ADD) v += OutF[o];
                OutF[o] = v;
            }
}

// ---------------------------------------------------------------------------
// Windowed attention v5: S in registers, cross-wave softmax via partials,
// unnormalized bf16 P + fp32 factors. Block per (b, w, h), 4 waves.
// ---------------------------------------------------------------------------
__global__ __launch_bounds__(256) void attn_kernel(
    const u16* __restrict__ QKV, const u16* __restrict__ BIASb,
    u16* __restrict__ O)
{
    __shared__ __align__(16) u16 sQ[64 * 40];    // 5 KB
    __shared__ __align__(16) u16 sK[128 * 40];   // 10 KB
    __shared__ __align__(16) u16 sVt[32 * 152];  // 9.5 KB
    __shared__ __align__(16) u16 sP[64 * 136];   // 17 KB
    __shared__ float pmax[4][64];
    __shared__ float psum[4][64];
    __shared__ float gfac[4][64];

    int tid = threadIdx.x;
    int h = blockIdx.x & 3, w = (blockIdx.x >> 2) & 127, b = blockIdx.x >> 9;
    size_t rowbase = (size_t)b * N_ + w * QW;
    const short8 zero8 = (short8){0, 0, 0, 0, 0, 0, 0, 0};

    {   // Q
        int r = tid >> 2, d8 = (tid & 3) * 8;
        *(short8*)&sQ[r * 40 + d8] =
            *(const short8*)&QKV[(rowbase + r) * 384 + h * DH + d8];
    }
    #pragma unroll
    for (int i = 0; i < 2; ++i) {  // K
        int idx = tid + i * 256;
        int r = idx >> 2, d8 = (idx & 3) * 8;
        int jk = w * QW + r - PADW;
        short8 v = zero8;
        if (jk >= 0 && jk < N_)
            v = *(const short8*)&QKV[((size_t)b * N_ + jk) * 384 + 128 + h * DH + d8];
        *(short8*)&sK[r * 40 + d8] = v;
    }
    {   // V transposed
        int kk = tid >> 1, d0 = (tid & 1) * 16;
        int jk = w * QW + kk - PADW;
        short8 v0 = zero8, v1 = zero8;
        if (jk >= 0 && jk < N_) {
            const u16* src = &QKV[((size_t)b * N_ + jk) * 384 + 256 + h * DH + d0];
            v0 = *(const short8*)src;
            v1 = *(const short8*)(src + 8);
        }
        #pragma unroll
        for (int j = 0; j < 8; ++j) {
            sVt[(d0 + j) * 152 + kk] = (u16)v0[j];
            sVt[(d0 + 8 + j) * 152 + kk] = (u16)v1[j];
        }
    }
    __syncthreads();

    int wv = tid >> 6, lane = tid & 63, quad = lane >> 4, l16 = lane & 15;
    const float scale = 0.17677669529663687f;  // 1/sqrt(32)
    size_t bbase = ((size_t)(b * NWIN + w) * HEADS + h) * (QW * KW);

    // ---- QK^T into registers ----
    short8 aq[4];
    #pragma unroll
    for (int mt = 0; mt < 4; ++mt)
        aq[mt] = *(short8*)&sQ[(mt * 16 + l16) * 40 + quad * 8];
    float e[2][4][4];
    #pragma unroll
    for (int ni = 0; ni < 2; ++ni) {
        int nt = wv * 2 + ni;
        short8 bk = *(short8*)&sK[(nt * 16 + l16) * 40 + quad * 8];
        int kk = nt * 16 + l16;
        int jk = w * QW + kk - PADW;
        float msk = (jk >= 0 && jk < N_) ? 0.f : -1e9f;
        #pragma unroll
        for (int mt = 0; mt < 4; ++mt) {
            f32x4v acc = (f32x4v){0.f, 0.f, 0.f, 0.f};
            acc = __builtin_amdgcn_mfma_f32_16x16x32_bf16(aq[mt], bk, acc, 0, 0, 0);
            #pragma unroll
            for (int r = 0; r < 4; ++r) {
                int q = mt * 16 + quad * 4 + r;
                e[ni][mt][r] = acc[r] * scale + b2f(BIASb[bbase + q * KW + kk]) + msk;
            }
        }
    }

    // ---- per-wave local max / exp / sum (over this wave's 32 kk) ----
    #pragma unroll
    for (int mt = 0; mt < 4; ++mt)
        #pragma unroll
        for (int r = 0; r < 4; ++r) {
            float m = fmaxf(e[0][mt][r], e[1][mt][r]);
            m = fmaxf(m, __shfl_xor(m, 1));
            m = fmaxf(m, __shfl_xor(m, 2));
            m = fmaxf(m, __shfl_xor(m, 4));
            m = fmaxf(m, __shfl_xor(m, 8));
            float e0 = __expf(e[0][mt][r] - m);
            float e1 = __expf(e[1][mt][r] - m);
            e[0][mt][r] = e0; e[1][mt][r] = e1;
            float s = e0 + e1;
            s += __shfl_xor(s, 1);
            s += __shfl_xor(s, 2);
            s += __shfl_xor(s, 4);
            s += __shfl_xor(s, 8);
            if (l16 == 0) {
                int q = mt * 16 + quad * 4 + r;
                pmax[wv][q] = m;
                psum[wv][q] = s;
            }
        }
    __syncthreads();

    // ---- cross-wave combine ----
    if (tid < 64) {
        float m0 = pmax[0][tid], m1 = pmax[1][tid], m2 = pmax[2][tid], m3 = pmax[3][tid];
        float M = fmaxf(fmaxf(m0, m1), fmaxf(m2, m3));
        float g0 = __expf(m0 - M), g1 = __expf(m1 - M),
              g2 = __expf(m2 - M), g3 = __expf(m3 - M);
        float T = psum[0][tid] * g0 + psum[1][tid] * g1 +
                  psum[2][tid] * g2 + psum[3][tid] * g3;
        float inv = 1.f / T;
        gfac[0][tid] = g0 * inv; gfac[1][tid] = g1 * inv;
        gfac[2][tid] = g2 * inv; gfac[3][tid] = g3 * inv;
    }
    __syncthreads();

    // ---- normalize + write P (bf16, [q][kk] stride 136) ----
    #pragma unroll
    for (int mt = 0; mt < 4; ++mt)
        #pragma unroll
        for (int r = 0; r < 4; ++r) {
            int q = mt * 16 + quad * 4 + r;
            float f = gfac[wv][q];
            #pragma unroll
            for (int ni = 0; ni < 2; ++ni) {
                int kk = (wv * 2 + ni) * 16 + l16;
                sP[q * 136 + kk] = f2b(e[ni][mt][r] * f);
            }
        }
    __syncthreads();

    // ---- P @ V ----
    {
        int mt = wv;
        short8 ap[4];
        #pragma unroll
        for (int ks = 0; ks < 4; ++ks)
            ap[ks] = *(short8*)&sP[(mt * 16 + l16) * 136 + ks * 32 + quad * 8];
        #pragma unroll
        for (int nt = 0; nt < 2; ++nt) {
            f32x4v acc = (f32x4v){0.f, 0.f, 0.f, 0.f};
            #pragma unroll
            for (int ks = 0; ks < 4; ++ks) {
                short8 bv = *(short8*)&sVt[(nt * 16 + l16) * 152 + ks * 32 + quad * 8];
                acc = __builtin_amdgcn_mfma_f32_16x16x32_bf16(ap[ks], bv, acc, 0, 0, 0);
            }
            int d = nt * 16 + l16;
            #pragma unroll
            for (int r = 0; r < 4; ++r) {
                int q = mt * 16 + quad * 4 + r;
                O[(rowbase + q) * DS + h * DH + d] = f2b(acc[r]);
            }
        }
    }
}

// ---------------------------------------------------------------------------
// Segment mean (sorted indices).
// ---------------------------------------------------------------------------
__global__ __launch_bounds__(128) void seg_kernel(
    const float* __restrict__ TOK, const int* __restrict__ idx,
    float* __restrict__ out)
{
    int t = blockIdx.x & (NT - 1);
    int b = blockIdx.x >> 10;
    const int* id = idx + (size_t)b * N_;

    int lo = 0, hi = N_;
    while (lo < hi) { int mid = (lo + hi) >> 1; if (id[mid] < t) lo = mid + 1; else hi = mid; }
    int start = lo;
    hi = N_;
    while (lo < hi) { int mid = (lo + hi) >> 1; if (id[mid] < t + 1) lo = mid + 1; else hi = mid; }
    int end = lo;

    float inv = 1.f / fmaxf((float)(end - start), 1.f);
    for (int c = threadIdx.x; c < DT; c += 128) {
        float s = 0.f;
        for (int r = start; r < end; ++r) s += TOK[((size_t)b * N_ + r) * DT + c];
        out[((size_t)b * NT + t) * DT + c] = s * inv;
    }
}

// ---------------------------------------------------------------------------
extern "C" void kernel_launch(void* const* d_in, const int* in_sizes, int n_in,
                              void* d_out, int out_size, void* d_ws, size_t ws_size,
                              hipStream_t stream)
{
    const float* ref_pos    = (const float*)d_in[0];
    const float* ref_charge = (const float*)d_in[1];
    const float* ref_mask   = (const float*)d_in[2];
    const float* ref_elem   = (const float*)d_in[3];
    const float* ref_chars  = (const float*)d_in[4];
    const float* W_single   = (const float*)d_in[5];
    const float* W_pair     = (const float*)d_in[6];
    const float* W_outer    = (const float*)d_in[7];
    const float* Wp_ff1     = (const float*)d_in[8];
    const float* Wp_ff2     = (const float*)d_in[9];
    const float* Wq         = (const float*)d_in[10];
    const float* Wk         = (const float*)d_in[11];
    const float* Wv         = (const float*)d_in[12];
    const float* Wo         = (const float*)d_in[13];
    const float* Wb         = (const float*)d_in[14];
    const float* Wff1       = (const float*)d_in[15];
    const float* Wff2       = (const float*)d_in[16];
    const float* W_out      = (const float*)d_in[17];
    const int*   uid        = (const int*)d_in[18];
    const int*   a2t        = (const int*)d_in[19];
    float* out = (float*)d_out;

    const size_t ROWS = (size_t)B_ * N_;  // 16384
    float* ws = (float*)d_ws;
    float* X    = ws;                          // 2,097,152 f
    float* P    = X + ROWS * DS;               //   524,288 f
    float* TOK  = P + ROWS * 32;               // 6,291,456 f
    u16* QKVb  = (u16*)(TOK + ROWS * DT);      // 6,291,456 u16
    u16* Ob    = QKVb + ROWS * 384;            // 2,097,152
    u16* FFb   = Ob + ROWS * DS;               // 8,388,608
    u16* BIASb = FFb + ROWS * 512;             // 8,388,608
    u16* qkvT  = BIASb + (size_t)B_ * NWIN * HEADS * QW * KW;
    u16* woT   = qkvT + 3 * 384 * 128;
    u16* ff1T  = woT + 3 * 128 * 128;
    u16* ff2T  = ff1T + 3 * 512 * 128;
    u16* woutT = ff2T + 3 * 128 * 512;
    u16* w1T32 = woutT + 384 * 128;
    u16* wcatT = w1T32 + 64 * 32;

    convw_kernel<<<768, 256, 0, stream>>>(Wq, Wk, Wv, Wo, Wff1, Wff2, W_out,
                                          Wp_ff1, Wp_ff2, Wb,
                                          qkvT, woT, ff1T, ff2T, woutT,
                                          w1T32, wcatT);
    embed_kernel<<<ROWS / 4, 128, 0, stream>>>(ref_pos, ref_charge, ref_mask,
                                               ref_elem, ref_chars, W_single,
                                               W_outer, X, P);
    bias_kernel<<<4096, 256, 0, stream>>>(ref_pos, uid, P, W_pair,
                                          w1T32, wcatT, BIASb);

    for (int l = 0; l < DEPTH; ++l) {
        gemm_ln<false><<<dim3(ROWS / 64, 3), 256, 0, stream>>>(
            X, qkvT + (size_t)l * 384 * 128, QKVb, 384);
        attn_kernel<<<B_ * NWIN * HEADS, 256, 0, stream>>>(QKVb, BIASb, Ob);
        gemm_mfma<false, true, false><<<dim3(ROWS / 64, 1), 256, 0, stream>>>(
            Ob, woT + (size_t)l * 128 * 128, X, ROWS, DS, DS);
        gemm_ln<true><<<dim3(ROWS / 64, 4), 256, 0, stream>>>(
            X, ff1T + (size_t)l * 512 * 128, FFb, 512);
        gemm_mfma<false, true, false><<<dim3(ROWS / 64, 1), 256, 0, stream>>>(
            FFb, ff2T + (size_t)l * 128 * 512, X, ROWS, 4 * DS, DS);
    }

    gemm_mfma<true, false, true><<<dim3(ROWS / 64, 3), 256, 0, stream>>>(
        X, woutT, TOK, ROWS, DS, DT);
    seg_kernel<<<B_ * NT, 128, 0, stream>>>(TOK, a2t, out);
}

// Round 6
// 482.374 us; speedup vs baseline: 3.0265x; 1.0656x over previous
//
#include <hip/hip_runtime.h>
#include <hip/hip_bf16.h>

#define QW 64
#define KW 128
#define PADW 32
#define DEPTH 3
#define HEADS 4
#define B_ 2
#define N_ 8192
#define DS 128
#define DP 16
#define DT 384
#define NT 1024
#define NWIN (N_ / QW)   // 128
#define DH (DS / HEADS)  // 32

typedef unsigned short u16;
typedef __attribute__((ext_vector_type(8))) short short8;
typedef __attribute__((ext_vector_type(4))) float f32x4v;
typedef __attribute__((ext_vector_type(4))) unsigned short us4;

__device__ __forceinline__ u16 f2b(float x) {
    union { float f; unsigned u; } v; v.f = x;
    unsigned r = v.u + 0x7fffu + ((v.u >> 16) & 1u);
    return (u16)(r >> 16);
}
__device__ __forceinline__ float b2f(u16 h) {
    union { unsigned u; float f; } v; v.u = ((unsigned)h) << 16; return v.f;
}

// ---------------------------------------------------------------------------
// Weight prep. wcatT[h(16)][k(96)] = [Wb^T | (W2@Wb)^T | 0] for h<4.
// wsT[n(128)][k(416)] = W_single^T with PERMUTED K: [elem128|chars256|pos3|
// charge|mask|pad27] (must match embed_gemm's LDS layout). woutrT[n(32)][k(128)].
// ---------------------------------------------------------------------------
__global__ __launch_bounds__(256) void convw_kernel(
    const float* __restrict__ Wq, const float* __restrict__ Wk,
    const float* __restrict__ Wv, const float* __restrict__ Wo,
    const float* __restrict__ Wff1, const float* __restrict__ Wff2,
    const float* __restrict__ Wout, const float* __restrict__ Wpff1,
    const float* __restrict__ Wpff2, const float* __restrict__ Wb,
    const float* __restrict__ Wsingle, const float* __restrict__ Wouter,
    u16* __restrict__ qkvT, u16* __restrict__ woT, u16* __restrict__ ff1T,
    u16* __restrict__ ff2T, u16* __restrict__ woutT,
    u16* __restrict__ w1T32, u16* __restrict__ wcatT,
    u16* __restrict__ wsT, u16* __restrict__ woutrT)
{
    int idx = blockIdx.x * 256 + threadIdx.x;
    if (idx < 3 * 384 * 128) {
        int l = idx / (384 * 128), r = idx % (384 * 128);
        int n = r / 128, k = r % 128;
        const float* W = (n < 128) ? Wq : (n < 256) ? Wk : Wv;
        qkvT[idx] = f2b(W[(size_t)l * 16384 + k * 128 + (n & 127)]);
    }
    if (idx < 3 * 128 * 128) {
        int l = idx / 16384, r = idx % 16384;
        int n = r / 128, k = r % 128;
        woT[idx] = f2b(Wo[(size_t)l * 16384 + k * 128 + n]);
    }
    if (idx < 3 * 512 * 128) {
        int l = idx / 65536, r = idx % 65536;
        int n = r / 128, k = r % 128;
        ff1T[idx] = f2b(Wff1[(size_t)l * 65536 + k * 512 + n]);
    }
    if (idx < 3 * 128 * 512) {
        int l = idx / 65536, r = idx % 65536;
        int n = r / 512, k = r % 512;
        ff2T[idx] = f2b(Wff2[(size_t)l * 65536 + k * 128 + n]);
    }
    if (idx < 384 * 128) {
        int n = idx / 128, k = idx % 128;
        woutT[idx] = f2b(Wout[(size_t)k * 384 + n]);
    }
    if (idx < 64 * 32) {
        int n = idx >> 5, k = idx & 31;
        w1T32[idx] = (k < 16) ? f2b(Wpff1[k * 64 + n]) : (u16)0;
    }
    if (idx < 16 * 96) {
        int h = idx / 96, k = idx % 96;
        float s = 0.f;
        if (h < 4) {
            if (k < 16) s = Wb[k * 4 + h];
            else if (k < 80) {
                int j = k - 16;
                for (int c = 0; c < 16; ++c) s += Wpff2[j * 16 + c] * Wb[c * 4 + h];
            }
        }
        wcatT[idx] = f2b(s);
    }
    if (idx < 128 * 416) {  // wsT[n][k], permuted K
        int n = idx / 416, k = idx % 416;
        float v = 0.f;
        if (k < 128)       v = Wsingle[(5 + k) * 128 + n];        // elem
        else if (k < 384)  v = Wsingle[(133 + k - 128) * 128 + n]; // chars
        else if (k < 387)  v = Wsingle[(k - 384) * 128 + n];       // pos
        else if (k == 387) v = Wsingle[3 * 128 + n];               // charge
        else if (k == 388) v = Wsingle[4 * 128 + n];               // mask
        wsT[idx] = f2b(v);
    }
    if (idx < 32 * 128) {   // woutrT[n][k] = W_outer^T
        int n = idx >> 7, k = idx & 127;
        woutrT[idx] = f2b(Wouter[k * 32 + n]);
    }
}

// ---------------------------------------------------------------------------
// Embed GEMM (MFMA): X[M,128] = feats[M,416p] @ wsT^T; SRELUb = relu(X) bf16.
// Block 256 thr, 64-row tile, K staged once in LDS (permuted layout).
// ---------------------------------------------------------------------------
__global__ __launch_bounds__(256) void embed_gemm(
    const float* __restrict__ pos, const float* __restrict__ charge,
    const float* __restrict__ mask, const float* __restrict__ elem,
    const float* __restrict__ chars, const u16* __restrict__ wsT,
    float* __restrict__ X, u16* __restrict__ SRELUb)
{
    __shared__ __align__(16) u16 As[64 * 424];  // 53 KB
    int tid = threadIdx.x;
    int row0 = blockIdx.x * 64;

    // stage elem (cols 0..127)
    #pragma unroll
    for (int it = 0; it < 8; ++it) {
        int idx = tid + it * 256;
        int r = idx >> 5, c4 = idx & 31;
        f32x4v v = *(const f32x4v*)(elem + (size_t)(row0 + r) * 128 + c4 * 4);
        us4 o = (us4){f2b(v[0]), f2b(v[1]), f2b(v[2]), f2b(v[3])};
        *(us4*)&As[r * 424 + c4 * 4] = o;
    }
    // stage chars (cols 128..383)
    #pragma unroll
    for (int it = 0; it < 16; ++it) {
        int idx = tid + it * 256;
        int r = idx >> 6, c4 = idx & 63;
        f32x4v v = *(const f32x4v*)(chars + (size_t)(row0 + r) * 256 + c4 * 4);
        us4 o = (us4){f2b(v[0]), f2b(v[1]), f2b(v[2]), f2b(v[3])};
        *(us4*)&As[r * 424 + 128 + c4 * 4] = o;
    }
    // tail: pos/charge/mask (cols 384..388) + zero pad (389..415)
    if (tid < 64) {
        int g = row0 + tid;
        As[tid * 424 + 384] = f2b(pos[g * 3]);
        As[tid * 424 + 385] = f2b(pos[g * 3 + 1]);
        As[tid * 424 + 386] = f2b(pos[g * 3 + 2]);
        As[tid * 424 + 387] = f2b(charge[g]);
        As[tid * 424 + 388] = f2b(mask[g]);
        for (int c = 389; c < 416; ++c) As[tid * 424 + c] = 0;
    }
    __syncthreads();

    int wv = tid >> 6, lane = tid & 63, quad = lane >> 4, l16 = lane & 15;
    int wm = (wv & 1) * 32, wn = (wv >> 1) * 64;
    f32x4v acc[2][4];
    #pragma unroll
    for (int i = 0; i < 2; ++i)
        #pragma unroll
        for (int j = 0; j < 4; ++j) acc[i][j] = (f32x4v){0.f, 0.f, 0.f, 0.f};

    #pragma unroll
    for (int kk = 0; kk < 13; ++kk) {
        short8 a0 = *(short8*)&As[(wm + l16) * 424 + kk * 32 + quad * 8];
        short8 a1 = *(short8*)&As[(wm + 16 + l16) * 424 + kk * 32 + quad * 8];
        #pragma unroll
        for (int nt = 0; nt < 4; ++nt) {
            short8 bw = *(const short8*)&wsT[(size_t)(wn + nt * 16 + l16) * 416 +
                                             kk * 32 + quad * 8];
            acc[0][nt] = __builtin_amdgcn_mfma_f32_16x16x32_bf16(a0, bw, acc[0][nt], 0, 0, 0);
            acc[1][nt] = __builtin_amdgcn_mfma_f32_16x16x32_bf16(a1, bw, acc[1][nt], 0, 0, 0);
        }
    }
    #pragma unroll
    for (int mt = 0; mt < 2; ++mt)
        #pragma unroll
        for (int nt = 0; nt < 4; ++nt)
            #pragma unroll
            for (int r = 0; r < 4; ++r) {
                int row = row0 + wm + mt * 16 + quad * 4 + r;
                int col = wn + nt * 16 + l16;
                float v = acc[mt][nt][r];
                X[(size_t)row * DS + col] = v;
                SRELUb[(size_t)row * DS + col] = f2b(fmaxf(v, 0.f));
            }
}

// ---------------------------------------------------------------------------
// P GEMM: P[M,32] = SRELUb[M,128] @ woutrT^T (fp32 out). 64-row blocks.
// ---------------------------------------------------------------------------
__global__ __launch_bounds__(256) void pgemm_kernel(
    const u16* __restrict__ SRELUb, const u16* __restrict__ woutrT,
    float* __restrict__ P)
{
    __shared__ __align__(16) u16 As[64 * 136];
    int tid = threadIdx.x;
    int row0 = blockIdx.x * 64;
    #pragma unroll
    for (int it = 0; it < 4; ++it) {
        int idx = tid + it * 256;
        int r = idx >> 4, c8 = idx & 15;
        *(short8*)&As[r * 136 + c8 * 8] =
            *(const short8*)&SRELUb[(size_t)(row0 + r) * 128 + c8 * 8];
    }
    __syncthreads();

    int wv = tid >> 6, lane = tid & 63, quad = lane >> 4, l16 = lane & 15;
    int wm = wv * 16;
    f32x4v acc[2];
    acc[0] = (f32x4v){0.f, 0.f, 0.f, 0.f};
    acc[1] = (f32x4v){0.f, 0.f, 0.f, 0.f};
    #pragma unroll
    for (int ks = 0; ks < 4; ++ks) {
        short8 a = *(short8*)&As[(wm + l16) * 136 + ks * 32 + quad * 8];
        #pragma unroll
        for (int nt = 0; nt < 2; ++nt) {
            short8 bw = *(const short8*)&woutrT[(size_t)(nt * 16 + l16) * 128 +
                                                ks * 32 + quad * 8];
            acc[nt] = __builtin_amdgcn_mfma_f32_16x16x32_bf16(a, bw, acc[nt], 0, 0, 0);
        }
    }
    #pragma unroll
    for (int nt = 0; nt < 2; ++nt)
        #pragma unroll
        for (int r = 0; r < 4; ++r) {
            int row = row0 + wm + quad * 4 + r;
            P[(size_t)row * 32 + nt * 16 + l16] = acc[nt][r];
        }
}

// ---------------------------------------------------------------------------
// Bias kernel v5 (unchanged from round 5).
// ---------------------------------------------------------------------------
__global__ __launch_bounds__(256) void bias_kernel(
    const float* __restrict__ pos, const int* __restrict__ uid,
    const float* __restrict__ P, const float* __restrict__ Wpair,
    const u16* __restrict__ w1T32, const u16* __restrict__ wcatT,
    u16* __restrict__ BIASb)
{
    __shared__ __align__(16) float pjS[128][16];
    __shared__ __align__(16) float posjS[128][4];
    __shared__ __align__(16) u16 lpS[4][16 * 24];
    __shared__ __align__(16) u16 A2S[4][16 * 104];

    int tid = threadIdx.x;
    int b  = blockIdx.x >> 11;
    int w  = (blockIdx.x >> 4) & 127;
    int qg = blockIdx.x & 15;

    {
        int r = tid >> 1, half = tid & 1;
        int jk = w * QW + r - PADW;
        bool valid = (jk >= 0) && (jk < N_);
        int gk = b * N_ + jk;
        f32x4v z = (f32x4v){0.f, 0.f, 0.f, 0.f};
        f32x4v v0 = z, v1 = z;
        if (valid) {
            v0 = *(const f32x4v*)(P + (size_t)gk * 32 + 16 + half * 8);
            v1 = *(const f32x4v*)(P + (size_t)gk * 32 + 20 + half * 8);
        }
        *(f32x4v*)&pjS[r][half * 8]     = v0;
        *(f32x4v*)&pjS[r][half * 8 + 4] = v1;
        if (half == 0) {
            float x = 0.f, y = 0.f, zz = 0.f; int u = 0;
            if (valid) { x = pos[gk * 3]; y = pos[gk * 3 + 1]; zz = pos[gk * 3 + 2]; u = uid[gk]; }
            posjS[r][0] = x; posjS[r][1] = y; posjS[r][2] = zz;
            ((int*)posjS[r])[3] = u;
        }
    }

    int wv = tid >> 6, lane = tid & 63, quad = lane >> 4, l16 = lane & 15;
    int cl = lane >> 2, cg = lane & 3;
    int q = qg * 4 + wv;
    int gq = b * N_ + w * QW + q;

    float xi = pos[gq * 3], yi = pos[gq * 3 + 1], zi = pos[gq * 3 + 2];
    int ui = uid[gq];
    f32x4v pi4 = *(const f32x4v*)(P + (size_t)gq * 32 + cg * 4);
    f32x4v wp[5];
    #pragma unroll
    for (int f = 0; f < 5; ++f)
        wp[f] = *(const f32x4v*)(Wpair + f * 16 + cg * 4);
    short8 w1f[4], wcat[3];
    #pragma unroll
    for (int nt = 0; nt < 4; ++nt)
        w1f[nt] = *(const short8*)&w1T32[(nt * 16 + l16) * 32 + quad * 8];
    #pragma unroll
    for (int ks = 0; ks < 3; ++ks)
        wcat[ks] = *(const short8*)&wcatT[l16 * 96 + ks * 32 + quad * 8];
    *(us4*)&A2S[wv][l16 * 104 + 80 + quad * 4] = (us4){0, 0, 0, 0};
    __syncthreads();

    size_t bbase = ((size_t)(b * NWIN + w) * HEADS) * (QW * KW);
    const short8 zero8 = (short8){0, 0, 0, 0, 0, 0, 0, 0};

    for (int t = 0; t < 8; ++t) {
        int kk1 = t * 16 + cl;
        f32x4v pjv = *(f32x4v*)&pjS[kk1][cg * 4];
        float xj = posjS[kk1][0], yj = posjS[kk1][1], zj = posjS[kk1][2];
        int uj = ((int*)posjS[kk1])[3];
        float dx = xi - xj, dy = yi - yj, dz = zi - zj;
        float inv = 1.f / (1.f + dx * dx + dy * dy + dz * dz);
        float bf = (ui == uj) ? 1.f : 0.f;
        float pr[4];
        #pragma unroll
        for (int j = 0; j < 4; ++j) {
            float s = fmaf(dx, wp[0][j], fmaf(dy, wp[1][j],
                      fmaf(dz, wp[2][j], fmaf(inv, wp[3][j], wp[4][j]))));
            pr[j] = fmaf(bf, s, pi4[j] + pjv[j]);
        }
        float sum = pr[0] + pr[1] + pr[2] + pr[3];
        sum += __shfl_xor(sum, 1); sum += __shfl_xor(sum, 2);
        float m = sum * (1.f / 16.f);
        float d0 = pr[0] - m, d1 = pr[1] - m, d2 = pr[2] - m, d3 = pr[3] - m;
        float vs = d0 * d0 + d1 * d1 + d2 * d2 + d3 * d3;
        vs += __shfl_xor(vs, 1); vs += __shfl_xor(vs, 2);
        float rstd = rsqrtf(vs * (1.f / 16.f) + 1e-5f);
        us4 lpu = (us4){f2b(d0 * rstd), f2b(d1 * rstd), f2b(d2 * rstd), f2b(d3 * rstd)};
        us4 pru = (us4){f2b(pr[0]), f2b(pr[1]), f2b(pr[2]), f2b(pr[3])};
        *(us4*)&lpS[wv][cl * 24 + cg * 4] = lpu;
        *(us4*)&A2S[wv][cl * 104 + cg * 4] = pru;

        short8 blp = zero8;
        if (quad < 2) blp = *(short8*)&lpS[wv][l16 * 24 + quad * 8];
        #pragma unroll
        for (int nt = 0; nt < 4; ++nt) {
            f32x4v z4 = (f32x4v){0.f, 0.f, 0.f, 0.f};
            z4 = __builtin_amdgcn_mfma_f32_16x16x32_bf16(w1f[nt], blp, z4, 0, 0, 0);
            us4 o;
            #pragma unroll
            for (int r = 0; r < 4; ++r) o[r] = f2b(fmaxf(z4[r], 0.f));
            *(us4*)&A2S[wv][l16 * 104 + 16 + nt * 16 + quad * 4] = o;
        }
        f32x4v acc = (f32x4v){0.f, 0.f, 0.f, 0.f};
        #pragma unroll
        for (int ks = 0; ks < 3; ++ks) {
            short8 a2 = *(short8*)&A2S[wv][l16 * 104 + ks * 32 + quad * 8];
            acc = __builtin_amdgcn_mfma_f32_16x16x32_bf16(a2, wcat[ks], acc, 0, 0, 0);
        }
        if (l16 < 4) {
            us4 o;
            #pragma unroll
            for (int r = 0; r < 4; ++r) o[r] = f2b(acc[r]);
            *(us4*)&BIASb[bbase + (size_t)l16 * (QW * KW) + q * KW +
                          t * 16 + quad * 4] = o;
        }
    }
}

// ---------------------------------------------------------------------------
// LN-fused MFMA GEMM (unchanged).
// ---------------------------------------------------------------------------
template <bool RELU>
__global__ __launch_bounds__(256) void gemm_ln(
    const float* __restrict__ X, const u16* __restrict__ WT,
    u16* __restrict__ OutB, int N)
{
    __shared__ __align__(16) u16 As[64 * 152];
    int tid = threadIdx.x;
    int row0 = blockIdx.x * 64, n0 = blockIdx.y * 128;

    {
        int r = tid >> 2, cg = tid & 3;
        const float* xr = X + (size_t)(row0 + r) * 128 + cg * 32;
        f32x4v xv[8];
        float s = 0.f, ss = 0.f;
        #pragma unroll
        for (int i = 0; i < 8; ++i) {
            xv[i] = *(const f32x4v*)(xr + i * 4);
            #pragma unroll
            for (int j = 0; j < 4; ++j) { s += xv[i][j]; ss += xv[i][j] * xv[i][j]; }
        }
        s += __shfl_xor(s, 1); s += __shfl_xor(s, 2);
        ss += __shfl_xor(ss, 1); ss += __shfl_xor(ss, 2);
        float m = s * (1.f / 128.f);
        float var = ss * (1.f / 128.f) - m * m;
        float rs = rsqrtf(var + 1e-5f);
        #pragma unroll
        for (int i2 = 0; i2 < 4; ++i2) {
            short8 o;
            #pragma unroll
            for (int j = 0; j < 4; ++j) {
                o[j]     = (short)f2b((xv[i2 * 2][j] - m) * rs);
                o[4 + j] = (short)f2b((xv[i2 * 2 + 1][j] - m) * rs);
            }
            *(short8*)&As[r * 152 + cg * 32 + i2 * 8] = o;
        }
    }
    __syncthreads();

    int wv = tid >> 6, lane = tid & 63, quad = lane >> 4, l16 = lane & 15;
    int wm = (wv & 1) * 32, wn = (wv >> 1) * 64;
    f32x4v acc[2][4];
    #pragma unroll
    for (int i = 0; i < 2; ++i)
        #pragma unroll
        for (int j = 0; j < 4; ++j) acc[i][j] = (f32x4v){0.f, 0.f, 0.f, 0.f};

    #pragma unroll
    for (int kk = 0; kk < 4; ++kk) {
        short8 a0 = *(short8*)&As[(wm + l16) * 152 + kk * 32 + quad * 8];
        short8 a1 = *(short8*)&As[(wm + 16 + l16) * 152 + kk * 32 + quad * 8];
        #pragma unroll
        for (int nt = 0; nt < 4; ++nt) {
            short8 bw = *(const short8*)&WT[(size_t)(n0 + wn + nt * 16 + l16) * 128 +
                                            kk * 32 + quad * 8];
            acc[0][nt] = __builtin_amdgcn_mfma_f32_16x16x32_bf16(a0, bw, acc[0][nt], 0, 0, 0);
            acc[1][nt] = __builtin_amdgcn_mfma_f32_16x16x32_bf16(a1, bw, acc[1][nt], 0, 0, 0);
        }
    }
    #pragma unroll
    for (int mt = 0; mt < 2; ++mt)
        #pragma unroll
        for (int nt = 0; nt < 4; ++nt)
            #pragma unroll
            for (int r = 0; r < 4; ++r) {
                int row = row0 + wm + mt * 16 + quad * 4 + r;
                int col = n0 + wn + nt * 16 + l16;
                float v = acc[mt][nt][r];
                if (RELU) v = fmaxf(v, 0.f);
                OutB[(size_t)row * N + col] = f2b(v);
            }
}

// ---------------------------------------------------------------------------
// Generic MFMA GEMM; OUTB selects bf16 output.
// ---------------------------------------------------------------------------
template <bool AF32, bool ADD, bool RELU, bool OUTB>
__global__ __launch_bounds__(256) void gemm_mfma(
    const void* __restrict__ Ap, const u16* __restrict__ WT,
    float* __restrict__ OutF, u16* __restrict__ OutB,
    int M, int K, int N)
{
    __shared__ __align__(16) u16 As[64 * 88];
    const int row0 = blockIdx.x * 64, n0 = blockIdx.y * 128;
    const int tid = threadIdx.x;
    const int w = tid >> 6, lane = tid & 63, quad = lane >> 4, l16 = lane & 15;
    const int wm = (w & 1) * 32, wn = (w >> 1) * 64;

    f32x4v acc[2][4];
    #pragma unroll
    for (int i = 0; i < 2; ++i)
        #pragma unroll
        for (int j = 0; j < 4; ++j) acc[i][j] = (f32x4v){0.f, 0.f, 0.f, 0.f};

    for (int k0 = 0; k0 < K; k0 += 64) {
        __syncthreads();
        if (AF32) {
            const float* A = (const float*)Ap;
            #pragma unroll
            for (int it = 0; it < 4; ++it) {
                int idx = tid + it * 256;
                int r = idx >> 4, c = idx & 15;
                f32x4v v = *(const f32x4v*)(A + (size_t)(row0 + r) * K + k0 + c * 4);
                us4 o = (us4){f2b(v[0]), f2b(v[1]), f2b(v[2]), f2b(v[3])};
                *(us4*)&As[r * 88 + c * 4] = o;
            }
        } else {
            const u16* A = (const u16*)Ap;
            #pragma unroll
            for (int it = 0; it < 2; ++it) {
                int idx = tid + it * 256;
                int r = idx >> 3, c = idx & 7;
                short8 v = *(const short8*)(A + (size_t)(row0 + r) * K + k0 + c * 8);
                *(short8*)&As[r * 88 + c * 8] = v;
            }
        }
        __syncthreads();
        #pragma unroll
        for (int kk = 0; kk < 64; kk += 32) {
            short8 a0 = *(const short8*)&As[(wm + l16) * 88 + kk + quad * 8];
            short8 a1 = *(const short8*)&As[(wm + 16 + l16) * 88 + kk + quad * 8];
            #pragma unroll
            for (int nt = 0; nt < 4; ++nt) {
                short8 b = *(const short8*)&WT[(size_t)(n0 + wn + nt * 16 + l16) * K + k0 + kk + quad * 8];
                acc[0][nt] = __builtin_amdgcn_mfma_f32_16x16x32_bf16(a0, b, acc[0][nt], 0, 0, 0);
                acc[1][nt] = __builtin_amdgcn_mfma_f32_16x16x32_bf16(a1, b, acc[1][nt], 0, 0, 0);
            }
        }
    }
    #pragma unroll
    for (int mt = 0; mt < 2; ++mt)
        #pragma unroll
        for (int nt = 0; nt < 4; ++nt)
            #pragma unroll
            for (int r = 0; r < 4; ++r) {
                int row = row0 + wm + mt * 16 + quad * 4 + r;
                int col = n0 + wn + nt * 16 + l16;
                size_t o = (size_t)row * N + col;
                float v = acc[mt][nt][r];
                if (RELU) v = fmaxf(v, 0.f);
                if (ADD) v += OutF[o];
                if (OUTB) OutB[o] = f2b(v);
                else      OutF[o] = v;
            }
}

// ---------------------------------------------------------------------------
// Windowed attention v5 (unchanged).
// ---------------------------------------------------------------------------
__global__ __launch_bounds__(256) void attn_kernel(
    const u16* __restrict__ QKV, const u16* __restrict__ BIASb,
    u16* __restrict__ O)
{
    __shared__ __align__(16) u16 sQ[64 * 40];
    __shared__ __align__(16) u16 sK[128 * 40];
    __shared__ __align__(16) u16 sVt[32 * 152];
    __shared__ __align__(16) u16 sP[64 * 136];
    __shared__ float pmax[4][64];
    __shared__ float psum[4][64];
    __shared__ float gfac[4][64];

    int tid = threadIdx.x;
    int h = blockIdx.x & 3, w = (blockIdx.x >> 2) & 127, b = blockIdx.x >> 9;
    size_t rowbase = (size_t)b * N_ + w * QW;
    const short8 zero8 = (short8){0, 0, 0, 0, 0, 0, 0, 0};

    {
        int r = tid >> 2, d8 = (tid & 3) * 8;
        *(short8*)&sQ[r * 40 + d8] =
            *(const short8*)&QKV[(rowbase + r) * 384 + h * DH + d8];
    }
    #pragma unroll
    for (int i = 0; i < 2; ++i) {
        int idx = tid + i * 256;
        int r = idx >> 2, d8 = (idx & 3) * 8;
        int jk = w * QW + r - PADW;
        short8 v = zero8;
        if (jk >= 0 && jk < N_)
            v = *(const short8*)&QKV[((size_t)b * N_ + jk) * 384 + 128 + h * DH + d8];
        *(short8*)&sK[r * 40 + d8] = v;
    }
    {
        int kk = tid >> 1, d0 = (tid & 1) * 16;
        int jk = w * QW + kk - PADW;
        short8 v0 = zero8, v1 = zero8;
        if (jk >= 0 && jk < N_) {
            const u16* src = &QKV[((size_t)b * N_ + jk) * 384 + 256 + h * DH + d0];
            v0 = *(const short8*)src;
            v1 = *(const short8*)(src + 8);
        }
        #pragma unroll
        for (int j = 0; j < 8; ++j) {
            sVt[(d0 + j) * 152 + kk] = (u16)v0[j];
            sVt[(d0 + 8 + j) * 152 + kk] = (u16)v1[j];
        }
    }
    __syncthreads();

    int wv = tid >> 6, lane = tid & 63, quad = lane >> 4, l16 = lane & 15;
    const float scale = 0.17677669529663687f;
    size_t bbase = ((size_t)(b * NWIN + w) * HEADS + h) * (QW * KW);

    short8 aq[4];
    #pragma unroll
    for (int mt = 0; mt < 4; ++mt)
        aq[mt] = *(short8*)&sQ[(mt * 16 + l16) * 40 + quad * 8];
    float e[2][4][4];
    #pragma unroll
    for (int ni = 0; ni < 2; ++ni) {
        int nt = wv * 2 + ni;
        short8 bk = *(short8*)&sK[(nt * 16 + l16) * 40 + quad * 8];
        int kk = nt * 16 + l16;
        int jk = w * QW + kk - PADW;
        float msk = (jk >= 0 && jk < N_) ? 0.f : -1e9f;
        #pragma unroll
        for (int mt = 0; mt < 4; ++mt) {
            f32x4v acc = (f32x4v){0.f, 0.f, 0.f, 0.f};
            acc = __builtin_amdgcn_mfma_f32_16x16x32_bf16(aq[mt], bk, acc, 0, 0, 0);
            #pragma unroll
            for (int r = 0; r < 4; ++r) {
                int q = mt * 16 + quad * 4 + r;
                e[ni][mt][r] = acc[r] * scale + b2f(BIASb[bbase + q * KW + kk]) + msk;
            }
        }
    }

    #pragma unroll
    for (int mt = 0; mt < 4; ++mt)
        #pragma unroll
        for (int r = 0; r < 4; ++r) {
            float m = fmaxf(e[0][mt][r], e[1][mt][r]);
            m = fmaxf(m, __shfl_xor(m, 1));
            m = fmaxf(m, __shfl_xor(m, 2));
            m = fmaxf(m, __shfl_xor(m, 4));
            m = fmaxf(m, __shfl_xor(m, 8));
            float e0 = __expf(e[0][mt][r] - m);
            float e1 = __expf(e[1][mt][r] - m);
            e[0][mt][r] = e0; e[1][mt][r] = e1;
            float s = e0 + e1;
            s += __shfl_xor(s, 1);
            s += __shfl_xor(s, 2);
            s += __shfl_xor(s, 4);
            s += __shfl_xor(s, 8);
            if (l16 == 0) {
                int q = mt * 16 + quad * 4 + r;
                pmax[wv][q] = m;
                psum[wv][q] = s;
            }
        }
    __syncthreads();

    if (tid < 64) {
        float m0 = pmax[0][tid], m1 = pmax[1][tid], m2 = pmax[2][tid], m3 = pmax[3][tid];
        float M = fmaxf(fmaxf(m0, m1), fmaxf(m2, m3));
        float g0 = __expf(m0 - M), g1 = __expf(m1 - M),
              g2 = __expf(m2 - M), g3 = __expf(m3 - M);
        float T = psum[0][tid] * g0 + psum[1][tid] * g1 +
                  psum[2][tid] * g2 + psum[3][tid] * g3;
        float inv = 1.f / T;
        gfac[0][tid] = g0 * inv; gfac[1][tid] = g1 * inv;
        gfac[2][tid] = g2 * inv; gfac[3][tid] = g3 * inv;
    }
    __syncthreads();

    #pragma unroll
    for (int mt = 0; mt < 4; ++mt)
        #pragma unroll
        for (int r = 0; r < 4; ++r) {
            int q = mt * 16 + quad * 4 + r;
            float f = gfac[wv][q];
            #pragma unroll
            for (int ni = 0; ni < 2; ++ni) {
                int kk = (wv * 2 + ni) * 16 + l16;
                sP[q * 136 + kk] = f2b(e[ni][mt][r] * f);
            }
        }
    __syncthreads();

    {
        int mt = wv;
        short8 ap[4];
        #pragma unroll
        for (int ks = 0; ks < 4; ++ks)
            ap[ks] = *(short8*)&sP[(mt * 16 + l16) * 136 + ks * 32 + quad * 8];
        #pragma unroll
        for (int nt = 0; nt < 2; ++nt) {
            f32x4v acc = (f32x4v){0.f, 0.f, 0.f, 0.f};
            #pragma unroll
            for (int ks = 0; ks < 4; ++ks) {
                short8 bv = *(short8*)&sVt[(nt * 16 + l16) * 152 + ks * 32 + quad * 8];
                acc = __builtin_amdgcn_mfma_f32_16x16x32_bf16(ap[ks], bv, acc, 0, 0, 0);
            }
            int d = nt * 16 + l16;
            #pragma unroll
            for (int r = 0; r < 4; ++r) {
                int q = mt * 16 + quad * 4 + r;
                O[(rowbase + q) * DS + h * DH + d] = f2b(acc[r]);
            }
        }
    }
}

// ---------------------------------------------------------------------------
// Segment mean (sorted indices), TOK in bf16.
// ---------------------------------------------------------------------------
__global__ __launch_bounds__(128) void seg_kernel(
    const u16* __restrict__ TOKb, const int* __restrict__ idx,
    float* __restrict__ out)
{
    int t = blockIdx.x & (NT - 1);
    int b = blockIdx.x >> 10;
    const int* id = idx + (size_t)b * N_;

    int lo = 0, hi = N_;
    while (lo < hi) { int mid = (lo + hi) >> 1; if (id[mid] < t) lo = mid + 1; else hi = mid; }
    int start = lo;
    hi = N_;
    while (lo < hi) { int mid = (lo + hi) >> 1; if (id[mid] < t + 1) lo = mid + 1; else hi = mid; }
    int end = lo;

    float inv = 1.f / fmaxf((float)(end - start), 1.f);
    for (int c = threadIdx.x; c < DT; c += 128) {
        float s = 0.f;
        for (int r = start; r < end; ++r) s += b2f(TOKb[((size_t)b * N_ + r) * DT + c]);
        out[((size_t)b * NT + t) * DT + c] = s * inv;
    }
}

// ---------------------------------------------------------------------------
extern "C" void kernel_launch(void* const* d_in, const int* in_sizes, int n_in,
                              void* d_out, int out_size, void* d_ws, size_t ws_size,
                              hipStream_t stream)
{
    const float* ref_pos    = (const float*)d_in[0];
    const float* ref_charge = (const float*)d_in[1];
    const float* ref_mask   = (const float*)d_in[2];
    const float* ref_elem   = (const float*)d_in[3];
    const float* ref_chars  = (const float*)d_in[4];
    const float* W_single   = (const float*)d_in[5];
    const float* W_pair     = (const float*)d_in[6];
    const float* W_outer    = (const float*)d_in[7];
    const float* Wp_ff1     = (const float*)d_in[8];
    const float* Wp_ff2     = (const float*)d_in[9];
    const float* Wq         = (const float*)d_in[10];
    const float* Wk         = (const float*)d_in[11];
    const float* Wv         = (const float*)d_in[12];
    const float* Wo         = (const float*)d_in[13];
    const float* Wb         = (const float*)d_in[14];
    const float* Wff1       = (const float*)d_in[15];
    const float* Wff2       = (const float*)d_in[16];
    const float* W_out      = (const float*)d_in[17];
    const int*   uid        = (const int*)d_in[18];
    const int*   a2t        = (const int*)d_in[19];
    float* out = (float*)d_out;

    const size_t ROWS = (size_t)B_ * N_;  // 16384
    float* ws = (float*)d_ws;
    float* X    = ws;                          // 2,097,152 f
    float* P    = X + ROWS * DS;               //   524,288 f
    u16* QKVb   = (u16*)(P + ROWS * 32);       // 6,291,456 u16
    u16* Ob     = QKVb + ROWS * 384;           // 2,097,152
    u16* FFb    = Ob + ROWS * DS;              // 8,388,608
    u16* BIASb  = FFb + ROWS * 512;            // 8,388,608
    u16* TOKb   = BIASb + (size_t)B_ * NWIN * HEADS * QW * KW;  // 6,291,456
    u16* SRELUb = TOKb + ROWS * DT;            // 2,097,152
    u16* qkvT   = SRELUb + ROWS * DS;
    u16* woT    = qkvT + 3 * 384 * 128;
    u16* ff1T   = woT + 3 * 128 * 128;
    u16* ff2T   = ff1T + 3 * 512 * 128;
    u16* woutT  = ff2T + 3 * 128 * 512;
    u16* w1T32  = woutT + 384 * 128;
    u16* wcatT  = w1T32 + 64 * 32;
    u16* wsT    = wcatT + 16 * 96;             // 53,248
    u16* woutrT = wsT + 128 * 416;             //  4,096

    convw_kernel<<<768, 256, 0, stream>>>(Wq, Wk, Wv, Wo, Wff1, Wff2, W_out,
                                          Wp_ff1, Wp_ff2, Wb, W_single, W_outer,
                                          qkvT, woT, ff1T, ff2T, woutT,
                                          w1T32, wcatT, wsT, woutrT);
    embed_gemm<<<ROWS / 64, 256, 0, stream>>>(ref_pos, ref_charge, ref_mask,
                                              ref_elem, ref_chars, wsT,
                                              X, SRELUb);
    pgemm_kernel<<<ROWS / 64, 256, 0, stream>>>(SRELUb, woutrT, P);
    bias_kernel<<<4096, 256, 0, stream>>>(ref_pos, uid, P, W_pair,
                                          w1T32, wcatT, BIASb);

    for (int l = 0; l < DEPTH; ++l) {
        gemm_ln<false><<<dim3(ROWS / 64, 3), 256, 0, stream>>>(
            X, qkvT + (size_t)l * 384 * 128, QKVb, 384);
        attn_kernel<<<B_ * NWIN * HEADS, 256, 0, stream>>>(QKVb, BIASb, Ob);
        gemm_mfma<false, true, false, false><<<dim3(ROWS / 64, 1), 256, 0, stream>>>(
            Ob, woT + (size_t)l * 128 * 128, X, nullptr, ROWS, DS, DS);
        gemm_ln<true><<<dim3(ROWS / 64, 4), 256, 0, stream>>>(
            X, ff1T + (size_t)l * 512 * 128, FFb, 512);
        gemm_mfma<false, true, false, false><<<dim3(ROWS / 64, 1), 256, 0, stream>>>(
            FFb, ff2T + (size_t)l * 128 * 512, X, nullptr, ROWS, 4 * DS, DS);
    }

    gemm_mfma<true, false, true, true><<<dim3(ROWS / 64, 3), 256, 0, stream>>>(
        X, woutT, nullptr, TOKb, ROWS, DS, DT);
    seg_kernel<<<B_ * NT, 128, 0, stream>>>(TOKb, a2t, out);
}

// Round 7
// 477.211 us; speedup vs baseline: 3.0592x; 1.0108x over previous
//
#include <hip/hip_runtime.h>
#include <hip/hip_bf16.h>

#define QW 64
#define KW 128
#define PADW 32
#define DEPTH 3
#define HEADS 4
#define B_ 2
#define N_ 8192
#define DS 128
#define DP 16
#define DT 384
#define NT 1024
#define NWIN (N_ / QW)   // 128
#define DH (DS / HEADS)  // 32

typedef unsigned short u16;
typedef __attribute__((ext_vector_type(8))) short short8;
typedef __attribute__((ext_vector_type(4))) float f32x4v;
typedef __attribute__((ext_vector_type(4))) unsigned short us4;

__device__ __forceinline__ u16 f2b(float x) {
    union { float f; unsigned u; } v; v.f = x;
    unsigned r = v.u + 0x7fffu + ((v.u >> 16) & 1u);
    return (u16)(r >> 16);
}
__device__ __forceinline__ float b2f(u16 h) {
    union { unsigned u; float f; } v; v.u = ((unsigned)h) << 16; return v.f;
}
__device__ __forceinline__ unsigned f2b2(float a, float b) {
    __hip_bfloat162 h = __float22bfloat162_rn(make_float2(a, b));
    union { __hip_bfloat162 h; unsigned u; } c; c.h = h; return c.u;
}
__device__ __forceinline__ us4 pack4(float a, float b, float c, float d) {
    union { us4 v; unsigned u[2]; } o;
    o.u[0] = f2b2(a, b);
    o.u[1] = f2b2(c, d);
    return o.v;
}

// ---------------------------------------------------------------------------
// Weight prep (same as round 6).
// ---------------------------------------------------------------------------
__global__ __launch_bounds__(256) void convw_kernel(
    const float* __restrict__ Wq, const float* __restrict__ Wk,
    const float* __restrict__ Wv, const float* __restrict__ Wo,
    const float* __restrict__ Wff1, const float* __restrict__ Wff2,
    const float* __restrict__ Wout, const float* __restrict__ Wpff1,
    const float* __restrict__ Wpff2, const float* __restrict__ Wb,
    const float* __restrict__ Wsingle, const float* __restrict__ Wouter,
    u16* __restrict__ qkvT, u16* __restrict__ woT, u16* __restrict__ ff1T,
    u16* __restrict__ ff2T, u16* __restrict__ woutT,
    u16* __restrict__ w1T32, u16* __restrict__ wcatT,
    u16* __restrict__ wsT, u16* __restrict__ woutrT)
{
    int idx = blockIdx.x * 256 + threadIdx.x;
    if (idx < 3 * 384 * 128) {
        int l = idx / (384 * 128), r = idx % (384 * 128);
        int n = r / 128, k = r % 128;
        const float* W = (n < 128) ? Wq : (n < 256) ? Wk : Wv;
        qkvT[idx] = f2b(W[(size_t)l * 16384 + k * 128 + (n & 127)]);
    }
    if (idx < 3 * 128 * 128) {
        int l = idx / 16384, r = idx % 16384;
        int n = r / 128, k = r % 128;
        woT[idx] = f2b(Wo[(size_t)l * 16384 + k * 128 + n]);
    }
    if (idx < 3 * 512 * 128) {
        int l = idx / 65536, r = idx % 65536;
        int n = r / 128, k = r % 128;
        ff1T[idx] = f2b(Wff1[(size_t)l * 65536 + k * 512 + n]);
    }
    if (idx < 3 * 128 * 512) {
        int l = idx / 65536, r = idx % 65536;
        int n = r / 512, k = r % 512;
        ff2T[idx] = f2b(Wff2[(size_t)l * 65536 + k * 128 + n]);
    }
    if (idx < 384 * 128) {
        int n = idx / 128, k = idx % 128;
        woutT[idx] = f2b(Wout[(size_t)k * 384 + n]);
    }
    if (idx < 64 * 32) {
        int n = idx >> 5, k = idx & 31;
        w1T32[idx] = (k < 16) ? f2b(Wpff1[k * 64 + n]) : (u16)0;
    }
    if (idx < 16 * 96) {
        int h = idx / 96, k = idx % 96;
        float s = 0.f;
        if (h < 4) {
            if (k < 16) s = Wb[k * 4 + h];
            else if (k < 80) {
                int j = k - 16;
                for (int c = 0; c < 16; ++c) s += Wpff2[j * 16 + c] * Wb[c * 4 + h];
            }
        }
        wcatT[idx] = f2b(s);
    }
    if (idx < 128 * 416) {  // wsT[n][k], permuted K
        int n = idx / 416, k = idx % 416;
        float v = 0.f;
        if (k < 128)       v = Wsingle[(5 + k) * 128 + n];
        else if (k < 384)  v = Wsingle[(133 + k - 128) * 128 + n];
        else if (k < 387)  v = Wsingle[(k - 384) * 128 + n];
        else if (k == 387) v = Wsingle[3 * 128 + n];
        else if (k == 388) v = Wsingle[4 * 128 + n];
        wsT[idx] = f2b(v);
    }
    if (idx < 32 * 128) {
        int n = idx >> 7, k = idx & 127;
        woutrT[idx] = f2b(Wouter[k * 32 + n]);
    }
}

// ---------------------------------------------------------------------------
// Embed GEMM (MFMA) + fused LN + fused P-GEMM.
// X = feats @ Ws; LNb = LN(X) bf16; P = relu(X) @ Wouter (relu tile in LDS).
// ---------------------------------------------------------------------------
__global__ __launch_bounds__(256) void embed_gemm(
    const float* __restrict__ pos, const float* __restrict__ charge,
    const float* __restrict__ mask, const float* __restrict__ elem,
    const float* __restrict__ chars, const u16* __restrict__ wsT,
    const u16* __restrict__ woutrT,
    float* __restrict__ X, u16* __restrict__ LNb, float* __restrict__ P)
{
    __shared__ __align__(16) u16 As[64 * 424];  // 53 KB (reused for relu tile)
    __shared__ float redS[64][4];
    int tid = threadIdx.x;
    int row0 = blockIdx.x * 64;

    #pragma unroll
    for (int it = 0; it < 8; ++it) {   // elem -> cols 0..127
        int idx = tid + it * 256;
        int r = idx >> 5, c4 = idx & 31;
        f32x4v v = *(const f32x4v*)(elem + (size_t)(row0 + r) * 128 + c4 * 4);
        *(us4*)&As[r * 424 + c4 * 4] = pack4(v[0], v[1], v[2], v[3]);
    }
    #pragma unroll
    for (int it = 0; it < 16; ++it) {  // chars -> cols 128..383
        int idx = tid + it * 256;
        int r = idx >> 6, c4 = idx & 63;
        f32x4v v = *(const f32x4v*)(chars + (size_t)(row0 + r) * 256 + c4 * 4);
        *(us4*)&As[r * 424 + 128 + c4 * 4] = pack4(v[0], v[1], v[2], v[3]);
    }
    if (tid < 64) {                    // tail cols 384..388 + pad
        int g = row0 + tid;
        As[tid * 424 + 384] = f2b(pos[g * 3]);
        As[tid * 424 + 385] = f2b(pos[g * 3 + 1]);
        As[tid * 424 + 386] = f2b(pos[g * 3 + 2]);
        As[tid * 424 + 387] = f2b(charge[g]);
        As[tid * 424 + 388] = f2b(mask[g]);
        for (int c = 389; c < 416; ++c) As[tid * 424 + c] = 0;
    }
    __syncthreads();

    int wv = tid >> 6, lane = tid & 63, quad = lane >> 4, l16 = lane & 15;
    int wm = (wv & 1) * 32, wn = (wv >> 1) * 64;
    f32x4v acc[2][4];
    #pragma unroll
    for (int i = 0; i < 2; ++i)
        #pragma unroll
        for (int j = 0; j < 4; ++j) acc[i][j] = (f32x4v){0.f, 0.f, 0.f, 0.f};

    #pragma unroll
    for (int kk = 0; kk < 13; ++kk) {
        short8 a0 = *(short8*)&As[(wm + l16) * 424 + kk * 32 + quad * 8];
        short8 a1 = *(short8*)&As[(wm + 16 + l16) * 424 + kk * 32 + quad * 8];
        #pragma unroll
        for (int nt = 0; nt < 4; ++nt) {
            short8 bw = *(const short8*)&wsT[(size_t)(wn + nt * 16 + l16) * 416 +
                                             kk * 32 + quad * 8];
            acc[0][nt] = __builtin_amdgcn_mfma_f32_16x16x32_bf16(a0, bw, acc[0][nt], 0, 0, 0);
            acc[1][nt] = __builtin_amdgcn_mfma_f32_16x16x32_bf16(a1, bw, acc[1][nt], 0, 0, 0);
        }
    }
    __syncthreads();  // done reading As; reuse as relu tile (stride 136)

    // write X, relu tile, LN partials
    #pragma unroll
    for (int mt = 0; mt < 2; ++mt) {
        #pragma unroll
        for (int r = 0; r < 4; ++r) {
            int lrow = wm + mt * 16 + quad * 4 + r;
            int row = row0 + lrow;
            float s = 0.f, ss = 0.f;
            #pragma unroll
            for (int nt = 0; nt < 4; ++nt) {
                float v = acc[mt][nt][r];
                int col = wn + nt * 16 + l16;
                X[(size_t)row * DS + col] = v;
                As[lrow * 136 + col] = f2b(fmaxf(v, 0.f));
                s += v; ss += v * v;
            }
            #pragma unroll
            for (int o = 1; o < 16; o <<= 1) {
                s  += __shfl_xor(s, o);
                ss += __shfl_xor(ss, o);
            }
            if (l16 == 0) {
                redS[lrow][(wv >> 1) * 2]     = s;
                redS[lrow][(wv >> 1) * 2 + 1] = ss;
            }
        }
    }
    __syncthreads();

    // LN write
    #pragma unroll
    for (int mt = 0; mt < 2; ++mt)
        #pragma unroll
        for (int r = 0; r < 4; ++r) {
            int lrow = wm + mt * 16 + quad * 4 + r;
            int row = row0 + lrow;
            f32x4v rv = *(f32x4v*)&redS[lrow][0];
            float s = rv[0] + rv[2], ss = rv[1] + rv[3];
            float m = s * (1.f / 128.f);
            float var = ss * (1.f / 128.f) - m * m;
            float rs = rsqrtf(var + 1e-5f);
            #pragma unroll
            for (int nt = 0; nt < 4; ++nt) {
                int col = wn + nt * 16 + l16;
                LNb[(size_t)row * DS + col] = f2b((acc[mt][nt][r] - m) * rs);
            }
        }

    // P-GEMM: wave wv owns rows wv*16..+15; N=32
    {
        f32x4v pacc[2];
        pacc[0] = (f32x4v){0.f, 0.f, 0.f, 0.f};
        pacc[1] = (f32x4v){0.f, 0.f, 0.f, 0.f};
        #pragma unroll
        for (int ks = 0; ks < 4; ++ks) {
            short8 a = *(short8*)&As[(wv * 16 + l16) * 136 + ks * 32 + quad * 8];
            #pragma unroll
            for (int nt = 0; nt < 2; ++nt) {
                short8 bw = *(const short8*)&woutrT[(size_t)(nt * 16 + l16) * 128 +
                                                    ks * 32 + quad * 8];
                pacc[nt] = __builtin_amdgcn_mfma_f32_16x16x32_bf16(a, bw, pacc[nt], 0, 0, 0);
            }
        }
        #pragma unroll
        for (int nt = 0; nt < 2; ++nt)
            #pragma unroll
            for (int r = 0; r < 4; ++r) {
                int row = row0 + wv * 16 + quad * 4 + r;
                P[(size_t)row * 32 + nt * 16 + l16] = pacc[nt][r];
            }
    }
}

// ---------------------------------------------------------------------------
// Bias kernel v6: pjS stride 20 (conflict fix) + packed bf16 cvt.
// ---------------------------------------------------------------------------
__global__ __launch_bounds__(256) void bias_kernel(
    const float* __restrict__ pos, const int* __restrict__ uid,
    const float* __restrict__ P, const float* __restrict__ Wpair,
    const u16* __restrict__ w1T32, const u16* __restrict__ wcatT,
    u16* __restrict__ BIASb)
{
    __shared__ __align__(16) float pjS[128][20];
    __shared__ __align__(16) float posjS[128][4];
    __shared__ __align__(16) u16 lpS[4][16 * 24];
    __shared__ __align__(16) u16 A2S[4][16 * 104];

    int tid = threadIdx.x;
    int b  = blockIdx.x >> 11;
    int w  = (blockIdx.x >> 4) & 127;
    int qg = blockIdx.x & 15;

    {
        int r = tid >> 1, half = tid & 1;
        int jk = w * QW + r - PADW;
        bool valid = (jk >= 0) && (jk < N_);
        int gk = b * N_ + jk;
        f32x4v z = (f32x4v){0.f, 0.f, 0.f, 0.f};
        f32x4v v0 = z, v1 = z;
        if (valid) {
            v0 = *(const f32x4v*)(P + (size_t)gk * 32 + 16 + half * 8);
            v1 = *(const f32x4v*)(P + (size_t)gk * 32 + 20 + half * 8);
        }
        *(f32x4v*)&pjS[r][half * 8]     = v0;
        *(f32x4v*)&pjS[r][half * 8 + 4] = v1;
        if (half == 0) {
            float x = 0.f, y = 0.f, zz = 0.f; int u = 0;
            if (valid) { x = pos[gk * 3]; y = pos[gk * 3 + 1]; zz = pos[gk * 3 + 2]; u = uid[gk]; }
            posjS[r][0] = x; posjS[r][1] = y; posjS[r][2] = zz;
            ((int*)posjS[r])[3] = u;
        }
    }

    int wv = tid >> 6, lane = tid & 63, quad = lane >> 4, l16 = lane & 15;
    int cl = lane >> 2, cg = lane & 3;
    int q = qg * 4 + wv;
    int gq = b * N_ + w * QW + q;

    float xi = pos[gq * 3], yi = pos[gq * 3 + 1], zi = pos[gq * 3 + 2];
    int ui = uid[gq];
    f32x4v pi4 = *(const f32x4v*)(P + (size_t)gq * 32 + cg * 4);
    f32x4v wp[5];
    #pragma unroll
    for (int f = 0; f < 5; ++f)
        wp[f] = *(const f32x4v*)(Wpair + f * 16 + cg * 4);
    short8 w1f[4], wcat[3];
    #pragma unroll
    for (int nt = 0; nt < 4; ++nt)
        w1f[nt] = *(const short8*)&w1T32[(nt * 16 + l16) * 32 + quad * 8];
    #pragma unroll
    for (int ks = 0; ks < 3; ++ks)
        wcat[ks] = *(const short8*)&wcatT[l16 * 96 + ks * 32 + quad * 8];
    *(us4*)&A2S[wv][l16 * 104 + 80 + quad * 4] = (us4){0, 0, 0, 0};
    __syncthreads();

    size_t bbase = ((size_t)(b * NWIN + w) * HEADS) * (QW * KW);
    const short8 zero8 = (short8){0, 0, 0, 0, 0, 0, 0, 0};

    for (int t = 0; t < 8; ++t) {
        int kk1 = t * 16 + cl;
        f32x4v pjv = *(f32x4v*)&pjS[kk1][cg * 4];
        float xj = posjS[kk1][0], yj = posjS[kk1][1], zj = posjS[kk1][2];
        int uj = ((int*)posjS[kk1])[3];
        float dx = xi - xj, dy = yi - yj, dz = zi - zj;
        float inv = 1.f / (1.f + dx * dx + dy * dy + dz * dz);
        float bf = (ui == uj) ? 1.f : 0.f;
        float pr[4];
        #pragma unroll
        for (int j = 0; j < 4; ++j) {
            float s = fmaf(dx, wp[0][j], fmaf(dy, wp[1][j],
                      fmaf(dz, wp[2][j], fmaf(inv, wp[3][j], wp[4][j]))));
            pr[j] = fmaf(bf, s, pi4[j] + pjv[j]);
        }
        float sum = pr[0] + pr[1] + pr[2] + pr[3];
        sum += __shfl_xor(sum, 1); sum += __shfl_xor(sum, 2);
        float m = sum * (1.f / 16.f);
        float d0 = pr[0] - m, d1 = pr[1] - m, d2 = pr[2] - m, d3 = pr[3] - m;
        float vs = d0 * d0 + d1 * d1 + d2 * d2 + d3 * d3;
        vs += __shfl_xor(vs, 1); vs += __shfl_xor(vs, 2);
        float rstd = rsqrtf(vs * (1.f / 16.f) + 1e-5f);
        *(us4*)&lpS[wv][cl * 24 + cg * 4] =
            pack4(d0 * rstd, d1 * rstd, d2 * rstd, d3 * rstd);
        *(us4*)&A2S[wv][cl * 104 + cg * 4] = pack4(pr[0], pr[1], pr[2], pr[3]);

        short8 blp = zero8;
        if (quad < 2) blp = *(short8*)&lpS[wv][l16 * 24 + quad * 8];
        #pragma unroll
        for (int nt = 0; nt < 4; ++nt) {
            f32x4v z4 = (f32x4v){0.f, 0.f, 0.f, 0.f};
            z4 = __builtin_amdgcn_mfma_f32_16x16x32_bf16(w1f[nt], blp, z4, 0, 0, 0);
            *(us4*)&A2S[wv][l16 * 104 + 16 + nt * 16 + quad * 4] =
                pack4(fmaxf(z4[0], 0.f), fmaxf(z4[1], 0.f),
                      fmaxf(z4[2], 0.f), fmaxf(z4[3], 0.f));
        }
        f32x4v acc = (f32x4v){0.f, 0.f, 0.f, 0.f};
        #pragma unroll
        for (int ks = 0; ks < 3; ++ks) {
            short8 a2 = *(short8*)&A2S[wv][l16 * 104 + ks * 32 + quad * 8];
            acc = __builtin_amdgcn_mfma_f32_16x16x32_bf16(a2, wcat[ks], acc, 0, 0, 0);
        }
        if (l16 < 4) {
            *(us4*)&BIASb[bbase + (size_t)l16 * (QW * KW) + q * KW +
                          t * 16 + quad * 4] = pack4(acc[0], acc[1], acc[2], acc[3]);
        }
    }
}

// ---------------------------------------------------------------------------
// Plain bf16-A GEMM (K=128): Out bf16 = (relu)(A @ WT^T). For QKV / FF1.
// ---------------------------------------------------------------------------
template <bool RELU>
__global__ __launch_bounds__(256) void gemm_bf(
    const u16* __restrict__ A, const u16* __restrict__ WT,
    u16* __restrict__ OutB, int N)
{
    __shared__ __align__(16) u16 As[64 * 136];
    int tid = threadIdx.x;
    int row0 = blockIdx.x * 64, n0 = blockIdx.y * 128;

    #pragma unroll
    for (int it = 0; it < 4; ++it) {
        int idx = tid + it * 256;
        int r = idx >> 4, c8 = idx & 15;
        *(short8*)&As[r * 136 + c8 * 8] =
            *(const short8*)&A[(size_t)(row0 + r) * 128 + c8 * 8];
    }
    __syncthreads();

    int wv = tid >> 6, lane = tid & 63, quad = lane >> 4, l16 = lane & 15;
    int wm = (wv & 1) * 32, wn = (wv >> 1) * 64;
    f32x4v acc[2][4];
    #pragma unroll
    for (int i = 0; i < 2; ++i)
        #pragma unroll
        for (int j = 0; j < 4; ++j) acc[i][j] = (f32x4v){0.f, 0.f, 0.f, 0.f};

    #pragma unroll
    for (int kk = 0; kk < 4; ++kk) {
        short8 a0 = *(short8*)&As[(wm + l16) * 136 + kk * 32 + quad * 8];
        short8 a1 = *(short8*)&As[(wm + 16 + l16) * 136 + kk * 32 + quad * 8];
        #pragma unroll
        for (int nt = 0; nt < 4; ++nt) {
            short8 bw = *(const short8*)&WT[(size_t)(n0 + wn + nt * 16 + l16) * 128 +
                                            kk * 32 + quad * 8];
            acc[0][nt] = __builtin_amdgcn_mfma_f32_16x16x32_bf16(a0, bw, acc[0][nt], 0, 0, 0);
            acc[1][nt] = __builtin_amdgcn_mfma_f32_16x16x32_bf16(a1, bw, acc[1][nt], 0, 0, 0);
        }
    }
    #pragma unroll
    for (int mt = 0; mt < 2; ++mt)
        #pragma unroll
        for (int nt = 0; nt < 4; ++nt)
            #pragma unroll
            for (int r = 0; r < 4; ++r) {
                int row = row0 + wm + mt * 16 + quad * 4 + r;
                int col = n0 + wn + nt * 16 + l16;
                float v = acc[mt][nt][r];
                if (RELU) v = fmaxf(v, 0.f);
                OutB[(size_t)row * N + col] = f2b(v);
            }
}

// ---------------------------------------------------------------------------
// bf16-A GEMM + residual ADD + fused LN: X += A@W; LNb = LN(X). N=128.
// For WO (K=128) and FF2 (K=512).
// ---------------------------------------------------------------------------
__global__ __launch_bounds__(256) void gemm_addln(
    const u16* __restrict__ A, const u16* __restrict__ WT,
    float* __restrict__ X, u16* __restrict__ LNb, int K)
{
    __shared__ __align__(16) u16 As[64 * 88];
    __shared__ float redS[64][4];
    const int row0 = blockIdx.x * 64;
    const int tid = threadIdx.x;
    const int wv = tid >> 6, lane = tid & 63, quad = lane >> 4, l16 = lane & 15;
    const int wm = (wv & 1) * 32, wn = (wv >> 1) * 64;

    f32x4v acc[2][4];
    #pragma unroll
    for (int i = 0; i < 2; ++i)
        #pragma unroll
        for (int j = 0; j < 4; ++j) acc[i][j] = (f32x4v){0.f, 0.f, 0.f, 0.f};

    for (int k0 = 0; k0 < K; k0 += 64) {
        __syncthreads();
        #pragma unroll
        for (int it = 0; it < 2; ++it) {
            int idx = tid + it * 256;
            int r = idx >> 3, c = idx & 7;
            *(short8*)&As[r * 88 + c * 8] =
                *(const short8*)&A[(size_t)(row0 + r) * K + k0 + c * 8];
        }
        __syncthreads();
        #pragma unroll
        for (int kk = 0; kk < 64; kk += 32) {
            short8 a0 = *(const short8*)&As[(wm + l16) * 88 + kk + quad * 8];
            short8 a1 = *(const short8*)&As[(wm + 16 + l16) * 88 + kk + quad * 8];
            #pragma unroll
            for (int nt = 0; nt < 4; ++nt) {
                short8 b = *(const short8*)&WT[(size_t)(wn + nt * 16 + l16) * K +
                                               k0 + kk + quad * 8];
                acc[0][nt] = __builtin_amdgcn_mfma_f32_16x16x32_bf16(a0, b, acc[0][nt], 0, 0, 0);
                acc[1][nt] = __builtin_amdgcn_mfma_f32_16x16x32_bf16(a1, b, acc[1][nt], 0, 0, 0);
            }
        }
    }

    // residual add + X store + LN partials
    #pragma unroll
    for (int mt = 0; mt < 2; ++mt) {
        #pragma unroll
        for (int r = 0; r < 4; ++r) {
            int lrow = wm + mt * 16 + quad * 4 + r;
            int row = row0 + lrow;
            float s = 0.f, ss = 0.f;
            #pragma unroll
            for (int nt = 0; nt < 4; ++nt) {
                int col = wn + nt * 16 + l16;
                size_t o = (size_t)row * DS + col;
                float v = acc[mt][nt][r] + X[o];
                acc[mt][nt][r] = v;
                X[o] = v;
                s += v; ss += v * v;
            }
            #pragma unroll
            for (int o2 = 1; o2 < 16; o2 <<= 1) {
                s  += __shfl_xor(s, o2);
                ss += __shfl_xor(ss, o2);
            }
            if (l16 == 0) {
                redS[lrow][(wv >> 1) * 2]     = s;
                redS[lrow][(wv >> 1) * 2 + 1] = ss;
            }
        }
    }
    __syncthreads();

    #pragma unroll
    for (int mt = 0; mt < 2; ++mt)
        #pragma unroll
        for (int r = 0; r < 4; ++r) {
            int lrow = wm + mt * 16 + quad * 4 + r;
            int row = row0 + lrow;
            f32x4v rv = *(f32x4v*)&redS[lrow][0];
            float s = rv[0] + rv[2], ss = rv[1] + rv[3];
            float m = s * (1.f / 128.f);
            float var = ss * (1.f / 128.f) - m * m;
            float rs = rsqrtf(var + 1e-5f);
            #pragma unroll
            for (int nt = 0; nt < 4; ++nt) {
                int col = wn + nt * 16 + l16;
                LNb[(size_t)row * DS + col] = f2b((acc[mt][nt][r] - m) * rs);
            }
        }
}

// ---------------------------------------------------------------------------
// Generic MFMA GEMM for final W_out (fp32 A, relu, bf16 out).
// ---------------------------------------------------------------------------
__global__ __launch_bounds__(256) void gemm_fin(
    const float* __restrict__ A, const u16* __restrict__ WT,
    u16* __restrict__ OutB, int K, int N)
{
    __shared__ __align__(16) u16 As[64 * 88];
    const int row0 = blockIdx.x * 64, n0 = blockIdx.y * 128;
    const int tid = threadIdx.x;
    const int w = tid >> 6, lane = tid & 63, quad = lane >> 4, l16 = lane & 15;
    const int wm = (w & 1) * 32, wn = (w >> 1) * 64;

    f32x4v acc[2][4];
    #pragma unroll
    for (int i = 0; i < 2; ++i)
        #pragma unroll
        for (int j = 0; j < 4; ++j) acc[i][j] = (f32x4v){0.f, 0.f, 0.f, 0.f};

    for (int k0 = 0; k0 < K; k0 += 64) {
        __syncthreads();
        #pragma unroll
        for (int it = 0; it < 4; ++it) {
            int idx = tid + it * 256;
            int r = idx >> 4, c = idx & 15;
            f32x4v v = *(const f32x4v*)(A + (size_t)(row0 + r) * K + k0 + c * 4);
            *(us4*)&As[r * 88 + c * 4] = pack4(v[0], v[1], v[2], v[3]);
        }
        __syncthreads();
        #pragma unroll
        for (int kk = 0; kk < 64; kk += 32) {
            short8 a0 = *(const short8*)&As[(wm + l16) * 88 + kk + quad * 8];
            short8 a1 = *(const short8*)&As[(wm + 16 + l16) * 88 + kk + quad * 8];
            #pragma unroll
            for (int nt = 0; nt < 4; ++nt) {
                short8 b = *(const short8*)&WT[(size_t)(n0 + wn + nt * 16 + l16) * K + k0 + kk + quad * 8];
                acc[0][nt] = __builtin_amdgcn_mfma_f32_16x16x32_bf16(a0, b, acc[0][nt], 0, 0, 0);
                acc[1][nt] = __builtin_amdgcn_mfma_f32_16x16x32_bf16(a1, b, acc[1][nt], 0, 0, 0);
            }
        }
    }
    #pragma unroll
    for (int mt = 0; mt < 2; ++mt)
        #pragma unroll
        for (int nt = 0; nt < 4; ++nt)
            #pragma unroll
            for (int r = 0; r < 4; ++r) {
                int row = row0 + wm + mt * 16 + quad * 4 + r;
                int col = n0 + wn + nt * 16 + l16;
                OutB[(size_t)row * N + col] = f2b(fmaxf(acc[mt][nt][r], 0.f));
            }
}

// ---------------------------------------------------------------------------
// Windowed attention v5 (unchanged).
// ---------------------------------------------------------------------------
__global__ __launch_bounds__(256) void attn_kernel(
    const u16* __restrict__ QKV, const u16* __restrict__ BIASb,
    u16* __restrict__ O)
{
    __shared__ __align__(16) u16 sQ[64 * 40];
    __shared__ __align__(16) u16 sK[128 * 40];
    __shared__ __align__(16) u16 sVt[32 * 152];
    __shared__ __align__(16) u16 sP[64 * 136];
    __shared__ float pmax[4][64];
    __shared__ float psum[4][64];
    __shared__ float gfac[4][64];

    int tid = threadIdx.x;
    int h = blockIdx.x & 3, w = (blockIdx.x >> 2) & 127, b = blockIdx.x >> 9;
    size_t rowbase = (size_t)b * N_ + w * QW;
    const short8 zero8 = (short8){0, 0, 0, 0, 0, 0, 0, 0};

    {
        int r = tid >> 2, d8 = (tid & 3) * 8;
        *(short8*)&sQ[r * 40 + d8] =
            *(const short8*)&QKV[(rowbase + r) * 384 + h * DH + d8];
    }
    #pragma unroll
    for (int i = 0; i < 2; ++i) {
        int idx = tid + i * 256;
        int r = idx >> 2, d8 = (idx & 3) * 8;
        int jk = w * QW + r - PADW;
        short8 v = zero8;
        if (jk >= 0 && jk < N_)
            v = *(const short8*)&QKV[((size_t)b * N_ + jk) * 384 + 128 + h * DH + d8];
        *(short8*)&sK[r * 40 + d8] = v;
    }
    {
        int kk = tid >> 1, d0 = (tid & 1) * 16;
        int jk = w * QW + kk - PADW;
        short8 v0 = zero8, v1 = zero8;
        if (jk >= 0 && jk < N_) {
            const u16* src = &QKV[((size_t)b * N_ + jk) * 384 + 256 + h * DH + d0];
            v0 = *(const short8*)src;
            v1 = *(const short8*)(src + 8);
        }
        #pragma unroll
        for (int j = 0; j < 8; ++j) {
            sVt[(d0 + j) * 152 + kk] = (u16)v0[j];
            sVt[(d0 + 8 + j) * 152 + kk] = (u16)v1[j];
        }
    }
    __syncthreads();

    int wv = tid >> 6, lane = tid & 63, quad = lane >> 4, l16 = lane & 15;
    const float scale = 0.17677669529663687f;
    size_t bbase = ((size_t)(b * NWIN + w) * HEADS + h) * (QW * KW);

    short8 aq[4];
    #pragma unroll
    for (int mt = 0; mt < 4; ++mt)
        aq[mt] = *(short8*)&sQ[(mt * 16 + l16) * 40 + quad * 8];
    float e[2][4][4];
    #pragma unroll
    for (int ni = 0; ni < 2; ++ni) {
        int nt = wv * 2 + ni;
        short8 bk = *(short8*)&sK[(nt * 16 + l16) * 40 + quad * 8];
        int kk = nt * 16 + l16;
        int jk = w * QW + kk - PADW;
        float msk = (jk >= 0 && jk < N_) ? 0.f : -1e9f;
        #pragma unroll
        for (int mt = 0; mt < 4; ++mt) {
            f32x4v acc = (f32x4v){0.f, 0.f, 0.f, 0.f};
            acc = __builtin_amdgcn_mfma_f32_16x16x32_bf16(aq[mt], bk, acc, 0, 0, 0);
            #pragma unroll
            for (int r = 0; r < 4; ++r) {
                int q = mt * 16 + quad * 4 + r;
                e[ni][mt][r] = acc[r] * scale + b2f(BIASb[bbase + q * KW + kk]) + msk;
            }
        }
    }

    #pragma unroll
    for (int mt = 0; mt < 4; ++mt)
        #pragma unroll
        for (int r = 0; r < 4; ++r) {
            float m = fmaxf(e[0][mt][r], e[1][mt][r]);
            m = fmaxf(m, __shfl_xor(m, 1));
            m = fmaxf(m, __shfl_xor(m, 2));
            m = fmaxf(m, __shfl_xor(m, 4));
            m = fmaxf(m, __shfl_xor(m, 8));
            float e0 = __expf(e[0][mt][r] - m);
            float e1 = __expf(e[1][mt][r] - m);
            e[0][mt][r] = e0; e[1][mt][r] = e1;
            float s = e0 + e1;
            s += __shfl_xor(s, 1);
            s += __shfl_xor(s, 2);
            s += __shfl_xor(s, 4);
            s += __shfl_xor(s, 8);
            if (l16 == 0) {
                int q = mt * 16 + quad * 4 + r;
                pmax[wv][q] = m;
                psum[wv][q] = s;
            }
        }
    __syncthreads();

    if (tid < 64) {
        float m0 = pmax[0][tid], m1 = pmax[1][tid], m2 = pmax[2][tid], m3 = pmax[3][tid];
        float M = fmaxf(fmaxf(m0, m1), fmaxf(m2, m3));
        float g0 = __expf(m0 - M), g1 = __expf(m1 - M),
              g2 = __expf(m2 - M), g3 = __expf(m3 - M);
        float T = psum[0][tid] * g0 + psum[1][tid] * g1 +
                  psum[2][tid] * g2 + psum[3][tid] * g3;
        float inv = 1.f / T;
        gfac[0][tid] = g0 * inv; gfac[1][tid] = g1 * inv;
        gfac[2][tid] = g2 * inv; gfac[3][tid] = g3 * inv;
    }
    __syncthreads();

    #pragma unroll
    for (int mt = 0; mt < 4; ++mt)
        #pragma unroll
        for (int r = 0; r < 4; ++r) {
            int q = mt * 16 + quad * 4 + r;
            float f = gfac[wv][q];
            #pragma unroll
            for (int ni = 0; ni < 2; ++ni) {
                int kk = (wv * 2 + ni) * 16 + l16;
                sP[q * 136 + kk] = f2b(e[ni][mt][r] * f);
            }
        }
    __syncthreads();

    {
        int mt = wv;
        short8 ap[4];
        #pragma unroll
        for (int ks = 0; ks < 4; ++ks)
            ap[ks] = *(short8*)&sP[(mt * 16 + l16) * 136 + ks * 32 + quad * 8];
        #pragma unroll
        for (int nt = 0; nt < 2; ++nt) {
            f32x4v acc = (f32x4v){0.f, 0.f, 0.f, 0.f};
            #pragma unroll
            for (int ks = 0; ks < 4; ++ks) {
                short8 bv = *(short8*)&sVt[(nt * 16 + l16) * 152 + ks * 32 + quad * 8];
                acc = __builtin_amdgcn_mfma_f32_16x16x32_bf16(ap[ks], bv, acc, 0, 0, 0);
            }
            int d = nt * 16 + l16;
            #pragma unroll
            for (int r = 0; r < 4; ++r) {
                int q = mt * 16 + quad * 4 + r;
                O[(rowbase + q) * DS + h * DH + d] = f2b(acc[r]);
            }
        }
    }
}

// ---------------------------------------------------------------------------
// Segment mean (sorted indices), TOK bf16.
// ---------------------------------------------------------------------------
__global__ __launch_bounds__(128) void seg_kernel(
    const u16* __restrict__ TOKb, const int* __restrict__ idx,
    float* __restrict__ out)
{
    int t = blockIdx.x & (NT - 1);
    int b = blockIdx.x >> 10;
    const int* id = idx + (size_t)b * N_;

    int lo = 0, hi = N_;
    while (lo < hi) { int mid = (lo + hi) >> 1; if (id[mid] < t) lo = mid + 1; else hi = mid; }
    int start = lo;
    hi = N_;
    while (lo < hi) { int mid = (lo + hi) >> 1; if (id[mid] < t + 1) lo = mid + 1; else hi = mid; }
    int end = lo;

    float inv = 1.f / fmaxf((float)(end - start), 1.f);
    for (int c = threadIdx.x; c < DT; c += 128) {
        float s = 0.f;
        for (int r = start; r < end; ++r) s += b2f(TOKb[((size_t)b * N_ + r) * DT + c]);
        out[((size_t)b * NT + t) * DT + c] = s * inv;
    }
}

// ---------------------------------------------------------------------------
extern "C" void kernel_launch(void* const* d_in, const int* in_sizes, int n_in,
                              void* d_out, int out_size, void* d_ws, size_t ws_size,
                              hipStream_t stream)
{
    const float* ref_pos    = (const float*)d_in[0];
    const float* ref_charge = (const float*)d_in[1];
    const float* ref_mask   = (const float*)d_in[2];
    const float* ref_elem   = (const float*)d_in[3];
    const float* ref_chars  = (const float*)d_in[4];
    const float* W_single   = (const float*)d_in[5];
    const float* W_pair     = (const float*)d_in[6];
    const float* W_outer    = (const float*)d_in[7];
    const float* Wp_ff1     = (const float*)d_in[8];
    const float* Wp_ff2     = (const float*)d_in[9];
    const float* Wq         = (const float*)d_in[10];
    const float* Wk         = (const float*)d_in[11];
    const float* Wv         = (const float*)d_in[12];
    const float* Wo         = (const float*)d_in[13];
    const float* Wb         = (const float*)d_in[14];
    const float* Wff1       = (const float*)d_in[15];
    const float* Wff2       = (const float*)d_in[16];
    const float* W_out      = (const float*)d_in[17];
    const int*   uid        = (const int*)d_in[18];
    const int*   a2t        = (const int*)d_in[19];
    float* out = (float*)d_out;

    const size_t ROWS = (size_t)B_ * N_;  // 16384
    float* ws = (float*)d_ws;
    float* X    = ws;                          // 2,097,152 f
    float* P    = X + ROWS * DS;               //   524,288 f
    u16* QKVb   = (u16*)(P + ROWS * 32);       // 6,291,456 u16
    u16* Ob     = QKVb + ROWS * 384;           // 2,097,152
    u16* FFb    = Ob + ROWS * DS;              // 8,388,608
    u16* BIASb  = FFb + ROWS * 512;            // 8,388,608
    u16* TOKb   = BIASb + (size_t)B_ * NWIN * HEADS * QW * KW;  // 6,291,456
    u16* LNb    = TOKb + ROWS * DT;            // 2,097,152
    u16* qkvT   = LNb + ROWS * DS;
    u16* woT    = qkvT + 3 * 384 * 128;
    u16* ff1T   = woT + 3 * 128 * 128;
    u16* ff2T   = ff1T + 3 * 512 * 128;
    u16* woutT  = ff2T + 3 * 128 * 512;
    u16* w1T32  = woutT + 384 * 128;
    u16* wcatT  = w1T32 + 64 * 32;
    u16* wsT    = wcatT + 16 * 96;
    u16* woutrT = wsT + 128 * 416;

    convw_kernel<<<768, 256, 0, stream>>>(Wq, Wk, Wv, Wo, Wff1, Wff2, W_out,
                                          Wp_ff1, Wp_ff2, Wb, W_single, W_outer,
                                          qkvT, woT, ff1T, ff2T, woutT,
                                          w1T32, wcatT, wsT, woutrT);
    embed_gemm<<<ROWS / 64, 256, 0, stream>>>(ref_pos, ref_charge, ref_mask,
                                              ref_elem, ref_chars, wsT, woutrT,
                                              X, LNb, P);
    bias_kernel<<<4096, 256, 0, stream>>>(ref_pos, uid, P, W_pair,
                                          w1T32, wcatT, BIASb);

    for (int l = 0; l < DEPTH; ++l) {
        gemm_bf<false><<<dim3(ROWS / 64, 3), 256, 0, stream>>>(
            LNb, qkvT + (size_t)l * 384 * 128, QKVb, 384);
        attn_kernel<<<B_ * NWIN * HEADS, 256, 0, stream>>>(QKVb, BIASb, Ob);
        gemm_addln<<<dim3(ROWS / 64, 1), 256, 0, stream>>>(
            Ob, woT + (size_t)l * 128 * 128, X, LNb, 128);
        gemm_bf<true><<<dim3(ROWS / 64, 4), 256, 0, stream>>>(
            LNb, ff1T + (size_t)l * 512 * 128, FFb, 512);
        gemm_addln<<<dim3(ROWS / 64, 1), 256, 0, stream>>>(
            FFb, ff2T + (size_t)l * 128 * 512, X, LNb, 512);
    }

    gemm_fin<<<dim3(ROWS / 64, 3), 256, 0, stream>>>(X, woutT, TOKb, DS, DT);
    seg_kernel<<<B_ * NT, 128, 0, stream>>>(TOKb, a2t, out);
}